// Round 1
// baseline (6131.654 us; speedup 1.0000x reference)
//
#include <hip/hip_runtime.h>

#define N_USERS 100000
#define N_ITEMS 50000
#define N_NODES (N_USERS + N_ITEMS)
#define DIM 64
#define BATCH 16384

// ---------------------------------------------------------------------------
// Block-level reduction: wave shfl_xor butterfly, then LDS across waves.
// Returns full block sum on thread 0 (garbage elsewhere).
// ---------------------------------------------------------------------------
__device__ __forceinline__ float block_reduce_sum(float v) {
    for (int s = 32; s > 0; s >>= 1) v += __shfl_xor(v, s, 64);
    __shared__ float sm[8];
    int lane = threadIdx.x & 63;
    int wid  = threadIdx.x >> 6;
    if (lane == 0) sm[wid] = v;
    __syncthreads();
    float t = 0.0f;
    if (threadIdx.x == 0) {
        int nw = (blockDim.x + 63) >> 6;
        for (int w = 0; w < nw; ++w) t += sm[w];
    }
    return t;
}

// ---------------------------------------------------------------------------
// Init: acc_0 = gathered layer-0 embeddings; also reg_sum (uses ORIGINAL
// weights, per reference). 16 threads per batch sample (float4 each).
// ---------------------------------------------------------------------------
__global__ void init_kernel(const float* __restrict__ uw, const float* __restrict__ iw,
                            const int* __restrict__ users, const int* __restrict__ pos,
                            const int* __restrict__ neg,
                            float* __restrict__ uacc, float* __restrict__ pacc,
                            float* __restrict__ nacc, float* __restrict__ reg_sum) {
    int tid = blockIdx.x * blockDim.x + threadIdx.x;
    int i = tid >> 4;
    int q = tid & 15;
    if (i >= BATCH) return;
    size_t o = (size_t)i * DIM + q * 4;
    float4 u = *(const float4*)(uw + (size_t)users[i] * DIM + q * 4);
    float4 p = *(const float4*)(iw + (size_t)pos[i]   * DIM + q * 4);
    float4 n = *(const float4*)(iw + (size_t)neg[i]   * DIM + q * 4);
    *(float4*)(uacc + o) = u;
    *(float4*)(pacc + o) = p;
    *(float4*)(nacc + o) = n;
    float ss = u.x*u.x + u.y*u.y + u.z*u.z + u.w*u.w
             + p.x*p.x + p.y*p.y + p.z*p.z + p.w*p.w
             + n.x*n.x + n.y*n.y + n.z*n.z + n.w*n.w;
    float bt = block_reduce_sum(ss);
    if (threadIdx.x == 0) unsafeAtomicAdd(reg_sum, bt);
}

// ---------------------------------------------------------------------------
// COO SpMM: out[row] += val * x[col].  16 threads/edge, float4 lanes,
// hardware f32 atomics. Layer-0 input is the virtual concat [uw; iw].
// ---------------------------------------------------------------------------
__global__ void spmm_kernel(const float* __restrict__ xu, const float* __restrict__ xi,
                            const float* __restrict__ vals, const int* __restrict__ rows,
                            const int* __restrict__ cols,
                            float* __restrict__ out, int nnz) {
    long long tid = (long long)blockIdx.x * blockDim.x + threadIdx.x;
    int e = (int)(tid >> 4);
    if (e >= nnz) return;
    int q = (int)(tid & 15);
    int r = rows[e];
    int c = cols[e];
    float v = vals[e];
    const float* src = (c < N_USERS) ? (xu + (size_t)c * DIM)
                                     : (xi + (size_t)(c - N_USERS) * DIM);
    float4 x = *(const float4*)(src + q * 4);
    float* dst = out + (size_t)r * DIM + q * 4;
    unsafeAtomicAdd(dst + 0, v * x.x);
    unsafeAtomicAdd(dst + 1, v * x.y);
    unsafeAtomicAdd(dst + 2, v * x.z);
    unsafeAtomicAdd(dst + 3, v * x.w);
}

// ---------------------------------------------------------------------------
// Gather-accumulate a layer's output at the batch rows only.
// ---------------------------------------------------------------------------
__global__ void gather_add_kernel(const float* __restrict__ x,
                                  const int* __restrict__ users, const int* __restrict__ pos,
                                  const int* __restrict__ neg,
                                  float* __restrict__ uacc, float* __restrict__ pacc,
                                  float* __restrict__ nacc) {
    int tid = blockIdx.x * blockDim.x + threadIdx.x;
    int i = tid >> 4;
    int q = tid & 15;
    if (i >= BATCH) return;
    size_t o = (size_t)i * DIM + q * 4;
    float4 a, b;

    a = *(float4*)(uacc + o);
    b = *(const float4*)(x + (size_t)users[i] * DIM + q * 4);
    a.x += b.x; a.y += b.y; a.z += b.z; a.w += b.w;
    *(float4*)(uacc + o) = a;

    a = *(float4*)(pacc + o);
    b = *(const float4*)(x + (size_t)(N_USERS + pos[i]) * DIM + q * 4);
    a.x += b.x; a.y += b.y; a.z += b.z; a.w += b.w;
    *(float4*)(pacc + o) = a;

    a = *(float4*)(nacc + o);
    b = *(const float4*)(x + (size_t)(N_USERS + neg[i]) * DIM + q * 4);
    a.x += b.x; a.y += b.y; a.z += b.z; a.w += b.w;
    *(float4*)(nacc + o) = a;
}

// ---------------------------------------------------------------------------
// Scores + loss partial sum. final = acc/4, so dot(u,p) = dot(uacc,pacc)/16.
// ---------------------------------------------------------------------------
__global__ void score_kernel(const float* __restrict__ uacc, const float* __restrict__ pacc,
                             const float* __restrict__ nacc, float* __restrict__ loss_sum) {
    int tid = blockIdx.x * blockDim.x + threadIdx.x;
    int i = tid >> 4;
    int q = tid & 15;
    float ps = 0.0f, ns = 0.0f;
    if (i < BATCH) {
        size_t o = (size_t)i * DIM + q * 4;
        float4 u = *(const float4*)(uacc + o);
        float4 p = *(const float4*)(pacc + o);
        float4 n = *(const float4*)(nacc + o);
        ps = u.x*p.x + u.y*p.y + u.z*p.z + u.w*p.w;
        ns = u.x*n.x + u.y*n.y + u.z*n.z + u.w*n.w;
    }
    // reduce within each 16-lane group (one sample)
    for (int s = 8; s > 0; s >>= 1) {
        ps += __shfl_xor(ps, s, 16);
        ns += __shfl_xor(ns, s, 16);
    }
    float term = 0.0f;
    if (q == 0 && i < BATCH) {
        float d = (ps - ns) * (1.0f / 16.0f);
        float sig = 1.0f / (1.0f + expf(-d));
        term = logf(sig + 1e-8f);
    }
    float bt = block_reduce_sum(term);
    if (threadIdx.x == 0) unsafeAtomicAdd(loss_sum, bt);
}

__global__ void finalize_kernel(const float* __restrict__ sums, float* __restrict__ out) {
    if (threadIdx.x == 0 && blockIdx.x == 0) {
        out[0] = -sums[0] / (float)BATCH;  // loss = -mean(log(...))
        out[1] =  sums[1] / (float)BATCH;  // reg_loss
    }
}

extern "C" void kernel_launch(void* const* d_in, const int* in_sizes, int n_in,
                              void* d_out, int out_size, void* d_ws, size_t ws_size,
                              hipStream_t stream) {
    const float* uw   = (const float*)d_in[0];
    const float* iw   = (const float*)d_in[1];
    const float* vals = (const float*)d_in[2];
    const int*   rows = (const int*)d_in[3];
    const int*   cols = (const int*)d_in[4];
    const int*   users = (const int*)d_in[5];
    const int*   pos   = (const int*)d_in[6];
    const int*   neg   = (const int*)d_in[7];
    const int nnz = in_sizes[2];

    char* ws = (char*)d_ws;
    const size_t nodeBytes = (size_t)N_NODES * DIM * sizeof(float);
    float* xA   = (float*)(ws);
    float* xB   = (float*)(ws + nodeBytes);
    float* uacc = (float*)(ws + 2 * nodeBytes);
    float* pacc = uacc + (size_t)BATCH * DIM;
    float* nacc = pacc + (size_t)BATCH * DIM;
    float* sums = nacc + (size_t)BATCH * DIM;  // [0]=loss_sum, [1]=reg_sum
    float* out  = (float*)d_out;

    const int bthreads = BATCH * 16;             // 262144
    const int bblocks  = bthreads / 256;         // 1024
    const long long sthreads = (long long)nnz * 16;
    const int sblocks = (int)((sthreads + 255) / 256);

    hipMemsetAsync(sums, 0, 2 * sizeof(float), stream);
    hipMemsetAsync(xA, 0, nodeBytes, stream);

    init_kernel<<<bblocks, 256, 0, stream>>>(uw, iw, users, pos, neg, uacc, pacc, nacc, sums + 1);

    // Layer 1: [uw;iw] -> xA
    spmm_kernel<<<sblocks, 256, 0, stream>>>(uw, iw, vals, rows, cols, xA, nnz);
    gather_add_kernel<<<bblocks, 256, 0, stream>>>(xA, users, pos, neg, uacc, pacc, nacc);

    // Layer 2: xA -> xB
    hipMemsetAsync(xB, 0, nodeBytes, stream);
    spmm_kernel<<<sblocks, 256, 0, stream>>>(xA, xA + (size_t)N_USERS * DIM, vals, rows, cols, xB, nnz);
    gather_add_kernel<<<bblocks, 256, 0, stream>>>(xB, users, pos, neg, uacc, pacc, nacc);

    // Layer 3: xB -> xA
    hipMemsetAsync(xA, 0, nodeBytes, stream);
    spmm_kernel<<<sblocks, 256, 0, stream>>>(xB, xB + (size_t)N_USERS * DIM, vals, rows, cols, xA, nnz);
    gather_add_kernel<<<bblocks, 256, 0, stream>>>(xA, users, pos, neg, uacc, pacc, nacc);

    score_kernel<<<bblocks, 256, 0, stream>>>(uacc, pacc, nacc, sums);
    finalize_kernel<<<1, 1, 0, stream>>>(sums, out);
}

// Round 2
// 645.416 us; speedup vs baseline: 9.5003x; 9.5003x over previous
//
#include <hip/hip_runtime.h>

#define N_USERS 100000
#define N_ITEMS 50000
#define N_NODES (N_USERS + N_ITEMS)
#define DIM 64
#define BATCH 16384
#define SCAN_BS 1024

// ---------------------------------------------------------------------------
// Block-level reduction: wave shfl_xor butterfly, then LDS across waves.
// ---------------------------------------------------------------------------
__device__ __forceinline__ float block_reduce_sum(float v) {
    for (int s = 32; s > 0; s >>= 1) v += __shfl_xor(v, s, 64);
    __shared__ float sm[8];
    int lane = threadIdx.x & 63;
    int wid  = threadIdx.x >> 6;
    if (lane == 0) sm[wid] = v;
    __syncthreads();
    float t = 0.0f;
    if (threadIdx.x == 0) {
        int nw = (blockDim.x + 63) >> 6;
        for (int w = 0; w < nw; ++w) t += sm[w];
    }
    return t;
}

// ---------------------------------------------------------------------------
// Init: acc_0 = gathered layer-0 embeddings + reg_sum from ORIGINAL weights.
// ---------------------------------------------------------------------------
__global__ void init_kernel(const float* __restrict__ uw, const float* __restrict__ iw,
                            const int* __restrict__ users, const int* __restrict__ pos,
                            const int* __restrict__ neg,
                            float* __restrict__ uacc, float* __restrict__ pacc,
                            float* __restrict__ nacc, float* __restrict__ reg_sum) {
    int tid = blockIdx.x * blockDim.x + threadIdx.x;
    int i = tid >> 4;
    int q = tid & 15;
    if (i >= BATCH) return;
    size_t o = (size_t)i * DIM + q * 4;
    float4 u = *(const float4*)(uw + (size_t)users[i] * DIM + q * 4);
    float4 p = *(const float4*)(iw + (size_t)pos[i]   * DIM + q * 4);
    float4 n = *(const float4*)(iw + (size_t)neg[i]   * DIM + q * 4);
    *(float4*)(uacc + o) = u;
    *(float4*)(pacc + o) = p;
    *(float4*)(nacc + o) = n;
    float ss = u.x*u.x + u.y*u.y + u.z*u.z + u.w*u.w
             + p.x*p.x + p.y*p.y + p.z*p.z + p.w*p.w
             + n.x*n.x + n.y*n.y + n.z*n.z + n.w*n.w;
    float bt = block_reduce_sum(ss);
    if (threadIdx.x == 0) unsafeAtomicAdd(reg_sum, bt);
}

// ---------------------------------------------------------------------------
// CSR build: histogram -> 3-phase exclusive scan -> scatter permutation.
// ---------------------------------------------------------------------------
__global__ void hist_kernel(const int* __restrict__ rows, int* __restrict__ counts, int nnz) {
    int e = blockIdx.x * blockDim.x + threadIdx.x;
    if (e < nnz) atomicAdd(&counts[rows[e]], 1);
}

// Per-block (1024) inclusive Hillis-Steele scan -> local exclusive + block totals.
__global__ void scan1_kernel(const int* __restrict__ counts, int* __restrict__ rowptr,
                             int* __restrict__ totals) {
    __shared__ int sm[SCAN_BS];
    int i = blockIdx.x * SCAN_BS + threadIdx.x;
    int v = (i < N_NODES) ? counts[i] : 0;
    sm[threadIdx.x] = v;
    __syncthreads();
    for (int off = 1; off < SCAN_BS; off <<= 1) {
        int t = (threadIdx.x >= off) ? sm[threadIdx.x - off] : 0;
        __syncthreads();
        sm[threadIdx.x] += t;
        __syncthreads();
    }
    if (i < N_NODES) rowptr[i] = sm[threadIdx.x] - v;   // local exclusive
    if (threadIdx.x == SCAN_BS - 1) totals[blockIdx.x] = sm[SCAN_BS - 1];
}

__global__ void scan2_kernel(int* __restrict__ totals, int* __restrict__ rowptr_last, int nb) {
    if (threadIdx.x == 0 && blockIdx.x == 0) {
        int run = 0;
        for (int b = 0; b < nb; ++b) { int t = totals[b]; totals[b] = run; run += t; }
        *rowptr_last = run;   // rowptr[N_NODES] = nnz
    }
}

__global__ void scan3_kernel(int* __restrict__ rowptr, int* __restrict__ cursor,
                             const int* __restrict__ offsets) {
    int i = blockIdx.x * blockDim.x + threadIdx.x;
    if (i < N_NODES) {
        int r = rowptr[i] + offsets[i >> 10];
        rowptr[i] = r;
        cursor[i] = r;
    }
}

__global__ void scatter_kernel(const int* __restrict__ rows, const int* __restrict__ cols,
                               const float* __restrict__ vals, int* __restrict__ cursor,
                               int* __restrict__ perm_col, float* __restrict__ perm_val,
                               int nnz) {
    int e = blockIdx.x * blockDim.x + threadIdx.x;
    if (e < nnz) {
        int p = atomicAdd(&cursor[rows[e]], 1);
        perm_col[p] = cols[e];
        perm_val[p] = vals[e];
    }
}

// ---------------------------------------------------------------------------
// CSR SpMM: one wave per row, register accumulate, one coalesced row write.
// Input is the virtual concat [xu; xi] (for layers 2/3 pass x, x+N_USERS*DIM).
// ---------------------------------------------------------------------------
__global__ void spmm_csr_kernel(const float* __restrict__ xu, const float* __restrict__ xi,
                                const float* __restrict__ pv, const int* __restrict__ pc,
                                const int* __restrict__ rowptr, float* __restrict__ out) {
    int row  = blockIdx.x * 4 + (threadIdx.x >> 6);
    int lane = threadIdx.x & 63;
    if (row >= N_NODES) return;
    int start = rowptr[row];
    int end   = rowptr[row + 1];
    float acc = 0.0f;
    for (int base = start; base < end; base += 64) {
        int n = end - base;
        if (n > 64) n = 64;
        int   cc = (lane < n) ? pc[base + lane] : 0;
        float vv = (lane < n) ? pv[base + lane] : 0.0f;
        int k = 0;
        for (; k + 4 <= n; k += 4) {
            int c0 = __shfl(cc, k,     64), c1 = __shfl(cc, k + 1, 64);
            int c2 = __shfl(cc, k + 2, 64), c3 = __shfl(cc, k + 3, 64);
            float v0 = __shfl(vv, k,     64), v1 = __shfl(vv, k + 1, 64);
            float v2 = __shfl(vv, k + 2, 64), v3 = __shfl(vv, k + 3, 64);
            const float* p0 = (c0 < N_USERS) ? xu + (size_t)c0 * DIM : xi + (size_t)(c0 - N_USERS) * DIM;
            const float* p1 = (c1 < N_USERS) ? xu + (size_t)c1 * DIM : xi + (size_t)(c1 - N_USERS) * DIM;
            const float* p2 = (c2 < N_USERS) ? xu + (size_t)c2 * DIM : xi + (size_t)(c2 - N_USERS) * DIM;
            const float* p3 = (c3 < N_USERS) ? xu + (size_t)c3 * DIM : xi + (size_t)(c3 - N_USERS) * DIM;
            float x0 = p0[lane], x1 = p1[lane], x2 = p2[lane], x3 = p3[lane];
            acc = fmaf(v0, x0, acc);
            acc = fmaf(v1, x1, acc);
            acc = fmaf(v2, x2, acc);
            acc = fmaf(v3, x3, acc);
        }
        for (; k < n; ++k) {
            int   c = __shfl(cc, k, 64);
            float v = __shfl(vv, k, 64);
            const float* p = (c < N_USERS) ? xu + (size_t)c * DIM : xi + (size_t)(c - N_USERS) * DIM;
            acc = fmaf(v, p[lane], acc);
        }
    }
    out[(size_t)row * DIM + lane] = acc;
}

// ---------------------------------------------------------------------------
// Legacy COO atomic SpMM (fallback when ws is too small for CSR buffers).
// ---------------------------------------------------------------------------
__global__ void spmm_atomic_kernel(const float* __restrict__ xu, const float* __restrict__ xi,
                                   const float* __restrict__ vals, const int* __restrict__ rows,
                                   const int* __restrict__ cols,
                                   float* __restrict__ out, int nnz) {
    long long tid = (long long)blockIdx.x * blockDim.x + threadIdx.x;
    int e = (int)(tid >> 4);
    if (e >= nnz) return;
    int q = (int)(tid & 15);
    int r = rows[e];
    int c = cols[e];
    float v = vals[e];
    const float* src = (c < N_USERS) ? (xu + (size_t)c * DIM)
                                     : (xi + (size_t)(c - N_USERS) * DIM);
    float4 x = *(const float4*)(src + q * 4);
    float* dst = out + (size_t)r * DIM + q * 4;
    unsafeAtomicAdd(dst + 0, v * x.x);
    unsafeAtomicAdd(dst + 1, v * x.y);
    unsafeAtomicAdd(dst + 2, v * x.z);
    unsafeAtomicAdd(dst + 3, v * x.w);
}

// ---------------------------------------------------------------------------
// Gather-accumulate a layer's output at the batch rows only.
// ---------------------------------------------------------------------------
__global__ void gather_add_kernel(const float* __restrict__ x,
                                  const int* __restrict__ users, const int* __restrict__ pos,
                                  const int* __restrict__ neg,
                                  float* __restrict__ uacc, float* __restrict__ pacc,
                                  float* __restrict__ nacc) {
    int tid = blockIdx.x * blockDim.x + threadIdx.x;
    int i = tid >> 4;
    int q = tid & 15;
    if (i >= BATCH) return;
    size_t o = (size_t)i * DIM + q * 4;
    float4 a, b;

    a = *(float4*)(uacc + o);
    b = *(const float4*)(x + (size_t)users[i] * DIM + q * 4);
    a.x += b.x; a.y += b.y; a.z += b.z; a.w += b.w;
    *(float4*)(uacc + o) = a;

    a = *(float4*)(pacc + o);
    b = *(const float4*)(x + (size_t)(N_USERS + pos[i]) * DIM + q * 4);
    a.x += b.x; a.y += b.y; a.z += b.z; a.w += b.w;
    *(float4*)(pacc + o) = a;

    a = *(float4*)(nacc + o);
    b = *(const float4*)(x + (size_t)(N_USERS + neg[i]) * DIM + q * 4);
    a.x += b.x; a.y += b.y; a.z += b.z; a.w += b.w;
    *(float4*)(nacc + o) = a;
}

// ---------------------------------------------------------------------------
// Scores + loss partial sum. final = acc/4, so dot scales by 1/16.
// ---------------------------------------------------------------------------
__global__ void score_kernel(const float* __restrict__ uacc, const float* __restrict__ pacc,
                             const float* __restrict__ nacc, float* __restrict__ loss_sum) {
    int tid = blockIdx.x * blockDim.x + threadIdx.x;
    int i = tid >> 4;
    int q = tid & 15;
    float ps = 0.0f, ns = 0.0f;
    if (i < BATCH) {
        size_t o = (size_t)i * DIM + q * 4;
        float4 u = *(const float4*)(uacc + o);
        float4 p = *(const float4*)(pacc + o);
        float4 n = *(const float4*)(nacc + o);
        ps = u.x*p.x + u.y*p.y + u.z*p.z + u.w*p.w;
        ns = u.x*n.x + u.y*n.y + u.z*n.z + u.w*n.w;
    }
    for (int s = 8; s > 0; s >>= 1) {
        ps += __shfl_xor(ps, s, 16);
        ns += __shfl_xor(ns, s, 16);
    }
    float term = 0.0f;
    if (q == 0 && i < BATCH) {
        float d = (ps - ns) * (1.0f / 16.0f);
        float sig = 1.0f / (1.0f + expf(-d));
        term = logf(sig + 1e-8f);
    }
    float bt = block_reduce_sum(term);
    if (threadIdx.x == 0) unsafeAtomicAdd(loss_sum, bt);
}

__global__ void finalize_kernel(const float* __restrict__ sums, float* __restrict__ out) {
    if (threadIdx.x == 0 && blockIdx.x == 0) {
        out[0] = -sums[0] / (float)BATCH;
        out[1] =  sums[1] / (float)BATCH;
    }
}

static inline size_t align256(size_t x) { return (x + 255) & ~(size_t)255; }

extern "C" void kernel_launch(void* const* d_in, const int* in_sizes, int n_in,
                              void* d_out, int out_size, void* d_ws, size_t ws_size,
                              hipStream_t stream) {
    const float* uw   = (const float*)d_in[0];
    const float* iw   = (const float*)d_in[1];
    const float* vals = (const float*)d_in[2];
    const int*   rows = (const int*)d_in[3];
    const int*   cols = (const int*)d_in[4];
    const int*   users = (const int*)d_in[5];
    const int*   pos   = (const int*)d_in[6];
    const int*   neg   = (const int*)d_in[7];
    const int nnz = in_sizes[2];

    char* ws = (char*)d_ws;
    const size_t nodeBytes = (size_t)N_NODES * DIM * sizeof(float);
    const size_t accBytes  = (size_t)BATCH * DIM * sizeof(float);

    size_t off = 0;
    float* xA = (float*)(ws + off);       off += align256(nodeBytes);
    float* xB = (float*)(ws + off);       off += align256(nodeBytes);
    float* uacc = (float*)(ws + off);     off += align256(accBytes);
    float* pacc = (float*)(ws + off);     off += align256(accBytes);
    float* nacc = (float*)(ws + off);     off += align256(accBytes);
    float* sums = (float*)(ws + off);     off += 256;   // [0]=loss, [1]=reg
    size_t csr_base = off;
    float* perm_val = (float*)(ws + off); off += align256((size_t)nnz * sizeof(float));
    int*   perm_col = (int*)(ws + off);   off += align256((size_t)nnz * sizeof(int));
    int*   rowptr   = (int*)(ws + off);   off += align256((size_t)(N_NODES + 1) * sizeof(int));
    int*   cursor   = (int*)(ws + off);   off += align256((size_t)N_NODES * sizeof(int));
    int*   counts   = (int*)(ws + off);   off += align256((size_t)N_NODES * sizeof(int));
    int*   totals   = (int*)(ws + off);   off += align256(((size_t)N_NODES / SCAN_BS + 2) * sizeof(int));
    const bool use_csr = (off <= ws_size);
    (void)csr_base;

    float* out = (float*)d_out;

    const int bthreads = BATCH * 16;
    const int bblocks  = bthreads / 256;
    const int eblocks  = (nnz + 255) / 256;
    const int nb_scan  = (N_NODES + SCAN_BS - 1) / SCAN_BS;

    hipMemsetAsync(sums, 0, 2 * sizeof(float), stream);
    init_kernel<<<bblocks, 256, 0, stream>>>(uw, iw, users, pos, neg, uacc, pacc, nacc, sums + 1);

    if (use_csr) {
        // ---- CSR build (once per launch, used 3x) ----
        hipMemsetAsync(counts, 0, (size_t)N_NODES * sizeof(int), stream);
        hist_kernel<<<eblocks, 256, 0, stream>>>(rows, counts, nnz);
        scan1_kernel<<<nb_scan, SCAN_BS, 0, stream>>>(counts, rowptr, totals);
        scan2_kernel<<<1, 64, 0, stream>>>(totals, rowptr + N_NODES, nb_scan);
        scan3_kernel<<<(N_NODES + 255) / 256, 256, 0, stream>>>(rowptr, cursor, totals);
        scatter_kernel<<<eblocks, 256, 0, stream>>>(rows, cols, vals, cursor, perm_col, perm_val, nnz);

        const int sblocks = (N_NODES + 3) / 4;
        // Layer 1: [uw;iw] -> xA
        spmm_csr_kernel<<<sblocks, 256, 0, stream>>>(uw, iw, perm_val, perm_col, rowptr, xA);
        gather_add_kernel<<<bblocks, 256, 0, stream>>>(xA, users, pos, neg, uacc, pacc, nacc);
        // Layer 2: xA -> xB
        spmm_csr_kernel<<<sblocks, 256, 0, stream>>>(xA, xA + (size_t)N_USERS * DIM, perm_val, perm_col, rowptr, xB);
        gather_add_kernel<<<bblocks, 256, 0, stream>>>(xB, users, pos, neg, uacc, pacc, nacc);
        // Layer 3: xB -> xA
        spmm_csr_kernel<<<sblocks, 256, 0, stream>>>(xB, xB + (size_t)N_USERS * DIM, perm_val, perm_col, rowptr, xA);
        gather_add_kernel<<<bblocks, 256, 0, stream>>>(xA, users, pos, neg, uacc, pacc, nacc);
    } else {
        // ---- Fallback: COO atomic path (round-1) ----
        const long long sthreads = (long long)nnz * 16;
        const int sblocks = (int)((sthreads + 255) / 256);
        hipMemsetAsync(xA, 0, nodeBytes, stream);
        spmm_atomic_kernel<<<sblocks, 256, 0, stream>>>(uw, iw, vals, rows, cols, xA, nnz);
        gather_add_kernel<<<bblocks, 256, 0, stream>>>(xA, users, pos, neg, uacc, pacc, nacc);
        hipMemsetAsync(xB, 0, nodeBytes, stream);
        spmm_atomic_kernel<<<sblocks, 256, 0, stream>>>(xA, xA + (size_t)N_USERS * DIM, vals, rows, cols, xB, nnz);
        gather_add_kernel<<<bblocks, 256, 0, stream>>>(xB, users, pos, neg, uacc, pacc, nacc);
        hipMemsetAsync(xA, 0, nodeBytes, stream);
        spmm_atomic_kernel<<<sblocks, 256, 0, stream>>>(xB, xB + (size_t)N_USERS * DIM, vals, rows, cols, xA, nnz);
        gather_add_kernel<<<bblocks, 256, 0, stream>>>(xA, users, pos, neg, uacc, pacc, nacc);
    }

    score_kernel<<<bblocks, 256, 0, stream>>>(uacc, pacc, nacc, sums);
    finalize_kernel<<<1, 1, 0, stream>>>(sums, out);
}

// Round 3
// 622.044 us; speedup vs baseline: 9.8573x; 1.0376x over previous
//
#include <hip/hip_runtime.h>

#define N_USERS 100000
#define N_ITEMS 50000
#define N_NODES (N_USERS + N_ITEMS)
#define DIM 64
#define BATCH 16384
#define SCAN_BS 1024

struct __align__(8) Pair { int c; float v; };

// ---------------------------------------------------------------------------
// Block-level reduction: wave shfl_xor butterfly, then LDS across waves.
// ---------------------------------------------------------------------------
__device__ __forceinline__ float block_reduce_sum(float v) {
    for (int s = 32; s > 0; s >>= 1) v += __shfl_xor(v, s, 64);
    __shared__ float sm[8];
    int lane = threadIdx.x & 63;
    int wid  = threadIdx.x >> 6;
    if (lane == 0) sm[wid] = v;
    __syncthreads();
    float t = 0.0f;
    if (threadIdx.x == 0) {
        int nw = (blockDim.x + 63) >> 6;
        for (int w = 0; w < nw; ++w) t += sm[w];
    }
    return t;
}

// ---------------------------------------------------------------------------
// Init: acc_0 = gathered layer-0 embeddings + reg_sum from ORIGINAL weights.
// ---------------------------------------------------------------------------
__global__ void init_kernel(const float* __restrict__ uw, const float* __restrict__ iw,
                            const int* __restrict__ users, const int* __restrict__ pos,
                            const int* __restrict__ neg,
                            float* __restrict__ uacc, float* __restrict__ pacc,
                            float* __restrict__ nacc, float* __restrict__ reg_sum) {
    int tid = blockIdx.x * blockDim.x + threadIdx.x;
    int i = tid >> 4;
    int q = tid & 15;
    if (i >= BATCH) return;
    size_t o = (size_t)i * DIM + q * 4;
    float4 u = *(const float4*)(uw + (size_t)users[i] * DIM + q * 4);
    float4 p = *(const float4*)(iw + (size_t)pos[i]   * DIM + q * 4);
    float4 n = *(const float4*)(iw + (size_t)neg[i]   * DIM + q * 4);
    *(float4*)(uacc + o) = u;
    *(float4*)(pacc + o) = p;
    *(float4*)(nacc + o) = n;
    float ss = u.x*u.x + u.y*u.y + u.z*u.z + u.w*u.w
             + p.x*p.x + p.y*p.y + p.z*p.z + p.w*p.w
             + n.x*n.x + n.y*n.y + n.z*n.z + n.w*n.w;
    float bt = block_reduce_sum(ss);
    if (threadIdx.x == 0) unsafeAtomicAdd(reg_sum, bt);
}

// ---------------------------------------------------------------------------
// CSR build: histogram -> 3-phase exclusive scan -> scatter permutation.
// ---------------------------------------------------------------------------
__global__ void hist_kernel(const int* __restrict__ rows, int* __restrict__ counts, int nnz) {
    int e = blockIdx.x * blockDim.x + threadIdx.x;
    if (e < nnz) atomicAdd(&counts[rows[e]], 1);
}

__global__ void scan1_kernel(const int* __restrict__ counts, int* __restrict__ rowptr,
                             int* __restrict__ totals) {
    __shared__ int sm[SCAN_BS];
    int i = blockIdx.x * SCAN_BS + threadIdx.x;
    int v = (i < N_NODES) ? counts[i] : 0;
    sm[threadIdx.x] = v;
    __syncthreads();
    for (int off = 1; off < SCAN_BS; off <<= 1) {
        int t = (threadIdx.x >= off) ? sm[threadIdx.x - off] : 0;
        __syncthreads();
        sm[threadIdx.x] += t;
        __syncthreads();
    }
    if (i < N_NODES) rowptr[i] = sm[threadIdx.x] - v;   // local exclusive
    if (threadIdx.x == SCAN_BS - 1) totals[blockIdx.x] = sm[SCAN_BS - 1];
}

__global__ void scan2_kernel(int* __restrict__ totals, int* __restrict__ rowptr_last, int nb) {
    if (threadIdx.x == 0 && blockIdx.x == 0) {
        int run = 0;
        for (int b = 0; b < nb; ++b) { int t = totals[b]; totals[b] = run; run += t; }
        *rowptr_last = run;   // rowptr[N_NODES] = nnz
    }
}

__global__ void scan3_kernel(int* __restrict__ rowptr, int* __restrict__ cursor,
                             const int* __restrict__ offsets) {
    int i = blockIdx.x * blockDim.x + threadIdx.x;
    if (i < N_NODES) {
        int r = rowptr[i] + offsets[i >> 10];
        rowptr[i] = r;
        cursor[i] = r;
    }
}

__global__ void scatter_kernel(const int* __restrict__ rows, const int* __restrict__ cols,
                               const float* __restrict__ vals, int* __restrict__ cursor,
                               Pair* __restrict__ perm, int nnz) {
    int e = blockIdx.x * blockDim.x + threadIdx.x;
    if (e < nnz) {
        int p = atomicAdd(&cursor[rows[e]], 1);
        Pair pr; pr.c = cols[e]; pr.v = vals[e];
        perm[p] = pr;                       // single 8B random store
    }
}

// ---------------------------------------------------------------------------
// CSR SpMM: one wave per row. 4 groups of 16 lanes; each group handles one
// edge at a time covering all 64 dims via float4 (16B/lane). 4 edges in
// flight per wave, no shfl in the inner loop. Cross-group reduce at the end.
// ---------------------------------------------------------------------------
__global__ void spmm_csr_kernel(const float* __restrict__ xu, const float* __restrict__ xi,
                                const Pair* __restrict__ pe, const int* __restrict__ rowptr,
                                float* __restrict__ out) {
    int row  = blockIdx.x * 4 + (threadIdx.x >> 6);
    if (row >= N_NODES) return;
    int lane = threadIdx.x & 63;
    int g = lane >> 4;        // edge slot 0..3
    int q = lane & 15;        // float4 slot within the 64-dim row
    int start = rowptr[row];
    int end   = rowptr[row + 1];
    float4 acc = make_float4(0.f, 0.f, 0.f, 0.f);
    int e = start + g;
    // 2x unrolled: two edges in flight per group (8 per wave)
    for (; e + 4 < end; e += 8) {
        Pair p0 = pe[e];
        Pair p1 = pe[e + 4];
        const float* s0 = (p0.c < N_USERS) ? xu + (size_t)p0.c * DIM
                                           : xi + (size_t)(p0.c - N_USERS) * DIM;
        const float* s1 = (p1.c < N_USERS) ? xu + (size_t)p1.c * DIM
                                           : xi + (size_t)(p1.c - N_USERS) * DIM;
        float4 x0 = *(const float4*)(s0 + q * 4);
        float4 x1 = *(const float4*)(s1 + q * 4);
        acc.x = fmaf(p0.v, x0.x, acc.x); acc.y = fmaf(p0.v, x0.y, acc.y);
        acc.z = fmaf(p0.v, x0.z, acc.z); acc.w = fmaf(p0.v, x0.w, acc.w);
        acc.x = fmaf(p1.v, x1.x, acc.x); acc.y = fmaf(p1.v, x1.y, acc.y);
        acc.z = fmaf(p1.v, x1.z, acc.z); acc.w = fmaf(p1.v, x1.w, acc.w);
    }
    for (; e < end; e += 4) {
        Pair p = pe[e];
        const float* s = (p.c < N_USERS) ? xu + (size_t)p.c * DIM
                                         : xi + (size_t)(p.c - N_USERS) * DIM;
        float4 x = *(const float4*)(s + q * 4);
        acc.x = fmaf(p.v, x.x, acc.x); acc.y = fmaf(p.v, x.y, acc.y);
        acc.z = fmaf(p.v, x.z, acc.z); acc.w = fmaf(p.v, x.w, acc.w);
    }
    // reduce across the 4 groups (lanes q, q+16, q+32, q+48)
    acc.x += __shfl_xor(acc.x, 16, 64); acc.y += __shfl_xor(acc.y, 16, 64);
    acc.z += __shfl_xor(acc.z, 16, 64); acc.w += __shfl_xor(acc.w, 16, 64);
    acc.x += __shfl_xor(acc.x, 32, 64); acc.y += __shfl_xor(acc.y, 32, 64);
    acc.z += __shfl_xor(acc.z, 32, 64); acc.w += __shfl_xor(acc.w, 32, 64);
    if (g == 0) *(float4*)(out + (size_t)row * DIM + q * 4) = acc;
}

// ---------------------------------------------------------------------------
// Legacy COO atomic SpMM (fallback when ws is too small for CSR buffers).
// ---------------------------------------------------------------------------
__global__ void spmm_atomic_kernel(const float* __restrict__ xu, const float* __restrict__ xi,
                                   const float* __restrict__ vals, const int* __restrict__ rows,
                                   const int* __restrict__ cols,
                                   float* __restrict__ out, int nnz) {
    long long tid = (long long)blockIdx.x * blockDim.x + threadIdx.x;
    int e = (int)(tid >> 4);
    if (e >= nnz) return;
    int q = (int)(tid & 15);
    int r = rows[e];
    int c = cols[e];
    float v = vals[e];
    const float* src = (c < N_USERS) ? (xu + (size_t)c * DIM)
                                     : (xi + (size_t)(c - N_USERS) * DIM);
    float4 x = *(const float4*)(src + q * 4);
    float* dst = out + (size_t)r * DIM + q * 4;
    unsafeAtomicAdd(dst + 0, v * x.x);
    unsafeAtomicAdd(dst + 1, v * x.y);
    unsafeAtomicAdd(dst + 2, v * x.z);
    unsafeAtomicAdd(dst + 3, v * x.w);
}

// ---------------------------------------------------------------------------
// Gather-accumulate a layer's output at the batch rows only.
// ---------------------------------------------------------------------------
__global__ void gather_add_kernel(const float* __restrict__ x,
                                  const int* __restrict__ users, const int* __restrict__ pos,
                                  const int* __restrict__ neg,
                                  float* __restrict__ uacc, float* __restrict__ pacc,
                                  float* __restrict__ nacc) {
    int tid = blockIdx.x * blockDim.x + threadIdx.x;
    int i = tid >> 4;
    int q = tid & 15;
    if (i >= BATCH) return;
    size_t o = (size_t)i * DIM + q * 4;
    float4 a, b;

    a = *(float4*)(uacc + o);
    b = *(const float4*)(x + (size_t)users[i] * DIM + q * 4);
    a.x += b.x; a.y += b.y; a.z += b.z; a.w += b.w;
    *(float4*)(uacc + o) = a;

    a = *(float4*)(pacc + o);
    b = *(const float4*)(x + (size_t)(N_USERS + pos[i]) * DIM + q * 4);
    a.x += b.x; a.y += b.y; a.z += b.z; a.w += b.w;
    *(float4*)(pacc + o) = a;

    a = *(float4*)(nacc + o);
    b = *(const float4*)(x + (size_t)(N_USERS + neg[i]) * DIM + q * 4);
    a.x += b.x; a.y += b.y; a.z += b.z; a.w += b.w;
    *(float4*)(nacc + o) = a;
}

// ---------------------------------------------------------------------------
// Scores + loss partial sum. final = acc/4, so dot scales by 1/16.
// ---------------------------------------------------------------------------
__global__ void score_kernel(const float* __restrict__ uacc, const float* __restrict__ pacc,
                             const float* __restrict__ nacc, float* __restrict__ loss_sum) {
    int tid = blockIdx.x * blockDim.x + threadIdx.x;
    int i = tid >> 4;
    int q = tid & 15;
    float ps = 0.0f, ns = 0.0f;
    if (i < BATCH) {
        size_t o = (size_t)i * DIM + q * 4;
        float4 u = *(const float4*)(uacc + o);
        float4 p = *(const float4*)(pacc + o);
        float4 n = *(const float4*)(nacc + o);
        ps = u.x*p.x + u.y*p.y + u.z*p.z + u.w*p.w;
        ns = u.x*n.x + u.y*n.y + u.z*n.z + u.w*n.w;
    }
    for (int s = 8; s > 0; s >>= 1) {
        ps += __shfl_xor(ps, s, 16);
        ns += __shfl_xor(ns, s, 16);
    }
    float term = 0.0f;
    if (q == 0 && i < BATCH) {
        float d = (ps - ns) * (1.0f / 16.0f);
        float sig = 1.0f / (1.0f + expf(-d));
        term = logf(sig + 1e-8f);
    }
    float bt = block_reduce_sum(term);
    if (threadIdx.x == 0) unsafeAtomicAdd(loss_sum, bt);
}

__global__ void finalize_kernel(const float* __restrict__ sums, float* __restrict__ out) {
    if (threadIdx.x == 0 && blockIdx.x == 0) {
        out[0] = -sums[0] / (float)BATCH;
        out[1] =  sums[1] / (float)BATCH;
    }
}

static inline size_t align256(size_t x) { return (x + 255) & ~(size_t)255; }

extern "C" void kernel_launch(void* const* d_in, const int* in_sizes, int n_in,
                              void* d_out, int out_size, void* d_ws, size_t ws_size,
                              hipStream_t stream) {
    const float* uw   = (const float*)d_in[0];
    const float* iw   = (const float*)d_in[1];
    const float* vals = (const float*)d_in[2];
    const int*   rows = (const int*)d_in[3];
    const int*   cols = (const int*)d_in[4];
    const int*   users = (const int*)d_in[5];
    const int*   pos   = (const int*)d_in[6];
    const int*   neg   = (const int*)d_in[7];
    const int nnz = in_sizes[2];

    char* ws = (char*)d_ws;
    const size_t nodeBytes = (size_t)N_NODES * DIM * sizeof(float);
    const size_t accBytes  = (size_t)BATCH * DIM * sizeof(float);

    size_t off = 0;
    float* xA = (float*)(ws + off);       off += align256(nodeBytes);
    float* xB = (float*)(ws + off);       off += align256(nodeBytes);
    float* uacc = (float*)(ws + off);     off += align256(accBytes);
    float* pacc = (float*)(ws + off);     off += align256(accBytes);
    float* nacc = (float*)(ws + off);     off += align256(accBytes);
    float* sums = (float*)(ws + off);     off += 256;   // [0]=loss, [1]=reg
    Pair*  perm = (Pair*)(ws + off);      off += align256((size_t)nnz * sizeof(Pair));
    int*   rowptr = (int*)(ws + off);     off += align256((size_t)(N_NODES + 1) * sizeof(int));
    int*   cursor = (int*)(ws + off);     off += align256((size_t)N_NODES * sizeof(int));
    int*   counts = (int*)(ws + off);     off += align256((size_t)N_NODES * sizeof(int));
    int*   totals = (int*)(ws + off);     off += align256(((size_t)N_NODES / SCAN_BS + 2) * sizeof(int));
    const bool use_csr = (off <= ws_size);

    float* out = (float*)d_out;

    const int bthreads = BATCH * 16;
    const int bblocks  = bthreads / 256;
    const int eblocks  = (nnz + 255) / 256;
    const int nb_scan  = (N_NODES + SCAN_BS - 1) / SCAN_BS;

    hipMemsetAsync(sums, 0, 2 * sizeof(float), stream);
    init_kernel<<<bblocks, 256, 0, stream>>>(uw, iw, users, pos, neg, uacc, pacc, nacc, sums + 1);

    if (use_csr) {
        // ---- CSR build (once per launch, used 3x) ----
        hipMemsetAsync(counts, 0, (size_t)N_NODES * sizeof(int), stream);
        hist_kernel<<<eblocks, 256, 0, stream>>>(rows, counts, nnz);
        scan1_kernel<<<nb_scan, SCAN_BS, 0, stream>>>(counts, rowptr, totals);
        scan2_kernel<<<1, 64, 0, stream>>>(totals, rowptr + N_NODES, nb_scan);
        scan3_kernel<<<(N_NODES + 255) / 256, 256, 0, stream>>>(rowptr, cursor, totals);
        scatter_kernel<<<eblocks, 256, 0, stream>>>(rows, cols, vals, cursor, perm, nnz);

        const int sblocks = (N_NODES + 3) / 4;
        // Layer 1: [uw;iw] -> xA
        spmm_csr_kernel<<<sblocks, 256, 0, stream>>>(uw, iw, perm, rowptr, xA);
        gather_add_kernel<<<bblocks, 256, 0, stream>>>(xA, users, pos, neg, uacc, pacc, nacc);
        // Layer 2: xA -> xB
        spmm_csr_kernel<<<sblocks, 256, 0, stream>>>(xA, xA + (size_t)N_USERS * DIM, perm, rowptr, xB);
        gather_add_kernel<<<bblocks, 256, 0, stream>>>(xB, users, pos, neg, uacc, pacc, nacc);
        // Layer 3: xB -> xA
        spmm_csr_kernel<<<sblocks, 256, 0, stream>>>(xB, xB + (size_t)N_USERS * DIM, perm, rowptr, xA);
        gather_add_kernel<<<bblocks, 256, 0, stream>>>(xA, users, pos, neg, uacc, pacc, nacc);
    } else {
        // ---- Fallback: COO atomic path ----
        const long long sthreads = (long long)nnz * 16;
        const int sblocks = (int)((sthreads + 255) / 256);
        hipMemsetAsync(xA, 0, nodeBytes, stream);
        spmm_atomic_kernel<<<sblocks, 256, 0, stream>>>(uw, iw, vals, rows, cols, xA, nnz);
        gather_add_kernel<<<bblocks, 256, 0, stream>>>(xA, users, pos, neg, uacc, pacc, nacc);
        hipMemsetAsync(xB, 0, nodeBytes, stream);
        spmm_atomic_kernel<<<sblocks, 256, 0, stream>>>(xA, xA + (size_t)N_USERS * DIM, vals, rows, cols, xB, nnz);
        gather_add_kernel<<<bblocks, 256, 0, stream>>>(xB, users, pos, neg, uacc, pacc, nacc);
        hipMemsetAsync(xA, 0, nodeBytes, stream);
        spmm_atomic_kernel<<<sblocks, 256, 0, stream>>>(xB, xB + (size_t)N_USERS * DIM, vals, rows, cols, xA, nnz);
        gather_add_kernel<<<bblocks, 256, 0, stream>>>(xA, users, pos, neg, uacc, pacc, nacc);
    }

    score_kernel<<<bblocks, 256, 0, stream>>>(uacc, pacc, nacc, sums);
    finalize_kernel<<<1, 1, 0, stream>>>(sums, out);
}

// Round 4
// 437.608 us; speedup vs baseline: 14.0117x; 1.4215x over previous
//
#include <hip/hip_runtime.h>

#define N_USERS 100000
#define N_ITEMS 50000
#define N_NODES (N_USERS + N_ITEMS)
#define DIM 64
#define BATCH 16384
#define RPB 512                      // rows per bucket
#define NB ((N_NODES + RPB - 1) / RPB)   // 293 buckets
#define K3_E 16                      // edges per thread in hist/scatter tiles

struct __align__(8) Pair { int c; float v; };

// ---------------------------------------------------------------------------
// Block-level reduction: wave shfl_xor butterfly, then LDS across waves.
// ---------------------------------------------------------------------------
__device__ __forceinline__ float block_reduce_sum(float v) {
    for (int s = 32; s > 0; s >>= 1) v += __shfl_xor(v, s, 64);
    __shared__ float sm[8];
    int lane = threadIdx.x & 63;
    int wid  = threadIdx.x >> 6;
    if (lane == 0) sm[wid] = v;
    __syncthreads();
    float t = 0.0f;
    if (threadIdx.x == 0) {
        int nw = (blockDim.x + 63) >> 6;
        for (int w = 0; w < nw; ++w) t += sm[w];
    }
    return t;
}

// ---------------------------------------------------------------------------
// Init: acc_0 = gathered layer-0 embeddings + reg_sum from ORIGINAL weights.
// ---------------------------------------------------------------------------
__global__ void init_kernel(const float* __restrict__ uw, const float* __restrict__ iw,
                            const int* __restrict__ users, const int* __restrict__ pos,
                            const int* __restrict__ neg,
                            float* __restrict__ uacc, float* __restrict__ pacc,
                            float* __restrict__ nacc, float* __restrict__ reg_sum) {
    int tid = blockIdx.x * blockDim.x + threadIdx.x;
    int i = tid >> 4;
    int q = tid & 15;
    if (i >= BATCH) return;
    size_t o = (size_t)i * DIM + q * 4;
    float4 u = *(const float4*)(uw + (size_t)users[i] * DIM + q * 4);
    float4 p = *(const float4*)(iw + (size_t)pos[i]   * DIM + q * 4);
    float4 n = *(const float4*)(iw + (size_t)neg[i]   * DIM + q * 4);
    *(float4*)(uacc + o) = u;
    *(float4*)(pacc + o) = p;
    *(float4*)(nacc + o) = n;
    float ss = u.x*u.x + u.y*u.y + u.z*u.z + u.w*u.w
             + p.x*p.x + p.y*p.y + p.z*p.z + p.w*p.w
             + n.x*n.x + n.y*n.y + n.z*n.z + n.w*n.w;
    float bt = block_reduce_sum(ss);
    if (threadIdx.x == 0) unsafeAtomicAdd(reg_sum, bt);
}

// ---------------------------------------------------------------------------
// k1: coarse-bucket histogram, LDS-privatized (293 buckets).
// ---------------------------------------------------------------------------
__global__ void bucket_hist_kernel(const int* __restrict__ rows, int* __restrict__ bcnt,
                                   int nnz) {
    __shared__ int h[NB];
    for (int b = threadIdx.x; b < NB; b += blockDim.x) h[b] = 0;
    __syncthreads();
    long long tile = (long long)blockIdx.x * (256 * K3_E);
    #pragma unroll
    for (int j = 0; j < K3_E; ++j) {
        long long e = tile + threadIdx.x + j * 256;
        if (e < nnz) atomicAdd(&h[rows[e] >> 9], 1);
    }
    __syncthreads();
    for (int b = threadIdx.x; b < NB; b += blockDim.x)
        if (h[b]) atomicAdd(&bcnt[b], h[b]);
}

// ---------------------------------------------------------------------------
// k2: 1-block exclusive scan of bucket counts -> bases + cursors.
// ---------------------------------------------------------------------------
__global__ void bucket_scan_kernel(const int* __restrict__ bcnt, int* __restrict__ bbase,
                                   int* __restrict__ bcursor, int* __restrict__ rowptr,
                                   int nnz) {
    __shared__ int sm[512];
    int t = threadIdx.x;
    int v = (t < NB) ? bcnt[t] : 0;
    sm[t] = v;
    __syncthreads();
    for (int off = 1; off < 512; off <<= 1) {
        int tmp = (t >= off) ? sm[t - off] : 0;
        __syncthreads();
        sm[t] += tmp;
        __syncthreads();
    }
    int excl = sm[t] - v;
    if (t < NB) { bbase[t] = excl; bcursor[t] = excl; }
    if (t == 511) bbase[NB] = sm[511];
    if (t == 0) rowptr[N_NODES] = nnz;
}

// ---------------------------------------------------------------------------
// k3: binned scatter. Each block claims per-bucket runs (1 global atomic per
// block x bucket), then writes ~14-edge contiguous runs into bucket regions.
// ---------------------------------------------------------------------------
__global__ void binned_scatter_kernel(const int* __restrict__ rows, const int* __restrict__ cols,
                                      const float* __restrict__ vals, int* __restrict__ bcursor,
                                      Pair* __restrict__ bcv, unsigned short* __restrict__ blrow,
                                      int nnz) {
    __shared__ int hist[NB];
    __shared__ int rbase[NB];
    int tid = threadIdx.x;
    long long tile = (long long)blockIdx.x * (256 * K3_E);
    for (int b = tid; b < NB; b += 256) hist[b] = 0;
    __syncthreads();
    int er[K3_E];
    #pragma unroll
    for (int j = 0; j < K3_E; ++j) {
        long long e = tile + tid + j * 256;
        if (e < nnz) {
            int r = rows[e];
            er[j] = r;
            atomicAdd(&hist[r >> 9], 1);
        } else er[j] = -1;
    }
    __syncthreads();
    for (int b = tid; b < NB; b += 256) {
        int c = hist[b];
        rbase[b] = c ? atomicAdd(&bcursor[b], c) : 0;
        hist[b] = 0;   // reuse as local rank cursor
    }
    __syncthreads();
    #pragma unroll
    for (int j = 0; j < K3_E; ++j) {
        long long e = tile + tid + j * 256;
        if (er[j] >= 0) {
            int r = er[j];
            int b = r >> 9;
            int rk = atomicAdd(&hist[b], 1);
            int dst = rbase[b] + rk;
            Pair p; p.c = cols[e]; p.v = vals[e];
            bcv[dst] = p;
            blrow[dst] = (unsigned short)(r & (RPB - 1));
        }
    }
}

// ---------------------------------------------------------------------------
// k4: per-bucket counting sort in LDS. One block per bucket; emits final CSR
// perm for its contiguous region + rowptr for its 512 rows. All perm writes
// stay in one XCD's L2 -> line-dense writeback.
// ---------------------------------------------------------------------------
__global__ void bucket_sort_kernel(const Pair* __restrict__ bcv,
                                   const unsigned short* __restrict__ blrow,
                                   const int* __restrict__ bbase,
                                   int* __restrict__ rowptr, Pair* __restrict__ perm) {
    __shared__ int rh[RPB];
    __shared__ int sc[RPB];
    int blk = blockIdx.x;
    int t = threadIdx.x;        // 512 threads
    int base = bbase[blk];
    int cnt  = bbase[blk + 1] - base;
    rh[t] = 0;
    __syncthreads();
    for (int i = t; i < cnt; i += 512) atomicAdd(&rh[blrow[base + i]], 1);
    __syncthreads();
    int v = rh[t];
    sc[t] = v;
    __syncthreads();
    for (int off = 1; off < 512; off <<= 1) {
        int tmp = (t >= off) ? sc[t - off] : 0;
        __syncthreads();
        sc[t] += tmp;
        __syncthreads();
    }
    int excl = sc[t] - v;
    int g = blk * RPB + t;
    if (g < N_NODES) rowptr[g] = base + excl;
    rh[t] = excl;               // reuse as per-row cursor
    __syncthreads();
    for (int i = t; i < cnt; i += 512) {
        int r = blrow[base + i];
        int rk = atomicAdd(&rh[r], 1);
        perm[base + rk] = bcv[base + i];
    }
}

// ---------------------------------------------------------------------------
// CSR SpMM: one wave per row; 4 groups of 16 lanes, float4 per lane, 2-edge
// unroll per group (8 edges in flight per wave), cross-group shfl reduce.
// ---------------------------------------------------------------------------
__global__ void spmm_csr_kernel(const float* __restrict__ xu, const float* __restrict__ xi,
                                const Pair* __restrict__ pe, const int* __restrict__ rowptr,
                                float* __restrict__ out) {
    int row  = blockIdx.x * 4 + (threadIdx.x >> 6);
    if (row >= N_NODES) return;
    int lane = threadIdx.x & 63;
    int g = lane >> 4;
    int q = lane & 15;
    int start = rowptr[row];
    int end   = rowptr[row + 1];
    float4 acc = make_float4(0.f, 0.f, 0.f, 0.f);
    int e = start + g;
    for (; e + 4 < end; e += 8) {
        Pair p0 = pe[e];
        Pair p1 = pe[e + 4];
        const float* s0 = (p0.c < N_USERS) ? xu + (size_t)p0.c * DIM
                                           : xi + (size_t)(p0.c - N_USERS) * DIM;
        const float* s1 = (p1.c < N_USERS) ? xu + (size_t)p1.c * DIM
                                           : xi + (size_t)(p1.c - N_USERS) * DIM;
        float4 x0 = *(const float4*)(s0 + q * 4);
        float4 x1 = *(const float4*)(s1 + q * 4);
        acc.x = fmaf(p0.v, x0.x, acc.x); acc.y = fmaf(p0.v, x0.y, acc.y);
        acc.z = fmaf(p0.v, x0.z, acc.z); acc.w = fmaf(p0.v, x0.w, acc.w);
        acc.x = fmaf(p1.v, x1.x, acc.x); acc.y = fmaf(p1.v, x1.y, acc.y);
        acc.z = fmaf(p1.v, x1.z, acc.z); acc.w = fmaf(p1.v, x1.w, acc.w);
    }
    for (; e < end; e += 4) {
        Pair p = pe[e];
        const float* s = (p.c < N_USERS) ? xu + (size_t)p.c * DIM
                                         : xi + (size_t)(p.c - N_USERS) * DIM;
        float4 x = *(const float4*)(s + q * 4);
        acc.x = fmaf(p.v, x.x, acc.x); acc.y = fmaf(p.v, x.y, acc.y);
        acc.z = fmaf(p.v, x.z, acc.z); acc.w = fmaf(p.v, x.w, acc.w);
    }
    acc.x += __shfl_xor(acc.x, 16, 64); acc.y += __shfl_xor(acc.y, 16, 64);
    acc.z += __shfl_xor(acc.z, 16, 64); acc.w += __shfl_xor(acc.w, 16, 64);
    acc.x += __shfl_xor(acc.x, 32, 64); acc.y += __shfl_xor(acc.y, 32, 64);
    acc.z += __shfl_xor(acc.z, 32, 64); acc.w += __shfl_xor(acc.w, 32, 64);
    if (g == 0) *(float4*)(out + (size_t)row * DIM + q * 4) = acc;
}

// ---------------------------------------------------------------------------
// Legacy COO atomic SpMM (fallback when ws is too small for CSR buffers).
// ---------------------------------------------------------------------------
__global__ void spmm_atomic_kernel(const float* __restrict__ xu, const float* __restrict__ xi,
                                   const float* __restrict__ vals, const int* __restrict__ rows,
                                   const int* __restrict__ cols,
                                   float* __restrict__ out, int nnz) {
    long long tid = (long long)blockIdx.x * blockDim.x + threadIdx.x;
    int e = (int)(tid >> 4);
    if (e >= nnz) return;
    int q = (int)(tid & 15);
    int r = rows[e];
    int c = cols[e];
    float v = vals[e];
    const float* src = (c < N_USERS) ? (xu + (size_t)c * DIM)
                                     : (xi + (size_t)(c - N_USERS) * DIM);
    float4 x = *(const float4*)(src + q * 4);
    float* dst = out + (size_t)r * DIM + q * 4;
    unsafeAtomicAdd(dst + 0, v * x.x);
    unsafeAtomicAdd(dst + 1, v * x.y);
    unsafeAtomicAdd(dst + 2, v * x.z);
    unsafeAtomicAdd(dst + 3, v * x.w);
}

// ---------------------------------------------------------------------------
// Gather-accumulate a layer's output at the batch rows only.
// ---------------------------------------------------------------------------
__global__ void gather_add_kernel(const float* __restrict__ x,
                                  const int* __restrict__ users, const int* __restrict__ pos,
                                  const int* __restrict__ neg,
                                  float* __restrict__ uacc, float* __restrict__ pacc,
                                  float* __restrict__ nacc) {
    int tid = blockIdx.x * blockDim.x + threadIdx.x;
    int i = tid >> 4;
    int q = tid & 15;
    if (i >= BATCH) return;
    size_t o = (size_t)i * DIM + q * 4;
    float4 a, b;

    a = *(float4*)(uacc + o);
    b = *(const float4*)(x + (size_t)users[i] * DIM + q * 4);
    a.x += b.x; a.y += b.y; a.z += b.z; a.w += b.w;
    *(float4*)(uacc + o) = a;

    a = *(float4*)(pacc + o);
    b = *(const float4*)(x + (size_t)(N_USERS + pos[i]) * DIM + q * 4);
    a.x += b.x; a.y += b.y; a.z += b.z; a.w += b.w;
    *(float4*)(pacc + o) = a;

    a = *(float4*)(nacc + o);
    b = *(const float4*)(x + (size_t)(N_USERS + neg[i]) * DIM + q * 4);
    a.x += b.x; a.y += b.y; a.z += b.z; a.w += b.w;
    *(float4*)(nacc + o) = a;
}

// ---------------------------------------------------------------------------
// Scores + loss partial sum. final = acc/4, so dot scales by 1/16.
// ---------------------------------------------------------------------------
__global__ void score_kernel(const float* __restrict__ uacc, const float* __restrict__ pacc,
                             const float* __restrict__ nacc, float* __restrict__ loss_sum) {
    int tid = blockIdx.x * blockDim.x + threadIdx.x;
    int i = tid >> 4;
    int q = tid & 15;
    float ps = 0.0f, ns = 0.0f;
    if (i < BATCH) {
        size_t o = (size_t)i * DIM + q * 4;
        float4 u = *(const float4*)(uacc + o);
        float4 p = *(const float4*)(pacc + o);
        float4 n = *(const float4*)(nacc + o);
        ps = u.x*p.x + u.y*p.y + u.z*p.z + u.w*p.w;
        ns = u.x*n.x + u.y*n.y + u.z*n.z + u.w*n.w;
    }
    for (int s = 8; s > 0; s >>= 1) {
        ps += __shfl_xor(ps, s, 16);
        ns += __shfl_xor(ns, s, 16);
    }
    float term = 0.0f;
    if (q == 0 && i < BATCH) {
        float d = (ps - ns) * (1.0f / 16.0f);
        float sig = 1.0f / (1.0f + expf(-d));
        term = logf(sig + 1e-8f);
    }
    float bt = block_reduce_sum(term);
    if (threadIdx.x == 0) unsafeAtomicAdd(loss_sum, bt);
}

__global__ void finalize_kernel(const float* __restrict__ sums, float* __restrict__ out) {
    if (threadIdx.x == 0 && blockIdx.x == 0) {
        out[0] = -sums[0] / (float)BATCH;
        out[1] =  sums[1] / (float)BATCH;
    }
}

static inline size_t align256(size_t x) { return (x + 255) & ~(size_t)255; }

extern "C" void kernel_launch(void* const* d_in, const int* in_sizes, int n_in,
                              void* d_out, int out_size, void* d_ws, size_t ws_size,
                              hipStream_t stream) {
    const float* uw   = (const float*)d_in[0];
    const float* iw   = (const float*)d_in[1];
    const float* vals = (const float*)d_in[2];
    const int*   rows = (const int*)d_in[3];
    const int*   cols = (const int*)d_in[4];
    const int*   users = (const int*)d_in[5];
    const int*   pos   = (const int*)d_in[6];
    const int*   neg   = (const int*)d_in[7];
    const int nnz = in_sizes[2];

    char* ws = (char*)d_ws;
    const size_t nodeBytes = (size_t)N_NODES * DIM * sizeof(float);
    const size_t accBytes  = (size_t)BATCH * DIM * sizeof(float);

    size_t off = 0;
    float* xA = (float*)(ws + off);       off += align256(nodeBytes);
    float* xB = (float*)(ws + off);       off += align256(nodeBytes);
    float* uacc = (float*)(ws + off);     off += align256(accBytes);
    float* pacc = (float*)(ws + off);     off += align256(accBytes);
    float* nacc = (float*)(ws + off);     off += align256(accBytes);
    float* sums = (float*)(ws + off);     off += 256;   // [0]=loss, [1]=reg
    Pair*  perm = (Pair*)(ws + off);      off += align256((size_t)nnz * sizeof(Pair));
    int*   rowptr = (int*)(ws + off);     off += align256((size_t)(N_NODES + 1) * sizeof(int));
    int*   bcnt   = (int*)(ws + off);     off += align256((size_t)NB * sizeof(int));
    int*   bbase  = (int*)(ws + off);     off += align256((size_t)(NB + 1) * sizeof(int));
    int*   bcursor= (int*)(ws + off);     off += align256((size_t)NB * sizeof(int));
    const bool use_csr = (off <= ws_size);

    // bucketed staging arrays alias xA (dead until SpMM layer 1 writes it)
    Pair*           bcv   = (Pair*)xA;
    unsigned short* blrow = (unsigned short*)((char*)xA + align256((size_t)nnz * sizeof(Pair)));

    float* out = (float*)d_out;

    const int bthreads = BATCH * 16;
    const int bblocks  = bthreads / 256;
    const int tblocks  = (nnz + 256 * K3_E - 1) / (256 * K3_E);

    hipMemsetAsync(sums, 0, 2 * sizeof(float), stream);
    init_kernel<<<bblocks, 256, 0, stream>>>(uw, iw, users, pos, neg, uacc, pacc, nacc, sums + 1);

    if (use_csr) {
        // ---- CSR build: bucket hist -> scan -> binned scatter -> LDS sort ----
        hipMemsetAsync(bcnt, 0, (size_t)NB * sizeof(int), stream);
        bucket_hist_kernel<<<tblocks, 256, 0, stream>>>(rows, bcnt, nnz);
        bucket_scan_kernel<<<1, 512, 0, stream>>>(bcnt, bbase, bcursor, rowptr, nnz);
        binned_scatter_kernel<<<tblocks, 256, 0, stream>>>(rows, cols, vals, bcursor, bcv, blrow, nnz);
        bucket_sort_kernel<<<NB, 512, 0, stream>>>(bcv, blrow, bbase, rowptr, perm);

        const int sblocks = (N_NODES + 3) / 4;
        // Layer 1: [uw;iw] -> xA   (bcv/blrow dead from here on)
        spmm_csr_kernel<<<sblocks, 256, 0, stream>>>(uw, iw, perm, rowptr, xA);
        gather_add_kernel<<<bblocks, 256, 0, stream>>>(xA, users, pos, neg, uacc, pacc, nacc);
        // Layer 2: xA -> xB
        spmm_csr_kernel<<<sblocks, 256, 0, stream>>>(xA, xA + (size_t)N_USERS * DIM, perm, rowptr, xB);
        gather_add_kernel<<<bblocks, 256, 0, stream>>>(xB, users, pos, neg, uacc, pacc, nacc);
        // Layer 3: xB -> xA
        spmm_csr_kernel<<<sblocks, 256, 0, stream>>>(xB, xB + (size_t)N_USERS * DIM, perm, rowptr, xA);
        gather_add_kernel<<<bblocks, 256, 0, stream>>>(xA, users, pos, neg, uacc, pacc, nacc);
    } else {
        // ---- Fallback: COO atomic path ----
        const long long sthreads = (long long)nnz * 16;
        const int sblocks = (int)((sthreads + 255) / 256);
        hipMemsetAsync(xA, 0, nodeBytes, stream);
        spmm_atomic_kernel<<<sblocks, 256, 0, stream>>>(uw, iw, vals, rows, cols, xA, nnz);
        gather_add_kernel<<<bblocks, 256, 0, stream>>>(xA, users, pos, neg, uacc, pacc, nacc);
        hipMemsetAsync(xB, 0, nodeBytes, stream);
        spmm_atomic_kernel<<<sblocks, 256, 0, stream>>>(xA, xA + (size_t)N_USERS * DIM, vals, rows, cols, xB, nnz);
        gather_add_kernel<<<bblocks, 256, 0, stream>>>(xB, users, pos, neg, uacc, pacc, nacc);
        hipMemsetAsync(xA, 0, nodeBytes, stream);
        spmm_atomic_kernel<<<sblocks, 256, 0, stream>>>(xB, xB + (size_t)N_USERS * DIM, vals, rows, cols, xA, nnz);
        gather_add_kernel<<<bblocks, 256, 0, stream>>>(xA, users, pos, neg, uacc, pacc, nacc);
    }

    score_kernel<<<bblocks, 256, 0, stream>>>(uacc, pacc, nacc, sums);
    finalize_kernel<<<1, 1, 0, stream>>>(sums, out);
}

// Round 5
// 328.823 us; speedup vs baseline: 18.6473x; 1.3308x over previous
//
#include <hip/hip_runtime.h>

#define N_USERS 100000
#define N_ITEMS 50000
#define N_NODES (N_USERS + N_ITEMS)
#define DIM 64
#define BATCH 16384
#define RPB 512                          // rows per bucket
#define NB ((N_NODES + RPB - 1) / RPB)   // 293 buckets
#define HP 296                           // padded hist stride (bank stagger)
#define TILE_E 4096                      // edges per build block (512 thr x 8)

struct __align__(8) Pair { int c; float v; };

// f32 -> bf16 round-to-nearest-even (finite inputs)
__device__ __forceinline__ unsigned short f2bf(float f) {
    unsigned u = __float_as_uint(f);
    return (unsigned short)((u + 0x7FFF + ((u >> 16) & 1)) >> 16);
}
__device__ __forceinline__ float bflo(unsigned u) { return __uint_as_float(u << 16); }
__device__ __forceinline__ float bfhi(unsigned u) { return __uint_as_float(u & 0xFFFF0000u); }

// ---------------------------------------------------------------------------
__device__ __forceinline__ float block_reduce_sum(float v) {
    for (int s = 32; s > 0; s >>= 1) v += __shfl_xor(v, s, 64);
    __shared__ float sm[8];
    int lane = threadIdx.x & 63;
    int wid  = threadIdx.x >> 6;
    if (lane == 0) sm[wid] = v;
    __syncthreads();
    float t = 0.0f;
    if (threadIdx.x == 0) {
        int nw = (blockDim.x + 63) >> 6;
        for (int w = 0; w < nw; ++w) t += sm[w];
    }
    return t;
}

// ---------------------------------------------------------------------------
// Convert concat [uw;iw] f32 -> bf16 once (layer-1 SpMM input).
// ---------------------------------------------------------------------------
__global__ void convert_kernel(const float* __restrict__ uw, const float* __restrict__ iw,
                               unsigned short* __restrict__ xbf) {
    size_t base = ((size_t)blockIdx.x * 256 + threadIdx.x) * 8;
    if (base >= (size_t)N_NODES * DIM) return;
    const float* src = (base < (size_t)N_USERS * DIM) ? uw + base
                                                      : iw + (base - (size_t)N_USERS * DIM);
    float4 a = ((const float4*)src)[0];
    float4 b = ((const float4*)src)[1];
    uint4 o;
    o.x = (unsigned)f2bf(a.x) | ((unsigned)f2bf(a.y) << 16);
    o.y = (unsigned)f2bf(a.z) | ((unsigned)f2bf(a.w) << 16);
    o.z = (unsigned)f2bf(b.x) | ((unsigned)f2bf(b.y) << 16);
    o.w = (unsigned)f2bf(b.z) | ((unsigned)f2bf(b.w) << 16);
    *(uint4*)(xbf + base) = o;
}

// ---------------------------------------------------------------------------
// Init: acc_0 = gathered layer-0 embeddings + reg_sum from ORIGINAL weights.
// ---------------------------------------------------------------------------
__global__ void init_kernel(const float* __restrict__ uw, const float* __restrict__ iw,
                            const int* __restrict__ users, const int* __restrict__ pos,
                            const int* __restrict__ neg,
                            float* __restrict__ uacc, float* __restrict__ pacc,
                            float* __restrict__ nacc, float* __restrict__ reg_sum) {
    int tid = blockIdx.x * blockDim.x + threadIdx.x;
    int i = tid >> 4;
    int q = tid & 15;
    if (i >= BATCH) return;
    size_t o = (size_t)i * DIM + q * 4;
    float4 u = *(const float4*)(uw + (size_t)users[i] * DIM + q * 4);
    float4 p = *(const float4*)(iw + (size_t)pos[i]   * DIM + q * 4);
    float4 n = *(const float4*)(iw + (size_t)neg[i]   * DIM + q * 4);
    *(float4*)(uacc + o) = u;
    *(float4*)(pacc + o) = p;
    *(float4*)(nacc + o) = n;
    float ss = u.x*u.x + u.y*u.y + u.z*u.z + u.w*u.w
             + p.x*p.x + p.y*p.y + p.z*p.z + p.w*p.w
             + n.x*n.x + n.y*n.y + n.z*n.z + n.w*n.w;
    float bt = block_reduce_sum(ss);
    if (threadIdx.x == 0) unsafeAtomicAdd(reg_sum, bt);
}

// ---------------------------------------------------------------------------
// k1: coarse-bucket histogram, per-wave LDS replication (8 waves).
// ---------------------------------------------------------------------------
__global__ void bucket_hist_kernel(const int* __restrict__ rows, int* __restrict__ bcnt,
                                   int nnz) {
    __shared__ int h[8][HP];
    int t = threadIdx.x, w = t >> 6;
    for (int i = t; i < 8 * HP; i += 512) ((int*)h)[i] = 0;
    __syncthreads();
    long long tile = (long long)blockIdx.x * TILE_E;
    #pragma unroll
    for (int j = 0; j < 8; ++j) {
        long long e = tile + t + j * 512;
        if (e < nnz) atomicAdd(&h[w][rows[e] >> 9], 1);
    }
    __syncthreads();
    for (int b = t; b < NB; b += 512) {
        int s = 0;
        #pragma unroll
        for (int w2 = 0; w2 < 8; ++w2) s += h[w2][b];
        if (s) atomicAdd(&bcnt[b], s);
    }
}

// ---------------------------------------------------------------------------
// k2: 1-block exclusive scan of bucket counts -> bases + cursors.
// ---------------------------------------------------------------------------
__global__ void bucket_scan_kernel(const int* __restrict__ bcnt, int* __restrict__ bbase,
                                   int* __restrict__ bcursor, int* __restrict__ rowptr,
                                   int nnz) {
    __shared__ int sm[512];
    int t = threadIdx.x;
    int v = (t < NB) ? bcnt[t] : 0;
    sm[t] = v;
    __syncthreads();
    for (int off = 1; off < 512; off <<= 1) {
        int tmp = (t >= off) ? sm[t - off] : 0;
        __syncthreads();
        sm[t] += tmp;
        __syncthreads();
    }
    int excl = sm[t] - v;
    if (t < NB) { bbase[t] = excl; bcursor[t] = excl; }
    if (t == 511) bbase[NB] = sm[511];
    if (t == 0) rowptr[N_NODES] = nnz;
}

// ---------------------------------------------------------------------------
// k3: binned scatter, per-wave hist; single packed 8B store per edge.
// packed c-field = col | (row_local << 18)   (col < 2^18, row_local < 512)
// ---------------------------------------------------------------------------
__global__ void binned_scatter_kernel(const int* __restrict__ rows, const int* __restrict__ cols,
                                      const float* __restrict__ vals, int* __restrict__ bcursor,
                                      Pair* __restrict__ bcv, int nnz) {
    __shared__ int h[8][HP];
    int t = threadIdx.x, w = t >> 6;
    for (int i = t; i < 8 * HP; i += 512) ((int*)h)[i] = 0;
    __syncthreads();
    long long tile = (long long)blockIdx.x * TILE_E;
    int er[8];
    #pragma unroll
    for (int j = 0; j < 8; ++j) {
        long long e = tile + t + j * 512;
        if (e < nnz) {
            int r = rows[e];
            er[j] = r;
            atomicAdd(&h[w][r >> 9], 1);
        } else er[j] = -1;
    }
    __syncthreads();
    // convert per-wave counts to absolute write bases (one global atomic/bucket)
    for (int b = t; b < NB; b += 512) {
        int cw[8], tot = 0;
        #pragma unroll
        for (int w2 = 0; w2 < 8; ++w2) { cw[w2] = h[w2][b]; tot += cw[w2]; }
        int base = tot ? atomicAdd(&bcursor[b], tot) : 0;
        #pragma unroll
        for (int w2 = 0; w2 < 8; ++w2) { h[w2][b] = base; base += cw[w2]; }
    }
    __syncthreads();
    #pragma unroll
    for (int j = 0; j < 8; ++j) {
        if (er[j] >= 0) {
            long long e = tile + t + j * 512;
            int r = er[j];
            int dst = atomicAdd(&h[w][r >> 9], 1);
            Pair p;
            p.c = cols[e] | ((r & (RPB - 1)) << 18);
            p.v = vals[e];
            bcv[dst] = p;
        }
    }
}

// ---------------------------------------------------------------------------
// k4: per-bucket counting sort in LDS -> final CSR perm + rowptr.
// ---------------------------------------------------------------------------
__global__ void bucket_sort_kernel(const Pair* __restrict__ bcv,
                                   const int* __restrict__ bbase,
                                   int* __restrict__ rowptr, Pair* __restrict__ perm) {
    __shared__ int rh[RPB];
    __shared__ int sc[RPB];
    int blk = blockIdx.x;
    int t = threadIdx.x;        // 512 threads
    int base = bbase[blk];
    int cnt  = bbase[blk + 1] - base;
    rh[t] = 0;
    __syncthreads();
    for (int i = t; i < cnt; i += 512)
        atomicAdd(&rh[(unsigned)bcv[base + i].c >> 18], 1);
    __syncthreads();
    int v = rh[t];
    sc[t] = v;
    __syncthreads();
    for (int off = 1; off < 512; off <<= 1) {
        int tmp = (t >= off) ? sc[t - off] : 0;
        __syncthreads();
        sc[t] += tmp;
        __syncthreads();
    }
    int excl = sc[t] - v;
    int g = blk * RPB + t;
    if (g < N_NODES) rowptr[g] = base + excl;
    rh[t] = excl;               // per-row cursor
    __syncthreads();
    for (int i = t; i < cnt; i += 512) {
        Pair p = bcv[base + i];
        int r = (unsigned)p.c >> 18;
        int rk = atomicAdd(&rh[r], 1);
        p.c &= 0x3FFFF;
        perm[base + rk] = p;
    }
}

// ---------------------------------------------------------------------------
// CSR SpMM, bf16 in / bf16 out (f32 accumulate). One wave per row; 8 groups
// of 8 lanes, each lane covers 8 dims via one 16B load; 2-edge unroll gives
// 16 edges in flight per wave. Cross-group shfl reduce; 16B row stores.
// ---------------------------------------------------------------------------
__global__ void spmm_csr_bf16_kernel(const unsigned short* __restrict__ xbf,
                                     const Pair* __restrict__ pe,
                                     const int* __restrict__ rowptr,
                                     unsigned short* __restrict__ out) {
    int row  = blockIdx.x * 4 + (threadIdx.x >> 6);
    if (row >= N_NODES) return;
    int lane = threadIdx.x & 63;
    int g = lane >> 3;        // edge slot 0..7
    int q = lane & 7;         // 8-dim chunk
    int start = rowptr[row];
    int end   = rowptr[row + 1];
    float a0=0,a1=0,a2=0,a3=0,a4=0,a5=0,a6=0,a7=0;
    int e = start + g;
    for (; e + 8 < end; e += 16) {
        Pair p0 = pe[e];
        Pair p1 = pe[e + 8];
        uint4 x0 = *(const uint4*)(xbf + (size_t)p0.c * DIM + q * 8);
        uint4 x1 = *(const uint4*)(xbf + (size_t)p1.c * DIM + q * 8);
        a0 = fmaf(p0.v, bflo(x0.x), a0); a1 = fmaf(p0.v, bfhi(x0.x), a1);
        a2 = fmaf(p0.v, bflo(x0.y), a2); a3 = fmaf(p0.v, bfhi(x0.y), a3);
        a4 = fmaf(p0.v, bflo(x0.z), a4); a5 = fmaf(p0.v, bfhi(x0.z), a5);
        a6 = fmaf(p0.v, bflo(x0.w), a6); a7 = fmaf(p0.v, bfhi(x0.w), a7);
        a0 = fmaf(p1.v, bflo(x1.x), a0); a1 = fmaf(p1.v, bfhi(x1.x), a1);
        a2 = fmaf(p1.v, bflo(x1.y), a2); a3 = fmaf(p1.v, bfhi(x1.y), a3);
        a4 = fmaf(p1.v, bflo(x1.z), a4); a5 = fmaf(p1.v, bfhi(x1.z), a5);
        a6 = fmaf(p1.v, bflo(x1.w), a6); a7 = fmaf(p1.v, bfhi(x1.w), a7);
    }
    for (; e < end; e += 8) {
        Pair p = pe[e];
        uint4 x = *(const uint4*)(xbf + (size_t)p.c * DIM + q * 8);
        a0 = fmaf(p.v, bflo(x.x), a0); a1 = fmaf(p.v, bfhi(x.x), a1);
        a2 = fmaf(p.v, bflo(x.y), a2); a3 = fmaf(p.v, bfhi(x.y), a3);
        a4 = fmaf(p.v, bflo(x.z), a4); a5 = fmaf(p.v, bfhi(x.z), a5);
        a6 = fmaf(p.v, bflo(x.w), a6); a7 = fmaf(p.v, bfhi(x.w), a7);
    }
    #pragma unroll
    for (int s = 8; s <= 32; s <<= 1) {
        a0 += __shfl_xor(a0, s, 64); a1 += __shfl_xor(a1, s, 64);
        a2 += __shfl_xor(a2, s, 64); a3 += __shfl_xor(a3, s, 64);
        a4 += __shfl_xor(a4, s, 64); a5 += __shfl_xor(a5, s, 64);
        a6 += __shfl_xor(a6, s, 64); a7 += __shfl_xor(a7, s, 64);
    }
    if (g == 0) {
        uint4 o;
        o.x = (unsigned)f2bf(a0) | ((unsigned)f2bf(a1) << 16);
        o.y = (unsigned)f2bf(a2) | ((unsigned)f2bf(a3) << 16);
        o.z = (unsigned)f2bf(a4) | ((unsigned)f2bf(a5) << 16);
        o.w = (unsigned)f2bf(a6) | ((unsigned)f2bf(a7) << 16);
        *(uint4*)(out + (size_t)row * DIM + q * 8) = o;
    }
}

// ---------------------------------------------------------------------------
// Legacy COO atomic SpMM (fallback when ws is too small for CSR buffers).
// ---------------------------------------------------------------------------
__global__ void spmm_atomic_kernel(const float* __restrict__ xu, const float* __restrict__ xi,
                                   const float* __restrict__ vals, const int* __restrict__ rows,
                                   const int* __restrict__ cols,
                                   float* __restrict__ out, int nnz) {
    long long tid = (long long)blockIdx.x * blockDim.x + threadIdx.x;
    int e = (int)(tid >> 4);
    if (e >= nnz) return;
    int q = (int)(tid & 15);
    int r = rows[e];
    int c = cols[e];
    float v = vals[e];
    const float* src = (c < N_USERS) ? (xu + (size_t)c * DIM)
                                     : (xi + (size_t)(c - N_USERS) * DIM);
    float4 x = *(const float4*)(src + q * 4);
    float* dst = out + (size_t)r * DIM + q * 4;
    unsafeAtomicAdd(dst + 0, v * x.x);
    unsafeAtomicAdd(dst + 1, v * x.y);
    unsafeAtomicAdd(dst + 2, v * x.z);
    unsafeAtomicAdd(dst + 3, v * x.w);
}

// ---------------------------------------------------------------------------
// Gather-accumulate a layer's bf16 output at the batch rows only.
// ---------------------------------------------------------------------------
__global__ void gather_add_bf16_kernel(const unsigned short* __restrict__ x,
                                       const int* __restrict__ users, const int* __restrict__ pos,
                                       const int* __restrict__ neg,
                                       float* __restrict__ uacc, float* __restrict__ pacc,
                                       float* __restrict__ nacc) {
    int tid = blockIdx.x * blockDim.x + threadIdx.x;
    int i = tid >> 4;
    int q = tid & 15;
    if (i >= BATCH) return;
    size_t o = (size_t)i * DIM + q * 4;
    float4 a;
    uint2 u;

    a = *(float4*)(uacc + o);
    u = *(const uint2*)(x + (size_t)users[i] * DIM + q * 4);
    a.x += bflo(u.x); a.y += bfhi(u.x); a.z += bflo(u.y); a.w += bfhi(u.y);
    *(float4*)(uacc + o) = a;

    a = *(float4*)(pacc + o);
    u = *(const uint2*)(x + (size_t)(N_USERS + pos[i]) * DIM + q * 4);
    a.x += bflo(u.x); a.y += bfhi(u.x); a.z += bflo(u.y); a.w += bfhi(u.y);
    *(float4*)(pacc + o) = a;

    a = *(float4*)(nacc + o);
    u = *(const uint2*)(x + (size_t)(N_USERS + neg[i]) * DIM + q * 4);
    a.x += bflo(u.x); a.y += bfhi(u.x); a.z += bflo(u.y); a.w += bfhi(u.y);
    *(float4*)(nacc + o) = a;
}

// f32 gather-add (fallback path)
__global__ void gather_add_kernel(const float* __restrict__ x,
                                  const int* __restrict__ users, const int* __restrict__ pos,
                                  const int* __restrict__ neg,
                                  float* __restrict__ uacc, float* __restrict__ pacc,
                                  float* __restrict__ nacc) {
    int tid = blockIdx.x * blockDim.x + threadIdx.x;
    int i = tid >> 4;
    int q = tid & 15;
    if (i >= BATCH) return;
    size_t o = (size_t)i * DIM + q * 4;
    float4 a, b;
    a = *(float4*)(uacc + o);
    b = *(const float4*)(x + (size_t)users[i] * DIM + q * 4);
    a.x += b.x; a.y += b.y; a.z += b.z; a.w += b.w;
    *(float4*)(uacc + o) = a;
    a = *(float4*)(pacc + o);
    b = *(const float4*)(x + (size_t)(N_USERS + pos[i]) * DIM + q * 4);
    a.x += b.x; a.y += b.y; a.z += b.z; a.w += b.w;
    *(float4*)(pacc + o) = a;
    a = *(float4*)(nacc + o);
    b = *(const float4*)(x + (size_t)(N_USERS + neg[i]) * DIM + q * 4);
    a.x += b.x; a.y += b.y; a.z += b.z; a.w += b.w;
    *(float4*)(nacc + o) = a;
}

// ---------------------------------------------------------------------------
// Scores + loss partial sum. final = acc/4, so dot scales by 1/16.
// ---------------------------------------------------------------------------
__global__ void score_kernel(const float* __restrict__ uacc, const float* __restrict__ pacc,
                             const float* __restrict__ nacc, float* __restrict__ loss_sum) {
    int tid = blockIdx.x * blockDim.x + threadIdx.x;
    int i = tid >> 4;
    int q = tid & 15;
    float ps = 0.0f, ns = 0.0f;
    if (i < BATCH) {
        size_t o = (size_t)i * DIM + q * 4;
        float4 u = *(const float4*)(uacc + o);
        float4 p = *(const float4*)(pacc + o);
        float4 n = *(const float4*)(nacc + o);
        ps = u.x*p.x + u.y*p.y + u.z*p.z + u.w*p.w;
        ns = u.x*n.x + u.y*n.y + u.z*n.z + u.w*n.w;
    }
    for (int s = 8; s > 0; s >>= 1) {
        ps += __shfl_xor(ps, s, 16);
        ns += __shfl_xor(ns, s, 16);
    }
    float term = 0.0f;
    if (q == 0 && i < BATCH) {
        float d = (ps - ns) * (1.0f / 16.0f);
        float sig = 1.0f / (1.0f + expf(-d));
        term = logf(sig + 1e-8f);
    }
    float bt = block_reduce_sum(term);
    if (threadIdx.x == 0) unsafeAtomicAdd(loss_sum, bt);
}

__global__ void finalize_kernel(const float* __restrict__ sums, float* __restrict__ out) {
    if (threadIdx.x == 0 && blockIdx.x == 0) {
        out[0] = -sums[0] / (float)BATCH;
        out[1] =  sums[1] / (float)BATCH;
    }
}

static inline size_t align256(size_t x) { return (x + 255) & ~(size_t)255; }

extern "C" void kernel_launch(void* const* d_in, const int* in_sizes, int n_in,
                              void* d_out, int out_size, void* d_ws, size_t ws_size,
                              hipStream_t stream) {
    const float* uw   = (const float*)d_in[0];
    const float* iw   = (const float*)d_in[1];
    const float* vals = (const float*)d_in[2];
    const int*   rows = (const int*)d_in[3];
    const int*   cols = (const int*)d_in[4];
    const int*   users = (const int*)d_in[5];
    const int*   pos   = (const int*)d_in[6];
    const int*   neg   = (const int*)d_in[7];
    const int nnz = in_sizes[2];

    char* ws = (char*)d_ws;
    const size_t nodeBytes = (size_t)N_NODES * DIM * sizeof(float);       // 38.4 MB
    const size_t bfBytes   = (size_t)N_NODES * DIM * sizeof(unsigned short); // 19.2 MB
    const size_t accBytes  = (size_t)BATCH * DIM * sizeof(float);

    size_t off = 0;
    char*  nodeReg = ws + off;            off += align256(2 * nodeBytes);   // 76.8 MB region
    float* uacc = (float*)(ws + off);     off += align256(accBytes);
    float* pacc = (float*)(ws + off);     off += align256(accBytes);
    float* nacc = (float*)(ws + off);     off += align256(accBytes);
    float* sums = (float*)(ws + off);     off += 256;   // [0]=loss, [1]=reg
    Pair*  perm = (Pair*)(ws + off);      off += align256((size_t)nnz * sizeof(Pair));
    int*   rowptr = (int*)(ws + off);     off += align256((size_t)(N_NODES + 1) * sizeof(int));
    int*   bcnt   = (int*)(ws + off);     off += align256((size_t)NB * sizeof(int));
    int*   bbase  = (int*)(ws + off);     off += align256((size_t)(NB + 1) * sizeof(int));
    int*   bcursor= (int*)(ws + off);     off += align256((size_t)NB * sizeof(int));
    const bool fits_alias = (3 * align256(bfBytes) + (size_t)nnz * sizeof(Pair)) <= 2 * nodeBytes;
    const bool use_csr = (off <= ws_size) && fits_alias && (N_NODES < (1 << 18));

    // bf16 node buffers + bcv staging all carved from the node region
    unsigned short* xb0 = (unsigned short*)nodeReg;
    unsigned short* xb1 = (unsigned short*)(nodeReg + align256(bfBytes));
    unsigned short* xb2 = (unsigned short*)(nodeReg + 2 * align256(bfBytes));
    Pair*           bcv = (Pair*)(nodeReg + 3 * align256(bfBytes));
    // fallback f32 views of the same region
    float* xA = (float*)nodeReg;
    float* xB = (float*)(nodeReg + nodeBytes);

    float* out = (float*)d_out;

    const int bthreads = BATCH * 16;
    const int bblocks  = bthreads / 256;
    const int tblocks  = (nnz + TILE_E - 1) / TILE_E;
    const int cblocks  = (int)(((size_t)N_NODES * DIM / 8 + 255) / 256);

    hipMemsetAsync(sums, 0, 2 * sizeof(float), stream);
    init_kernel<<<bblocks, 256, 0, stream>>>(uw, iw, users, pos, neg, uacc, pacc, nacc, sums + 1);

    if (use_csr) {
        // ---- CSR build: bucket hist -> scan -> binned scatter -> LDS sort ----
        hipMemsetAsync(bcnt, 0, (size_t)NB * sizeof(int), stream);
        convert_kernel<<<cblocks, 256, 0, stream>>>(uw, iw, xb0);
        bucket_hist_kernel<<<tblocks, 512, 0, stream>>>(rows, bcnt, nnz);
        bucket_scan_kernel<<<1, 512, 0, stream>>>(bcnt, bbase, bcursor, rowptr, nnz);
        binned_scatter_kernel<<<tblocks, 512, 0, stream>>>(rows, cols, vals, bcursor, bcv, nnz);
        bucket_sort_kernel<<<NB, 512, 0, stream>>>(bcv, bbase, rowptr, perm);

        const int sblocks = (N_NODES + 3) / 4;
        // Layer 1: xb0 -> xb1
        spmm_csr_bf16_kernel<<<sblocks, 256, 0, stream>>>(xb0, perm, rowptr, xb1);
        gather_add_bf16_kernel<<<bblocks, 256, 0, stream>>>(xb1, users, pos, neg, uacc, pacc, nacc);
        // Layer 2: xb1 -> xb2
        spmm_csr_bf16_kernel<<<sblocks, 256, 0, stream>>>(xb1, perm, rowptr, xb2);
        gather_add_bf16_kernel<<<bblocks, 256, 0, stream>>>(xb2, users, pos, neg, uacc, pacc, nacc);
        // Layer 3: xb2 -> xb0 (xb0 dead after layer 1)
        spmm_csr_bf16_kernel<<<sblocks, 256, 0, stream>>>(xb2, perm, rowptr, xb0);
        gather_add_bf16_kernel<<<bblocks, 256, 0, stream>>>(xb0, users, pos, neg, uacc, pacc, nacc);
    } else {
        // ---- Fallback: COO atomic path (f32) ----
        const long long sthreads = (long long)nnz * 16;
        const int sblocks = (int)((sthreads + 255) / 256);
        hipMemsetAsync(xA, 0, nodeBytes, stream);
        spmm_atomic_kernel<<<sblocks, 256, 0, stream>>>(uw, iw, vals, rows, cols, xA, nnz);
        gather_add_kernel<<<bblocks, 256, 0, stream>>>(xA, users, pos, neg, uacc, pacc, nacc);
        hipMemsetAsync(xB, 0, nodeBytes, stream);
        spmm_atomic_kernel<<<sblocks, 256, 0, stream>>>(xA, xA + (size_t)N_USERS * DIM, vals, rows, cols, xB, nnz);
        gather_add_kernel<<<bblocks, 256, 0, stream>>>(xB, users, pos, neg, uacc, pacc, nacc);
        hipMemsetAsync(xA, 0, nodeBytes, stream);
        spmm_atomic_kernel<<<sblocks, 256, 0, stream>>>(xB, xB + (size_t)N_USERS * DIM, vals, rows, cols, xA, nnz);
        gather_add_kernel<<<bblocks, 256, 0, stream>>>(xA, users, pos, neg, uacc, pacc, nacc);
    }

    score_kernel<<<bblocks, 256, 0, stream>>>(uacc, pacc, nacc, sums);
    finalize_kernel<<<1, 1, 0, stream>>>(sums, out);
}

// Round 7
// 322.467 us; speedup vs baseline: 19.0148x; 1.0197x over previous
//
#include <hip/hip_runtime.h>

#define N_USERS 100000
#define N_ITEMS 50000
#define N_NODES (N_USERS + N_ITEMS)
#define DIM 64
#define BATCH 16384
#define RPB 512                          // rows per bucket
#define NB ((N_NODES + RPB - 1) / RPB)   // 293 buckets
#define HP 296                           // padded hist stride (bank stagger)
#define TILE_E 4096                      // edges per build block (512 thr x 8)

struct __align__(8) Pair { int c; float v; };

// ---- f16 helpers ----------------------------------------------------------
__device__ __forceinline__ float h2f(unsigned short s) {
    union { unsigned short u; _Float16 h; } c; c.u = s; return (float)c.h;
}
// pack two f32 -> one dword of two f16 (round toward zero), via raw VOP2
__device__ __forceinline__ unsigned pkh(float a, float b) {
    unsigned r;
    asm("v_cvt_pkrtz_f16_f32 %0, %1, %2" : "=v"(r) : "v"(a), "v"(b));
    return r;
}
// acc += f16(lo/hi half of xu) * vf   — no unpack instruction needed
#define MIX_LO(acc, xu, vf) \
    asm("v_fma_mix_f32 %0, %1, %2, %0 op_sel:[0,0,0] op_sel_hi:[1,0,0]" \
        : "+v"(acc) : "v"(xu), "v"(vf))
#define MIX_HI(acc, xu, vf) \
    asm("v_fma_mix_f32 %0, %1, %2, %0 op_sel:[1,0,0] op_sel_hi:[1,0,0]" \
        : "+v"(acc) : "v"(xu), "v"(vf))

// ---------------------------------------------------------------------------
__device__ __forceinline__ float block_reduce_sum(float v) {
    for (int s = 32; s > 0; s >>= 1) v += __shfl_xor(v, s, 64);
    __shared__ float sm[8];
    int lane = threadIdx.x & 63;
    int wid  = threadIdx.x >> 6;
    if (lane == 0) sm[wid] = v;
    __syncthreads();
    float t = 0.0f;
    if (threadIdx.x == 0) {
        int nw = (blockDim.x + 63) >> 6;
        for (int w = 0; w < nw; ++w) t += sm[w];
    }
    return t;
}

// ---------------------------------------------------------------------------
// Convert concat [uw;iw] f32 -> f16 once (layer-1 SpMM input).
// ---------------------------------------------------------------------------
__global__ void convert_kernel(const float* __restrict__ uw, const float* __restrict__ iw,
                               unsigned short* __restrict__ xh) {
    size_t base = ((size_t)blockIdx.x * 256 + threadIdx.x) * 8;
    if (base >= (size_t)N_NODES * DIM) return;
    const float* src = (base < (size_t)N_USERS * DIM) ? uw + base
                                                      : iw + (base - (size_t)N_USERS * DIM);
    float4 a = ((const float4*)src)[0];
    float4 b = ((const float4*)src)[1];
    uint4 o;
    o.x = pkh(a.x, a.y);
    o.y = pkh(a.z, a.w);
    o.z = pkh(b.x, b.y);
    o.w = pkh(b.z, b.w);
    *(uint4*)(xh + base) = o;
}

// ---------------------------------------------------------------------------
// Init: acc_0 = gathered layer-0 embeddings + reg_sum from ORIGINAL weights.
// ---------------------------------------------------------------------------
__global__ void init_kernel(const float* __restrict__ uw, const float* __restrict__ iw,
                            const int* __restrict__ users, const int* __restrict__ pos,
                            const int* __restrict__ neg,
                            float* __restrict__ uacc, float* __restrict__ pacc,
                            float* __restrict__ nacc, float* __restrict__ reg_sum) {
    int tid = blockIdx.x * blockDim.x + threadIdx.x;
    int i = tid >> 4;
    int q = tid & 15;
    if (i >= BATCH) return;
    size_t o = (size_t)i * DIM + q * 4;
    float4 u = *(const float4*)(uw + (size_t)users[i] * DIM + q * 4);
    float4 p = *(const float4*)(iw + (size_t)pos[i]   * DIM + q * 4);
    float4 n = *(const float4*)(iw + (size_t)neg[i]   * DIM + q * 4);
    *(float4*)(uacc + o) = u;
    *(float4*)(pacc + o) = p;
    *(float4*)(nacc + o) = n;
    float ss = u.x*u.x + u.y*u.y + u.z*u.z + u.w*u.w
             + p.x*p.x + p.y*p.y + p.z*p.z + p.w*p.w
             + n.x*n.x + n.y*n.y + n.z*n.z + n.w*n.w;
    float bt = block_reduce_sum(ss);
    if (threadIdx.x == 0) unsafeAtomicAdd(reg_sum, bt);
}

// ---------------------------------------------------------------------------
// k1: coarse-bucket histogram, per-wave LDS replication (8 waves).
// ---------------------------------------------------------------------------
__global__ void bucket_hist_kernel(const int* __restrict__ rows, int* __restrict__ bcnt,
                                   int nnz) {
    __shared__ int h[8][HP];
    int t = threadIdx.x, w = t >> 6;
    for (int i = t; i < 8 * HP; i += 512) ((int*)h)[i] = 0;
    __syncthreads();
    long long tile = (long long)blockIdx.x * TILE_E;
    #pragma unroll
    for (int j = 0; j < 8; ++j) {
        long long e = tile + t + j * 512;
        if (e < nnz) atomicAdd(&h[w][rows[e] >> 9], 1);
    }
    __syncthreads();
    for (int b = t; b < NB; b += 512) {
        int s = 0;
        #pragma unroll
        for (int w2 = 0; w2 < 8; ++w2) s += h[w2][b];
        if (s) atomicAdd(&bcnt[b], s);
    }
}

// ---------------------------------------------------------------------------
// k2: 1-block exclusive scan of bucket counts -> bases + cursors.
// ---------------------------------------------------------------------------
__global__ void bucket_scan_kernel(const int* __restrict__ bcnt, int* __restrict__ bbase,
                                   int* __restrict__ bcursor, int* __restrict__ rowptr,
                                   int nnz) {
    __shared__ int sm[512];
    int t = threadIdx.x;
    int v = (t < NB) ? bcnt[t] : 0;
    sm[t] = v;
    __syncthreads();
    for (int off = 1; off < 512; off <<= 1) {
        int tmp = (t >= off) ? sm[t - off] : 0;
        __syncthreads();
        sm[t] += tmp;
        __syncthreads();
    }
    int excl = sm[t] - v;
    if (t < NB) { bbase[t] = excl; bcursor[t] = excl; }
    if (t == 511) bbase[NB] = sm[511];
    if (t == 0) rowptr[N_NODES] = nnz;
}

// ---------------------------------------------------------------------------
// k3: binned scatter, per-wave hist; single packed 8B store per edge.
// packed c-field = col | (row_local << 18)   (col < 2^18, row_local < 512)
// ---------------------------------------------------------------------------
__global__ void binned_scatter_kernel(const int* __restrict__ rows, const int* __restrict__ cols,
                                      const float* __restrict__ vals, int* __restrict__ bcursor,
                                      Pair* __restrict__ bcv, int nnz) {
    __shared__ int h[8][HP];
    int t = threadIdx.x, w = t >> 6;
    for (int i = t; i < 8 * HP; i += 512) ((int*)h)[i] = 0;
    __syncthreads();
    long long tile = (long long)blockIdx.x * TILE_E;
    int er[8];
    #pragma unroll
    for (int j = 0; j < 8; ++j) {
        long long e = tile + t + j * 512;
        if (e < nnz) {
            int r = rows[e];
            er[j] = r;
            atomicAdd(&h[w][r >> 9], 1);
        } else er[j] = -1;
    }
    __syncthreads();
    for (int b = t; b < NB; b += 512) {
        int cw[8], tot = 0;
        #pragma unroll
        for (int w2 = 0; w2 < 8; ++w2) { cw[w2] = h[w2][b]; tot += cw[w2]; }
        int base = tot ? atomicAdd(&bcursor[b], tot) : 0;
        #pragma unroll
        for (int w2 = 0; w2 < 8; ++w2) { h[w2][b] = base; base += cw[w2]; }
    }
    __syncthreads();
    #pragma unroll
    for (int j = 0; j < 8; ++j) {
        if (er[j] >= 0) {
            long long e = tile + t + j * 512;
            int r = er[j];
            int dst = atomicAdd(&h[w][r >> 9], 1);
            Pair p;
            p.c = cols[e] | ((r & (RPB - 1)) << 18);
            p.v = vals[e];
            bcv[dst] = p;
        }
    }
}

// ---------------------------------------------------------------------------
// k4: per-bucket counting sort in LDS -> final CSR perm + rowptr.
// Phase-1 hist uses 8-way wave replication to cut LDS atomic contention.
// ---------------------------------------------------------------------------
__global__ void bucket_sort_kernel(const Pair* __restrict__ bcv,
                                   const int* __restrict__ bbase,
                                   int* __restrict__ rowptr, Pair* __restrict__ perm) {
    __shared__ int rh8[8][RPB + 8];
    __shared__ int rh[RPB];
    __shared__ int sc[RPB];
    int blk = blockIdx.x;
    int t = threadIdx.x;        // 512 threads
    int w = t >> 6;
    int base = bbase[blk];
    int cnt  = bbase[blk + 1] - base;
    for (int i = t; i < 8 * (RPB + 8); i += 512) ((int*)rh8)[i] = 0;
    __syncthreads();
    for (int i = t; i < cnt; i += 512)
        atomicAdd(&rh8[w][(unsigned)bcv[base + i].c >> 18], 1);
    __syncthreads();
    int v = 0;
    #pragma unroll
    for (int w2 = 0; w2 < 8; ++w2) v += rh8[w2][t];
    sc[t] = v;
    __syncthreads();
    for (int off = 1; off < 512; off <<= 1) {
        int tmp = (t >= off) ? sc[t - off] : 0;
        __syncthreads();
        sc[t] += tmp;
        __syncthreads();
    }
    int excl = sc[t] - v;
    int g = blk * RPB + t;
    if (g < N_NODES) rowptr[g] = base + excl;
    rh[t] = excl;               // per-row cursor
    __syncthreads();
    for (int i = t; i < cnt; i += 512) {
        Pair p = bcv[base + i];
        int r = (unsigned)p.c >> 18;
        int rk = atomicAdd(&rh[r], 1);
        p.c &= 0x3FFFF;
        perm[base + rk] = p;
    }
}

// ---------------------------------------------------------------------------
// CSR SpMM, f16 in / f16 out (f32 accumulate via v_fma_mix). One wave per
// row; 8 groups of 8 lanes, each lane covers 8 dims with one 16B load;
// 2-edge unroll -> 16 edges in flight per wave. Cross-group shfl reduce.
// ---------------------------------------------------------------------------
__global__ void spmm_csr_f16_kernel(const unsigned short* __restrict__ xh,
                                    const Pair* __restrict__ pe,
                                    const int* __restrict__ rowptr,
                                    unsigned short* __restrict__ out) {
    int row  = blockIdx.x * 4 + (threadIdx.x >> 6);
    if (row >= N_NODES) return;
    int lane = threadIdx.x & 63;
    int g = lane >> 3;        // edge slot 0..7
    int q = lane & 7;         // 8-dim chunk
    int start = rowptr[row];
    int end   = rowptr[row + 1];
    float a0=0,a1=0,a2=0,a3=0,a4=0,a5=0,a6=0,a7=0;
    int e = start + g;
    for (; e + 8 < end; e += 16) {
        Pair p0 = pe[e];
        Pair p1 = pe[e + 8];
        uint4 x0 = *(const uint4*)(xh + (size_t)p0.c * DIM + q * 8);
        uint4 x1 = *(const uint4*)(xh + (size_t)p1.c * DIM + q * 8);
        MIX_LO(a0, x0.x, p0.v); MIX_HI(a1, x0.x, p0.v);
        MIX_LO(a2, x0.y, p0.v); MIX_HI(a3, x0.y, p0.v);
        MIX_LO(a4, x0.z, p0.v); MIX_HI(a5, x0.z, p0.v);
        MIX_LO(a6, x0.w, p0.v); MIX_HI(a7, x0.w, p0.v);
        MIX_LO(a0, x1.x, p1.v); MIX_HI(a1, x1.x, p1.v);
        MIX_LO(a2, x1.y, p1.v); MIX_HI(a3, x1.y, p1.v);
        MIX_LO(a4, x1.z, p1.v); MIX_HI(a5, x1.z, p1.v);
        MIX_LO(a6, x1.w, p1.v); MIX_HI(a7, x1.w, p1.v);
    }
    for (; e < end; e += 8) {
        Pair p = pe[e];
        uint4 x = *(const uint4*)(xh + (size_t)p.c * DIM + q * 8);
        MIX_LO(a0, x.x, p.v); MIX_HI(a1, x.x, p.v);
        MIX_LO(a2, x.y, p.v); MIX_HI(a3, x.y, p.v);
        MIX_LO(a4, x.z, p.v); MIX_HI(a5, x.z, p.v);
        MIX_LO(a6, x.w, p.v); MIX_HI(a7, x.w, p.v);
    }
    #pragma unroll
    for (int s = 8; s <= 32; s <<= 1) {
        a0 += __shfl_xor(a0, s, 64); a1 += __shfl_xor(a1, s, 64);
        a2 += __shfl_xor(a2, s, 64); a3 += __shfl_xor(a3, s, 64);
        a4 += __shfl_xor(a4, s, 64); a5 += __shfl_xor(a5, s, 64);
        a6 += __shfl_xor(a6, s, 64); a7 += __shfl_xor(a7, s, 64);
    }
    if (g == 0) {
        uint4 o;
        o.x = pkh(a0, a1);
        o.y = pkh(a2, a3);
        o.z = pkh(a4, a5);
        o.w = pkh(a6, a7);
        *(uint4*)(out + (size_t)row * DIM + q * 8) = o;
    }
}

// ---------------------------------------------------------------------------
// Legacy COO atomic SpMM (fallback when ws is too small for CSR buffers).
// ---------------------------------------------------------------------------
__global__ void spmm_atomic_kernel(const float* __restrict__ xu, const float* __restrict__ xi,
                                   const float* __restrict__ vals, const int* __restrict__ rows,
                                   const int* __restrict__ cols,
                                   float* __restrict__ out, int nnz) {
    long long tid = (long long)blockIdx.x * blockDim.x + threadIdx.x;
    int e = (int)(tid >> 4);
    if (e >= nnz) return;
    int q = (int)(tid & 15);
    int r = rows[e];
    int c = cols[e];
    float v = vals[e];
    const float* src = (c < N_USERS) ? (xu + (size_t)c * DIM)
                                     : (xi + (size_t)(c - N_USERS) * DIM);
    float4 x = *(const float4*)(src + q * 4);
    float* dst = out + (size_t)r * DIM + q * 4;
    unsafeAtomicAdd(dst + 0, v * x.x);
    unsafeAtomicAdd(dst + 1, v * x.y);
    unsafeAtomicAdd(dst + 2, v * x.z);
    unsafeAtomicAdd(dst + 3, v * x.w);
}

// ---------------------------------------------------------------------------
// Gather-accumulate a layer's f16 output at the batch rows only.
// ---------------------------------------------------------------------------
__global__ void gather_add_f16_kernel(const unsigned short* __restrict__ x,
                                      const int* __restrict__ users, const int* __restrict__ pos,
                                      const int* __restrict__ neg,
                                      float* __restrict__ uacc, float* __restrict__ pacc,
                                      float* __restrict__ nacc) {
    int tid = blockIdx.x * blockDim.x + threadIdx.x;
    int i = tid >> 4;
    int q = tid & 15;
    if (i >= BATCH) return;
    size_t o = (size_t)i * DIM + q * 4;
    float4 a;
    uint2 u;

    a = *(float4*)(uacc + o);
    u = *(const uint2*)(x + (size_t)users[i] * DIM + q * 4);
    a.x += h2f(u.x & 0xffff); a.y += h2f(u.x >> 16);
    a.z += h2f(u.y & 0xffff); a.w += h2f(u.y >> 16);
    *(float4*)(uacc + o) = a;

    a = *(float4*)(pacc + o);
    u = *(const uint2*)(x + (size_t)(N_USERS + pos[i]) * DIM + q * 4);
    a.x += h2f(u.x & 0xffff); a.y += h2f(u.x >> 16);
    a.z += h2f(u.y & 0xffff); a.w += h2f(u.y >> 16);
    *(float4*)(pacc + o) = a;

    a = *(float4*)(nacc + o);
    u = *(const uint2*)(x + (size_t)(N_USERS + neg[i]) * DIM + q * 4);
    a.x += h2f(u.x & 0xffff); a.y += h2f(u.x >> 16);
    a.z += h2f(u.y & 0xffff); a.w += h2f(u.y >> 16);
    *(float4*)(nacc + o) = a;
}

// ---------------------------------------------------------------------------
// Fused layer-3 gather + BPR score. Adds the final layer contribution in
// registers (no acc write-back) and computes the loss partial sums.
// final = acc/4, so dot scales by 1/16.
// ---------------------------------------------------------------------------
__global__ void gather_score_kernel(const unsigned short* __restrict__ x,
                                    const int* __restrict__ users, const int* __restrict__ pos,
                                    const int* __restrict__ neg,
                                    const float* __restrict__ uacc, const float* __restrict__ pacc,
                                    const float* __restrict__ nacc, float* __restrict__ loss_sum) {
    int tid = blockIdx.x * blockDim.x + threadIdx.x;
    int i = tid >> 4;
    int q = tid & 15;
    float ps = 0.0f, ns = 0.0f;
    if (i < BATCH) {
        size_t o = (size_t)i * DIM + q * 4;
        float4 u = *(const float4*)(uacc + o);
        float4 p = *(const float4*)(pacc + o);
        float4 n = *(const float4*)(nacc + o);
        uint2 t;
        t = *(const uint2*)(x + (size_t)users[i] * DIM + q * 4);
        u.x += h2f(t.x & 0xffff); u.y += h2f(t.x >> 16);
        u.z += h2f(t.y & 0xffff); u.w += h2f(t.y >> 16);
        t = *(const uint2*)(x + (size_t)(N_USERS + pos[i]) * DIM + q * 4);
        p.x += h2f(t.x & 0xffff); p.y += h2f(t.x >> 16);
        p.z += h2f(t.y & 0xffff); p.w += h2f(t.y >> 16);
        t = *(const uint2*)(x + (size_t)(N_USERS + neg[i]) * DIM + q * 4);
        n.x += h2f(t.x & 0xffff); n.y += h2f(t.x >> 16);
        n.z += h2f(t.y & 0xffff); n.w += h2f(t.y >> 16);
        ps = u.x*p.x + u.y*p.y + u.z*p.z + u.w*p.w;
        ns = u.x*n.x + u.y*n.y + u.z*n.z + u.w*n.w;
    }
    for (int s = 8; s > 0; s >>= 1) {
        ps += __shfl_xor(ps, s, 16);
        ns += __shfl_xor(ns, s, 16);
    }
    float term = 0.0f;
    if (q == 0 && i < BATCH) {
        float d = (ps - ns) * (1.0f / 16.0f);
        float sig = 1.0f / (1.0f + expf(-d));
        term = logf(sig + 1e-8f);
    }
    float bt = block_reduce_sum(term);
    if (threadIdx.x == 0) unsafeAtomicAdd(loss_sum, bt);
}

// f32 gather-add + score (fallback path)
__global__ void gather_add_kernel(const float* __restrict__ x,
                                  const int* __restrict__ users, const int* __restrict__ pos,
                                  const int* __restrict__ neg,
                                  float* __restrict__ uacc, float* __restrict__ pacc,
                                  float* __restrict__ nacc) {
    int tid = blockIdx.x * blockDim.x + threadIdx.x;
    int i = tid >> 4;
    int q = tid & 15;
    if (i >= BATCH) return;
    size_t o = (size_t)i * DIM + q * 4;
    float4 a, b;
    a = *(float4*)(uacc + o);
    b = *(const float4*)(x + (size_t)users[i] * DIM + q * 4);
    a.x += b.x; a.y += b.y; a.z += b.z; a.w += b.w;
    *(float4*)(uacc + o) = a;
    a = *(float4*)(pacc + o);
    b = *(const float4*)(x + (size_t)(N_USERS + pos[i]) * DIM + q * 4);
    a.x += b.x; a.y += b.y; a.z += b.z; a.w += b.w;
    *(float4*)(pacc + o) = a;
    a = *(float4*)(nacc + o);
    b = *(const float4*)(x + (size_t)(N_USERS + neg[i]) * DIM + q * 4);
    a.x += b.x; a.y += b.y; a.z += b.z; a.w += b.w;
    *(float4*)(nacc + o) = a;
}

__global__ void score_kernel(const float* __restrict__ uacc, const float* __restrict__ pacc,
                             const float* __restrict__ nacc, float* __restrict__ loss_sum) {
    int tid = blockIdx.x * blockDim.x + threadIdx.x;
    int i = tid >> 4;
    int q = tid & 15;
    float ps = 0.0f, ns = 0.0f;
    if (i < BATCH) {
        size_t o = (size_t)i * DIM + q * 4;
        float4 u = *(const float4*)(uacc + o);
        float4 p = *(const float4*)(pacc + o);
        float4 n = *(const float4*)(nacc + o);
        ps = u.x*p.x + u.y*p.y + u.z*p.z + u.w*p.w;
        ns = u.x*n.x + u.y*n.y + u.z*n.z + u.w*n.w;
    }
    for (int s = 8; s > 0; s >>= 1) {
        ps += __shfl_xor(ps, s, 16);
        ns += __shfl_xor(ns, s, 16);
    }
    float term = 0.0f;
    if (q == 0 && i < BATCH) {
        float d = (ps - ns) * (1.0f / 16.0f);
        float sig = 1.0f / (1.0f + expf(-d));
        term = logf(sig + 1e-8f);
    }
    float bt = block_reduce_sum(term);
    if (threadIdx.x == 0) unsafeAtomicAdd(loss_sum, bt);
}

__global__ void finalize_kernel(const float* __restrict__ sums, float* __restrict__ out) {
    if (threadIdx.x == 0 && blockIdx.x == 0) {
        out[0] = -sums[0] / (float)BATCH;
        out[1] =  sums[1] / (float)BATCH;
    }
}

static inline size_t align256(size_t x) { return (x + 255) & ~(size_t)255; }

extern "C" void kernel_launch(void* const* d_in, const int* in_sizes, int n_in,
                              void* d_out, int out_size, void* d_ws, size_t ws_size,
                              hipStream_t stream) {
    const float* uw   = (const float*)d_in[0];
    const float* iw   = (const float*)d_in[1];
    const float* vals = (const float*)d_in[2];
    const int*   rows = (const int*)d_in[3];
    const int*   cols = (const int*)d_in[4];
    const int*   users = (const int*)d_in[5];
    const int*   pos   = (const int*)d_in[6];
    const int*   neg   = (const int*)d_in[7];
    const int nnz = in_sizes[2];

    char* ws = (char*)d_ws;
    const size_t nodeBytes = (size_t)N_NODES * DIM * sizeof(float);          // 38.4 MB
    const size_t hBytes    = (size_t)N_NODES * DIM * sizeof(unsigned short); // 19.2 MB
    const size_t accBytes  = (size_t)BATCH * DIM * sizeof(float);

    size_t off = 0;
    char*  nodeReg = ws + off;            off += align256(2 * nodeBytes);    // 76.8 MB region
    float* uacc = (float*)(ws + off);     off += align256(accBytes);
    float* pacc = (float*)(ws + off);     off += align256(accBytes);
    float* nacc = (float*)(ws + off);     off += align256(accBytes);
    float* sums = (float*)(ws + off);     off += 256;   // [0]=loss, [1]=reg
    Pair*  perm = (Pair*)(ws + off);      off += align256((size_t)nnz * sizeof(Pair));
    int*   rowptr = (int*)(ws + off);     off += align256((size_t)(N_NODES + 1) * sizeof(int));
    int*   bcnt   = (int*)(ws + off);     off += align256((size_t)NB * sizeof(int));
    int*   bbase  = (int*)(ws + off);     off += align256((size_t)(NB + 1) * sizeof(int));
    int*   bcursor= (int*)(ws + off);     off += align256((size_t)NB * sizeof(int));
    const bool fits_alias = (3 * align256(hBytes) + (size_t)nnz * sizeof(Pair)) <= 2 * nodeBytes;
    const bool use_csr = (off <= ws_size) && fits_alias && (N_NODES < (1 << 18));

    // f16 node buffers + bcv staging all carved from the node region
    unsigned short* xb0 = (unsigned short*)nodeReg;
    unsigned short* xb1 = (unsigned short*)(nodeReg + align256(hBytes));
    unsigned short* xb2 = (unsigned short*)(nodeReg + 2 * align256(hBytes));
    Pair*           bcv = (Pair*)(nodeReg + 3 * align256(hBytes));
    // fallback f32 views of the same region
    float* xA = (float*)nodeReg;
    float* xB = (float*)(nodeReg + nodeBytes);

    float* out = (float*)d_out;

    const int bthreads = BATCH * 16;
    const int bblocks  = bthreads / 256;
    const int tblocks  = (nnz + TILE_E - 1) / TILE_E;
    const int cblocks  = (int)(((size_t)N_NODES * DIM / 8 + 255) / 256);

    (void)hipMemsetAsync(sums, 0, 2 * sizeof(float), stream);
    init_kernel<<<bblocks, 256, 0, stream>>>(uw, iw, users, pos, neg, uacc, pacc, nacc, sums + 1);

    if (use_csr) {
        // ---- CSR build: bucket hist -> scan -> binned scatter -> LDS sort ----
        (void)hipMemsetAsync(bcnt, 0, (size_t)NB * sizeof(int), stream);
        convert_kernel<<<cblocks, 256, 0, stream>>>(uw, iw, xb0);
        bucket_hist_kernel<<<tblocks, 512, 0, stream>>>(rows, bcnt, nnz);
        bucket_scan_kernel<<<1, 512, 0, stream>>>(bcnt, bbase, bcursor, rowptr, nnz);
        binned_scatter_kernel<<<tblocks, 512, 0, stream>>>(rows, cols, vals, bcursor, bcv, nnz);
        bucket_sort_kernel<<<NB, 512, 0, stream>>>(bcv, bbase, rowptr, perm);

        const int sblocks = (N_NODES + 3) / 4;
        // Layer 1: xb0 -> xb1
        spmm_csr_f16_kernel<<<sblocks, 256, 0, stream>>>(xb0, perm, rowptr, xb1);
        gather_add_f16_kernel<<<bblocks, 256, 0, stream>>>(xb1, users, pos, neg, uacc, pacc, nacc);
        // Layer 2: xb1 -> xb2
        spmm_csr_f16_kernel<<<sblocks, 256, 0, stream>>>(xb1, perm, rowptr, xb2);
        gather_add_f16_kernel<<<bblocks, 256, 0, stream>>>(xb2, users, pos, neg, uacc, pacc, nacc);
        // Layer 3: xb2 -> xb0, fused gather+score epilogue
        spmm_csr_f16_kernel<<<sblocks, 256, 0, stream>>>(xb2, perm, rowptr, xb0);
        gather_score_kernel<<<bblocks, 256, 0, stream>>>(xb0, users, pos, neg, uacc, pacc, nacc, sums);
    } else {
        // ---- Fallback: COO atomic path (f32) ----
        const long long sthreads = (long long)nnz * 16;
        const int sblocks = (int)((sthreads + 255) / 256);
        (void)hipMemsetAsync(xA, 0, nodeBytes, stream);
        spmm_atomic_kernel<<<sblocks, 256, 0, stream>>>(uw, iw, vals, rows, cols, xA, nnz);
        gather_add_kernel<<<bblocks, 256, 0, stream>>>(xA, users, pos, neg, uacc, pacc, nacc);
        (void)hipMemsetAsync(xB, 0, nodeBytes, stream);
        spmm_atomic_kernel<<<sblocks, 256, 0, stream>>>(xA, xA + (size_t)N_USERS * DIM, vals, rows, cols, xB, nnz);
        gather_add_kernel<<<bblocks, 256, 0, stream>>>(xB, users, pos, neg, uacc, pacc, nacc);
        (void)hipMemsetAsync(xA, 0, nodeBytes, stream);
        spmm_atomic_kernel<<<sblocks, 256, 0, stream>>>(xB, xB + (size_t)N_USERS * DIM, vals, rows, cols, xA, nnz);
        gather_add_kernel<<<bblocks, 256, 0, stream>>>(xA, users, pos, neg, uacc, pacc, nacc);
        score_kernel<<<bblocks, 256, 0, stream>>>(uacc, pacc, nacc, sums);
    }

    finalize_kernel<<<1, 1, 0, stream>>>(sums, out);
}

// Round 8
// 283.511 us; speedup vs baseline: 21.6276x; 1.1374x over previous
//
#include <hip/hip_runtime.h>

#define N_USERS 100000
#define N_ITEMS 50000
#define N_NODES (N_USERS + N_ITEMS)
#define DIM 64
#define BATCH 16384
#define RPB 512                          // rows per bucket
#define NB ((N_NODES + RPB - 1) / RPB)   // 293 buckets
#define HP 296                           // padded hist stride (bank stagger)
#define EPT 16                           // edges per thread in scatter
#define TILE_E (512 * EPT)               // 8192 edges per scatter block
#define STRIDE 12288                     // bcv region stride per bucket (45-sigma headroom)

struct __align__(8) Pair { int c; float v; };

// ---- f16 helpers ----------------------------------------------------------
__device__ __forceinline__ float h2f(unsigned short s) {
    union { unsigned short u; _Float16 h; } c; c.u = s; return (float)c.h;
}
__device__ __forceinline__ unsigned pkh(float a, float b) {
    unsigned r;
    asm("v_cvt_pkrtz_f16_f32 %0, %1, %2" : "=v"(r) : "v"(a), "v"(b));
    return r;
}
// acc += f16(lo/hi half of xu) * vf   — no unpack instruction needed
#define MIX_LO(acc, xu, vf) \
    asm("v_fma_mix_f32 %0, %1, %2, %0 op_sel:[0,0,0] op_sel_hi:[1,0,0]" \
        : "+v"(acc) : "v"(xu), "v"(vf))
#define MIX_HI(acc, xu, vf) \
    asm("v_fma_mix_f32 %0, %1, %2, %0 op_sel:[1,0,0] op_sel_hi:[1,0,0]" \
        : "+v"(acc) : "v"(xu), "v"(vf))

// ---------------------------------------------------------------------------
__device__ __forceinline__ float block_reduce_sum(float v) {
    for (int s = 32; s > 0; s >>= 1) v += __shfl_xor(v, s, 64);
    __shared__ float sm[8];
    int lane = threadIdx.x & 63;
    int wid  = threadIdx.x >> 6;
    if (lane == 0) sm[wid] = v;
    __syncthreads();
    float t = 0.0f;
    if (threadIdx.x == 0) {
        int nw = (blockDim.x + 63) >> 6;
        for (int w = 0; w < nw; ++w) t += sm[w];
    }
    return t;
}

// ---------------------------------------------------------------------------
// Convert concat [uw;iw] f32 -> f16 once (layer-1 SpMM input).
// ---------------------------------------------------------------------------
__global__ void convert_kernel(const float* __restrict__ uw, const float* __restrict__ iw,
                               unsigned short* __restrict__ xh) {
    size_t base = ((size_t)blockIdx.x * 256 + threadIdx.x) * 8;
    if (base >= (size_t)N_NODES * DIM) return;
    const float* src = (base < (size_t)N_USERS * DIM) ? uw + base
                                                      : iw + (base - (size_t)N_USERS * DIM);
    float4 a = ((const float4*)src)[0];
    float4 b = ((const float4*)src)[1];
    uint4 o;
    o.x = pkh(a.x, a.y);
    o.y = pkh(a.z, a.w);
    o.z = pkh(b.x, b.y);
    o.w = pkh(b.z, b.w);
    *(uint4*)(xh + base) = o;
}

// ---------------------------------------------------------------------------
// Init: acc_0 = gathered layer-0 embeddings + reg_sum from ORIGINAL weights.
// ---------------------------------------------------------------------------
__global__ void init_kernel(const float* __restrict__ uw, const float* __restrict__ iw,
                            const int* __restrict__ users, const int* __restrict__ pos,
                            const int* __restrict__ neg,
                            float* __restrict__ uacc, float* __restrict__ pacc,
                            float* __restrict__ nacc, float* __restrict__ reg_sum) {
    int tid = blockIdx.x * blockDim.x + threadIdx.x;
    int i = tid >> 4;
    int q = tid & 15;
    if (i >= BATCH) return;
    size_t o = (size_t)i * DIM + q * 4;
    float4 u = *(const float4*)(uw + (size_t)users[i] * DIM + q * 4);
    float4 p = *(const float4*)(iw + (size_t)pos[i]   * DIM + q * 4);
    float4 n = *(const float4*)(iw + (size_t)neg[i]   * DIM + q * 4);
    *(float4*)(uacc + o) = u;
    *(float4*)(pacc + o) = p;
    *(float4*)(nacc + o) = n;
    float ss = u.x*u.x + u.y*u.y + u.z*u.z + u.w*u.w
             + p.x*p.x + p.y*p.y + p.z*p.z + p.w*p.w
             + n.x*n.x + n.y*n.y + n.z*n.z + n.w*n.w;
    float bt = block_reduce_sum(ss);
    if (threadIdx.x == 0) unsafeAtomicAdd(reg_sum, bt);
}

// ---------------------------------------------------------------------------
// Mark rows needed by the final gather (layer-3 output consumers).
// ---------------------------------------------------------------------------
__global__ void flag_kernel(const int* __restrict__ users, const int* __restrict__ pos,
                            const int* __restrict__ neg, int* __restrict__ flags) {
    int tid = blockIdx.x * blockDim.x + threadIdx.x;
    if (tid < BATCH)               flags[users[tid]] = 1;
    else if (tid < 2 * BATCH)      flags[N_USERS + pos[tid - BATCH]] = 1;
    else if (tid < 3 * BATCH)      flags[N_USERS + neg[tid - 2 * BATCH]] = 1;
}

// ---------------------------------------------------------------------------
// Binned scatter into fixed-stride per-bucket regions (no pre-histogram).
// Per-wave LDS hist; one packed 8B store per edge.
// packed c-field = col | (row_local << 18)   (col < 2^18, row_local < 512)
// ---------------------------------------------------------------------------
__global__ void binned_scatter_kernel(const int* __restrict__ rows, const int* __restrict__ cols,
                                      const float* __restrict__ vals, int* __restrict__ bcursor,
                                      Pair* __restrict__ bcv, int nnz) {
    __shared__ int h[8][HP];
    int t = threadIdx.x, w = t >> 6;
    for (int i = t; i < 8 * HP; i += 512) ((int*)h)[i] = 0;
    __syncthreads();
    long long tile = (long long)blockIdx.x * TILE_E;
    int er[EPT];
    #pragma unroll
    for (int j = 0; j < EPT; ++j) {
        long long e = tile + t + j * 512;
        if (e < nnz) {
            int r = rows[e];
            er[j] = r;
            atomicAdd(&h[w][r >> 9], 1);
        } else er[j] = -1;
    }
    __syncthreads();
    // per-bucket: claim a contiguous run in the bucket's fixed region
    for (int b = t; b < NB; b += 512) {
        int cw[8], tot = 0;
        #pragma unroll
        for (int w2 = 0; w2 < 8; ++w2) { cw[w2] = h[w2][b]; tot += cw[w2]; }
        int base = tot ? (b * STRIDE + atomicAdd(&bcursor[b], tot)) : 0;
        #pragma unroll
        for (int w2 = 0; w2 < 8; ++w2) { h[w2][b] = base; base += cw[w2]; }
    }
    __syncthreads();
    #pragma unroll
    for (int j = 0; j < EPT; ++j) {
        if (er[j] >= 0) {
            long long e = tile + t + j * 512;
            int r = er[j];
            int dst = atomicAdd(&h[w][r >> 9], 1);
            Pair p;
            p.c = cols[e] | ((r & (RPB - 1)) << 18);
            p.v = vals[e];
            bcv[dst] = p;
        }
    }
}

// ---------------------------------------------------------------------------
// Post-scan: bucket counts (=bcursor) -> dense CSR bucket bases.
// ---------------------------------------------------------------------------
__global__ void post_scan_kernel(const int* __restrict__ counts, int* __restrict__ bbase,
                                 int* __restrict__ rowptr, int nnz) {
    __shared__ int sm[512];
    int t = threadIdx.x;
    int v = (t < NB) ? counts[t] : 0;
    sm[t] = v;
    __syncthreads();
    for (int off = 1; off < 512; off <<= 1) {
        int tmp = (t >= off) ? sm[t - off] : 0;
        __syncthreads();
        sm[t] += tmp;
        __syncthreads();
    }
    if (t < NB) bbase[t] = sm[t] - v;
    if (t == 511) bbase[NB] = sm[511];
    if (t == 0) rowptr[N_NODES] = nnz;
}

// ---------------------------------------------------------------------------
// Per-bucket counting sort in LDS -> final dense CSR perm + rowptr.
// Phase-1 hist uses 8-way wave replication to cut LDS atomic contention.
// ---------------------------------------------------------------------------
__global__ void bucket_sort_kernel(const Pair* __restrict__ bcv,
                                   const int* __restrict__ counts,
                                   const int* __restrict__ bbase,
                                   int* __restrict__ rowptr, Pair* __restrict__ perm) {
    __shared__ int rh8[8][RPB + 8];
    __shared__ int rh[RPB];
    __shared__ int sc[RPB];
    int blk = blockIdx.x;
    int t = threadIdx.x;        // 512 threads
    int w = t >> 6;
    int src  = blk * STRIDE;
    int base = bbase[blk];
    int cnt  = counts[blk];
    for (int i = t; i < 8 * (RPB + 8); i += 512) ((int*)rh8)[i] = 0;
    __syncthreads();
    for (int i = t; i < cnt; i += 512)
        atomicAdd(&rh8[w][(unsigned)bcv[src + i].c >> 18], 1);
    __syncthreads();
    int v = 0;
    #pragma unroll
    for (int w2 = 0; w2 < 8; ++w2) v += rh8[w2][t];
    sc[t] = v;
    __syncthreads();
    for (int off = 1; off < 512; off <<= 1) {
        int tmp = (t >= off) ? sc[t - off] : 0;
        __syncthreads();
        sc[t] += tmp;
        __syncthreads();
    }
    int excl = sc[t] - v;
    int g = blk * RPB + t;
    if (g < N_NODES) rowptr[g] = base + excl;
    rh[t] = excl;               // per-row cursor
    __syncthreads();
    for (int i = t; i < cnt; i += 512) {
        Pair p = bcv[src + i];
        int r = (unsigned)p.c >> 18;
        int rk = atomicAdd(&rh[r], 1);
        p.c &= 0x3FFFF;
        perm[base + rk] = p;
    }
}

// ---------------------------------------------------------------------------
// CSR SpMM, f16 in / f16 out (f32 accumulate via v_fma_mix). One wave per
// row; 8 groups of 8 lanes, each lane covers 8 dims with one 16B load;
// 2-edge unroll -> 16 edges in flight per wave. Cross-group shfl reduce.
// FLAGGED variant computes only rows marked in `flags` (layer 3).
// ---------------------------------------------------------------------------
template<bool FLAGGED>
__global__ void spmm_csr_f16_kernel(const unsigned short* __restrict__ xh,
                                    const Pair* __restrict__ pe,
                                    const int* __restrict__ rowptr,
                                    const int* __restrict__ flags,
                                    unsigned short* __restrict__ out) {
    int row  = blockIdx.x * 4 + (threadIdx.x >> 6);
    if (row >= N_NODES) return;
    if (FLAGGED && !flags[row]) return;
    int lane = threadIdx.x & 63;
    int g = lane >> 3;        // edge slot 0..7
    int q = lane & 7;         // 8-dim chunk
    int start = rowptr[row];
    int end   = rowptr[row + 1];
    float a0=0,a1=0,a2=0,a3=0,a4=0,a5=0,a6=0,a7=0;
    int e = start + g;
    for (; e + 8 < end; e += 16) {
        Pair p0 = pe[e];
        Pair p1 = pe[e + 8];
        uint4 x0 = *(const uint4*)(xh + (size_t)p0.c * DIM + q * 8);
        uint4 x1 = *(const uint4*)(xh + (size_t)p1.c * DIM + q * 8);
        MIX_LO(a0, x0.x, p0.v); MIX_HI(a1, x0.x, p0.v);
        MIX_LO(a2, x0.y, p0.v); MIX_HI(a3, x0.y, p0.v);
        MIX_LO(a4, x0.z, p0.v); MIX_HI(a5, x0.z, p0.v);
        MIX_LO(a6, x0.w, p0.v); MIX_HI(a7, x0.w, p0.v);
        MIX_LO(a0, x1.x, p1.v); MIX_HI(a1, x1.x, p1.v);
        MIX_LO(a2, x1.y, p1.v); MIX_HI(a3, x1.y, p1.v);
        MIX_LO(a4, x1.z, p1.v); MIX_HI(a5, x1.z, p1.v);
        MIX_LO(a6, x1.w, p1.v); MIX_HI(a7, x1.w, p1.v);
    }
    for (; e < end; e += 8) {
        Pair p = pe[e];
        uint4 x = *(const uint4*)(xh + (size_t)p.c * DIM + q * 8);
        MIX_LO(a0, x.x, p.v); MIX_HI(a1, x.x, p.v);
        MIX_LO(a2, x.y, p.v); MIX_HI(a3, x.y, p.v);
        MIX_LO(a4, x.z, p.v); MIX_HI(a5, x.z, p.v);
        MIX_LO(a6, x.w, p.v); MIX_HI(a7, x.w, p.v);
    }
    #pragma unroll
    for (int s = 8; s <= 32; s <<= 1) {
        a0 += __shfl_xor(a0, s, 64); a1 += __shfl_xor(a1, s, 64);
        a2 += __shfl_xor(a2, s, 64); a3 += __shfl_xor(a3, s, 64);
        a4 += __shfl_xor(a4, s, 64); a5 += __shfl_xor(a5, s, 64);
        a6 += __shfl_xor(a6, s, 64); a7 += __shfl_xor(a7, s, 64);
    }
    if (g == 0) {
        uint4 o;
        o.x = pkh(a0, a1);
        o.y = pkh(a2, a3);
        o.z = pkh(a4, a5);
        o.w = pkh(a6, a7);
        *(uint4*)(out + (size_t)row * DIM + q * 8) = o;
    }
}

// ---------------------------------------------------------------------------
// Legacy COO atomic SpMM (fallback when ws is too small for CSR buffers).
// ---------------------------------------------------------------------------
__global__ void spmm_atomic_kernel(const float* __restrict__ xu, const float* __restrict__ xi,
                                   const float* __restrict__ vals, const int* __restrict__ rows,
                                   const int* __restrict__ cols,
                                   float* __restrict__ out, int nnz) {
    long long tid = (long long)blockIdx.x * blockDim.x + threadIdx.x;
    int e = (int)(tid >> 4);
    if (e >= nnz) return;
    int q = (int)(tid & 15);
    int r = rows[e];
    int c = cols[e];
    float v = vals[e];
    const float* src = (c < N_USERS) ? (xu + (size_t)c * DIM)
                                     : (xi + (size_t)(c - N_USERS) * DIM);
    float4 x = *(const float4*)(src + q * 4);
    float* dst = out + (size_t)r * DIM + q * 4;
    unsafeAtomicAdd(dst + 0, v * x.x);
    unsafeAtomicAdd(dst + 1, v * x.y);
    unsafeAtomicAdd(dst + 2, v * x.z);
    unsafeAtomicAdd(dst + 3, v * x.w);
}

// ---------------------------------------------------------------------------
// Gather-accumulate a layer's f16 output at the batch rows only.
// ---------------------------------------------------------------------------
__global__ void gather_add_f16_kernel(const unsigned short* __restrict__ x,
                                      const int* __restrict__ users, const int* __restrict__ pos,
                                      const int* __restrict__ neg,
                                      float* __restrict__ uacc, float* __restrict__ pacc,
                                      float* __restrict__ nacc) {
    int tid = blockIdx.x * blockDim.x + threadIdx.x;
    int i = tid >> 4;
    int q = tid & 15;
    if (i >= BATCH) return;
    size_t o = (size_t)i * DIM + q * 4;
    float4 a;
    uint2 u;

    a = *(float4*)(uacc + o);
    u = *(const uint2*)(x + (size_t)users[i] * DIM + q * 4);
    a.x += h2f(u.x & 0xffff); a.y += h2f(u.x >> 16);
    a.z += h2f(u.y & 0xffff); a.w += h2f(u.y >> 16);
    *(float4*)(uacc + o) = a;

    a = *(float4*)(pacc + o);
    u = *(const uint2*)(x + (size_t)(N_USERS + pos[i]) * DIM + q * 4);
    a.x += h2f(u.x & 0xffff); a.y += h2f(u.x >> 16);
    a.z += h2f(u.y & 0xffff); a.w += h2f(u.y >> 16);
    *(float4*)(pacc + o) = a;

    a = *(float4*)(nacc + o);
    u = *(const uint2*)(x + (size_t)(N_USERS + neg[i]) * DIM + q * 4);
    a.x += h2f(u.x & 0xffff); a.y += h2f(u.x >> 16);
    a.z += h2f(u.y & 0xffff); a.w += h2f(u.y >> 16);
    *(float4*)(nacc + o) = a;
}

// ---------------------------------------------------------------------------
// Fused layer-3 gather + BPR score. final = acc/4, so dot scales by 1/16.
// ---------------------------------------------------------------------------
__global__ void gather_score_kernel(const unsigned short* __restrict__ x,
                                    const int* __restrict__ users, const int* __restrict__ pos,
                                    const int* __restrict__ neg,
                                    const float* __restrict__ uacc, const float* __restrict__ pacc,
                                    const float* __restrict__ nacc, float* __restrict__ loss_sum) {
    int tid = blockIdx.x * blockDim.x + threadIdx.x;
    int i = tid >> 4;
    int q = tid & 15;
    float ps = 0.0f, ns = 0.0f;
    if (i < BATCH) {
        size_t o = (size_t)i * DIM + q * 4;
        float4 u = *(const float4*)(uacc + o);
        float4 p = *(const float4*)(pacc + o);
        float4 n = *(const float4*)(nacc + o);
        uint2 t;
        t = *(const uint2*)(x + (size_t)users[i] * DIM + q * 4);
        u.x += h2f(t.x & 0xffff); u.y += h2f(t.x >> 16);
        u.z += h2f(t.y & 0xffff); u.w += h2f(t.y >> 16);
        t = *(const uint2*)(x + (size_t)(N_USERS + pos[i]) * DIM + q * 4);
        p.x += h2f(t.x & 0xffff); p.y += h2f(t.x >> 16);
        p.z += h2f(t.y & 0xffff); p.w += h2f(t.y >> 16);
        t = *(const uint2*)(x + (size_t)(N_USERS + neg[i]) * DIM + q * 4);
        n.x += h2f(t.x & 0xffff); n.y += h2f(t.x >> 16);
        n.z += h2f(t.y & 0xffff); n.w += h2f(t.y >> 16);
        ps = u.x*p.x + u.y*p.y + u.z*p.z + u.w*p.w;
        ns = u.x*n.x + u.y*n.y + u.z*n.z + u.w*n.w;
    }
    for (int s = 8; s > 0; s >>= 1) {
        ps += __shfl_xor(ps, s, 16);
        ns += __shfl_xor(ns, s, 16);
    }
    float term = 0.0f;
    if (q == 0 && i < BATCH) {
        float d = (ps - ns) * (1.0f / 16.0f);
        float sig = 1.0f / (1.0f + expf(-d));
        term = logf(sig + 1e-8f);
    }
    float bt = block_reduce_sum(term);
    if (threadIdx.x == 0) unsafeAtomicAdd(loss_sum, bt);
}

// f32 gather-add + score (fallback path)
__global__ void gather_add_kernel(const float* __restrict__ x,
                                  const int* __restrict__ users, const int* __restrict__ pos,
                                  const int* __restrict__ neg,
                                  float* __restrict__ uacc, float* __restrict__ pacc,
                                  float* __restrict__ nacc) {
    int tid = blockIdx.x * blockDim.x + threadIdx.x;
    int i = tid >> 4;
    int q = tid & 15;
    if (i >= BATCH) return;
    size_t o = (size_t)i * DIM + q * 4;
    float4 a, b;
    a = *(float4*)(uacc + o);
    b = *(const float4*)(x + (size_t)users[i] * DIM + q * 4);
    a.x += b.x; a.y += b.y; a.z += b.z; a.w += b.w;
    *(float4*)(uacc + o) = a;
    a = *(float4*)(pacc + o);
    b = *(const float4*)(x + (size_t)(N_USERS + pos[i]) * DIM + q * 4);
    a.x += b.x; a.y += b.y; a.z += b.z; a.w += b.w;
    *(float4*)(pacc + o) = a;
    a = *(float4*)(nacc + o);
    b = *(const float4*)(x + (size_t)(N_USERS + neg[i]) * DIM + q * 4);
    a.x += b.x; a.y += b.y; a.z += b.z; a.w += b.w;
    *(float4*)(nacc + o) = a;
}

__global__ void score_kernel(const float* __restrict__ uacc, const float* __restrict__ pacc,
                             const float* __restrict__ nacc, float* __restrict__ loss_sum) {
    int tid = blockIdx.x * blockDim.x + threadIdx.x;
    int i = tid >> 4;
    int q = tid & 15;
    float ps = 0.0f, ns = 0.0f;
    if (i < BATCH) {
        size_t o = (size_t)i * DIM + q * 4;
        float4 u = *(const float4*)(uacc + o);
        float4 p = *(const float4*)(pacc + o);
        float4 n = *(const float4*)(nacc + o);
        ps = u.x*p.x + u.y*p.y + u.z*p.z + u.w*p.w;
        ns = u.x*n.x + u.y*n.y + u.z*n.z + u.w*n.w;
    }
    for (int s = 8; s > 0; s >>= 1) {
        ps += __shfl_xor(ps, s, 16);
        ns += __shfl_xor(ns, s, 16);
    }
    float term = 0.0f;
    if (q == 0 && i < BATCH) {
        float d = (ps - ns) * (1.0f / 16.0f);
        float sig = 1.0f / (1.0f + expf(-d));
        term = logf(sig + 1e-8f);
    }
    float bt = block_reduce_sum(term);
    if (threadIdx.x == 0) unsafeAtomicAdd(loss_sum, bt);
}

__global__ void finalize_kernel(const float* __restrict__ sums, float* __restrict__ out) {
    if (threadIdx.x == 0 && blockIdx.x == 0) {
        out[0] = -sums[0] / (float)BATCH;
        out[1] =  sums[1] / (float)BATCH;
    }
}

static inline size_t align256(size_t x) { return (x + 255) & ~(size_t)255; }

extern "C" void kernel_launch(void* const* d_in, const int* in_sizes, int n_in,
                              void* d_out, int out_size, void* d_ws, size_t ws_size,
                              hipStream_t stream) {
    const float* uw   = (const float*)d_in[0];
    const float* iw   = (const float*)d_in[1];
    const float* vals = (const float*)d_in[2];
    const int*   rows = (const int*)d_in[3];
    const int*   cols = (const int*)d_in[4];
    const int*   users = (const int*)d_in[5];
    const int*   pos   = (const int*)d_in[6];
    const int*   neg   = (const int*)d_in[7];
    const int nnz = in_sizes[2];

    char* ws = (char*)d_ws;
    const size_t nodeBytes = (size_t)N_NODES * DIM * sizeof(float);          // 38.4 MB
    const size_t hBytes    = (size_t)N_NODES * DIM * sizeof(unsigned short); // 19.2 MB
    const size_t accBytes  = (size_t)BATCH * DIM * sizeof(float);

    size_t off = 0;
    char*  nodeReg = ws + off;            off += align256(2 * nodeBytes);    // 76.8 MB region
    float* uacc = (float*)(ws + off);     off += align256(accBytes);
    float* pacc = (float*)(ws + off);     off += align256(accBytes);
    float* nacc = (float*)(ws + off);     off += align256(accBytes);
    float* sums = (float*)(ws + off);     off += 256;   // [0]=loss, [1]=reg
    Pair*  perm = (Pair*)(ws + off);      off += align256((size_t)nnz * sizeof(Pair));
    int*   rowptr = (int*)(ws + off);     off += align256((size_t)(N_NODES + 1) * sizeof(int));
    int*   bbase  = (int*)(ws + off);     off += align256((size_t)(NB + 1) * sizeof(int));
    int*   bcursor= (int*)(ws + off);     off += align256((size_t)NB * sizeof(int));
    int*   flags  = (int*)(ws + off);     off += align256((size_t)N_NODES * sizeof(int));
    // bcv fixed-stride region aliases xb2's slot + spare (consumed before xb2 is written)
    const bool fits_alias = (2 * align256(hBytes) + (size_t)NB * STRIDE * sizeof(Pair)) <= 2 * nodeBytes;
    const bool use_csr = (off <= ws_size) && fits_alias && (N_NODES < (1 << 18));

    unsigned short* xb0 = (unsigned short*)nodeReg;
    unsigned short* xb1 = (unsigned short*)(nodeReg + align256(hBytes));
    unsigned short* xb2 = (unsigned short*)(nodeReg + 2 * align256(hBytes));
    Pair*           bcv = (Pair*)(nodeReg + 2 * align256(hBytes));
    // fallback f32 views of the same region
    float* xA = (float*)nodeReg;
    float* xB = (float*)(nodeReg + nodeBytes);

    float* out = (float*)d_out;

    const int bthreads = BATCH * 16;
    const int bblocks  = bthreads / 256;
    const int tblocks  = (nnz + TILE_E - 1) / TILE_E;
    const int cblocks  = (int)(((size_t)N_NODES * DIM / 8 + 255) / 256);

    (void)hipMemsetAsync(sums, 0, 2 * sizeof(float), stream);
    init_kernel<<<bblocks, 256, 0, stream>>>(uw, iw, users, pos, neg, uacc, pacc, nacc, sums + 1);

    if (use_csr) {
        // ---- CSR build: binned scatter (fixed regions) -> scan -> LDS sort ----
        (void)hipMemsetAsync(bcursor, 0, (size_t)NB * sizeof(int), stream);
        (void)hipMemsetAsync(flags, 0, (size_t)N_NODES * sizeof(int), stream);
        flag_kernel<<<(3 * BATCH + 255) / 256, 256, 0, stream>>>(users, pos, neg, flags);
        convert_kernel<<<cblocks, 256, 0, stream>>>(uw, iw, xb0);
        binned_scatter_kernel<<<tblocks, 512, 0, stream>>>(rows, cols, vals, bcursor, bcv, nnz);
        post_scan_kernel<<<1, 512, 0, stream>>>(bcursor, bbase, rowptr, nnz);
        bucket_sort_kernel<<<NB, 512, 0, stream>>>(bcv, bcursor, bbase, rowptr, perm);

        const int sblocks = (N_NODES + 3) / 4;
        // Layer 1: xb0 -> xb1
        spmm_csr_f16_kernel<false><<<sblocks, 256, 0, stream>>>(xb0, perm, rowptr, flags, xb1);
        gather_add_f16_kernel<<<bblocks, 256, 0, stream>>>(xb1, users, pos, neg, uacc, pacc, nacc);
        // Layer 2: xb1 -> xb2 (bcv dead after sort)
        spmm_csr_f16_kernel<false><<<sblocks, 256, 0, stream>>>(xb1, perm, rowptr, flags, xb2);
        gather_add_f16_kernel<<<bblocks, 256, 0, stream>>>(xb2, users, pos, neg, uacc, pacc, nacc);
        // Layer 3: xb2 -> xb0, only needed rows; fused gather+score epilogue
        spmm_csr_f16_kernel<true><<<sblocks, 256, 0, stream>>>(xb2, perm, rowptr, flags, xb0);
        gather_score_kernel<<<bblocks, 256, 0, stream>>>(xb0, users, pos, neg, uacc, pacc, nacc, sums);
    } else {
        // ---- Fallback: COO atomic path (f32) ----
        const long long sthreads = (long long)nnz * 16;
        const int sblocks = (int)((sthreads + 255) / 256);
        (void)hipMemsetAsync(xA, 0, nodeBytes, stream);
        spmm_atomic_kernel<<<sblocks, 256, 0, stream>>>(uw, iw, vals, rows, cols, xA, nnz);
        gather_add_kernel<<<bblocks, 256, 0, stream>>>(xA, users, pos, neg, uacc, pacc, nacc);
        (void)hipMemsetAsync(xB, 0, nodeBytes, stream);
        spmm_atomic_kernel<<<sblocks, 256, 0, stream>>>(xA, xA + (size_t)N_USERS * DIM, vals, rows, cols, xB, nnz);
        gather_add_kernel<<<bblocks, 256, 0, stream>>>(xB, users, pos, neg, uacc, pacc, nacc);
        (void)hipMemsetAsync(xA, 0, nodeBytes, stream);
        spmm_atomic_kernel<<<sblocks, 256, 0, stream>>>(xB, xB + (size_t)N_USERS * DIM, vals, rows, cols, xA, nnz);
        gather_add_kernel<<<bblocks, 256, 0, stream>>>(xA, users, pos, neg, uacc, pacc, nacc);
        score_kernel<<<bblocks, 256, 0, stream>>>(uacc, pacc, nacc, sums);
    }

    finalize_kernel<<<1, 1, 0, stream>>>(sums, out);
}

// Round 9
// 280.663 us; speedup vs baseline: 21.8470x; 1.0101x over previous
//
#include <hip/hip_runtime.h>

#define N_USERS 100000
#define N_ITEMS 50000
#define N_NODES (N_USERS + N_ITEMS)
#define DIM 64
#define BATCH 16384
#define RPB 512                          // rows per bucket
#define NB ((N_NODES + RPB - 1) / RPB)   // 293 buckets
#define HP 296                           // padded hist stride (bank stagger)
#define EPT 8                            // edges per thread in scatter
#define TILE_E (512 * EPT)               // 4096 edges per scatter block
#define STRIDE 12288                     // bcv region stride per bucket (45-sigma headroom)

struct __align__(8) Pair { int c; float v; };

// ---- f16 helpers ----------------------------------------------------------
__device__ __forceinline__ float h2f(unsigned short s) {
    union { unsigned short u; _Float16 h; } c; c.u = s; return (float)c.h;
}
__device__ __forceinline__ unsigned pkh(float a, float b) {
    unsigned r;
    asm("v_cvt_pkrtz_f16_f32 %0, %1, %2" : "=v"(r) : "v"(a), "v"(b));
    return r;
}
// acc += f16(lo/hi half of xu) * vf   — no unpack instruction needed
#define MIX_LO(acc, xu, vf) \
    asm("v_fma_mix_f32 %0, %1, %2, %0 op_sel:[0,0,0] op_sel_hi:[1,0,0]" \
        : "+v"(acc) : "v"(xu), "v"(vf))
#define MIX_HI(acc, xu, vf) \
    asm("v_fma_mix_f32 %0, %1, %2, %0 op_sel:[1,0,0] op_sel_hi:[1,0,0]" \
        : "+v"(acc) : "v"(xu), "v"(vf))

#define EDGE_MIX(P, X) \
    MIX_LO(a0, X.x, P.v); MIX_HI(a1, X.x, P.v); \
    MIX_LO(a2, X.y, P.v); MIX_HI(a3, X.y, P.v); \
    MIX_LO(a4, X.z, P.v); MIX_HI(a5, X.z, P.v); \
    MIX_LO(a6, X.w, P.v); MIX_HI(a7, X.w, P.v)

// ---------------------------------------------------------------------------
__device__ __forceinline__ float block_reduce_sum(float v) {
    for (int s = 32; s > 0; s >>= 1) v += __shfl_xor(v, s, 64);
    __shared__ float sm[8];
    int lane = threadIdx.x & 63;
    int wid  = threadIdx.x >> 6;
    if (lane == 0) sm[wid] = v;
    __syncthreads();
    float t = 0.0f;
    if (threadIdx.x == 0) {
        int nw = (blockDim.x + 63) >> 6;
        for (int w = 0; w < nw; ++w) t += sm[w];
    }
    return t;
}

// ---------------------------------------------------------------------------
// Convert concat [uw;iw] f32 -> f16 once (layer-1 SpMM input).
// ---------------------------------------------------------------------------
__global__ void convert_kernel(const float* __restrict__ uw, const float* __restrict__ iw,
                               unsigned short* __restrict__ xh) {
    size_t base = ((size_t)blockIdx.x * 256 + threadIdx.x) * 8;
    if (base >= (size_t)N_NODES * DIM) return;
    const float* src = (base < (size_t)N_USERS * DIM) ? uw + base
                                                      : iw + (base - (size_t)N_USERS * DIM);
    float4 a = ((const float4*)src)[0];
    float4 b = ((const float4*)src)[1];
    uint4 o;
    o.x = pkh(a.x, a.y);
    o.y = pkh(a.z, a.w);
    o.z = pkh(b.x, b.y);
    o.w = pkh(b.z, b.w);
    *(uint4*)(xh + base) = o;
}

// ---------------------------------------------------------------------------
// Init: acc_0 = gathered layer-0 embeddings + reg_sum from ORIGINAL weights.
// ---------------------------------------------------------------------------
__global__ void init_kernel(const float* __restrict__ uw, const float* __restrict__ iw,
                            const int* __restrict__ users, const int* __restrict__ pos,
                            const int* __restrict__ neg,
                            float* __restrict__ uacc, float* __restrict__ pacc,
                            float* __restrict__ nacc, float* __restrict__ reg_sum) {
    int tid = blockIdx.x * blockDim.x + threadIdx.x;
    int i = tid >> 4;
    int q = tid & 15;
    if (i >= BATCH) return;
    size_t o = (size_t)i * DIM + q * 4;
    float4 u = *(const float4*)(uw + (size_t)users[i] * DIM + q * 4);
    float4 p = *(const float4*)(iw + (size_t)pos[i]   * DIM + q * 4);
    float4 n = *(const float4*)(iw + (size_t)neg[i]   * DIM + q * 4);
    *(float4*)(uacc + o) = u;
    *(float4*)(pacc + o) = p;
    *(float4*)(nacc + o) = n;
    float ss = u.x*u.x + u.y*u.y + u.z*u.z + u.w*u.w
             + p.x*p.x + p.y*p.y + p.z*p.z + p.w*p.w
             + n.x*n.x + n.y*n.y + n.z*n.z + n.w*n.w;
    float bt = block_reduce_sum(ss);
    if (threadIdx.x == 0) unsafeAtomicAdd(reg_sum, bt);
}

// ---------------------------------------------------------------------------
// Mark rows needed by the final gather (layer-3 output consumers).
// ---------------------------------------------------------------------------
__global__ void flag_kernel(const int* __restrict__ users, const int* __restrict__ pos,
                            const int* __restrict__ neg, int* __restrict__ flags) {
    int tid = blockIdx.x * blockDim.x + threadIdx.x;
    if (tid < BATCH)               flags[users[tid]] = 1;
    else if (tid < 2 * BATCH)      flags[N_USERS + pos[tid - BATCH]] = 1;
    else if (tid < 3 * BATCH)      flags[N_USERS + neg[tid - 2 * BATCH]] = 1;
}

// ---------------------------------------------------------------------------
// Binned scatter into fixed-stride per-bucket regions (no pre-histogram).
// All global loads (rows, cols, vals) issued in phase 1; phase 3 is pure
// LDS-rank + store. Per-wave LDS hist; one packed 8B store per edge.
// packed c-field = col | (row_local << 18)   (col < 2^18, row_local < 512)
// ---------------------------------------------------------------------------
__global__ void binned_scatter_kernel(const int* __restrict__ rows, const int* __restrict__ cols,
                                      const float* __restrict__ vals, int* __restrict__ bcursor,
                                      Pair* __restrict__ bcv, int nnz) {
    __shared__ int h[8][HP];
    int t = threadIdx.x, w = t >> 6;
    for (int i = t; i < 8 * HP; i += 512) ((int*)h)[i] = 0;
    __syncthreads();
    long long tile = (long long)blockIdx.x * TILE_E;
    int er[EPT], cr[EPT];
    float vr[EPT];
    #pragma unroll
    for (int j = 0; j < EPT; ++j) {
        long long e = tile + t + j * 512;
        if (e < nnz) {
            int r = rows[e];
            er[j] = r;
            cr[j] = cols[e];
            vr[j] = vals[e];
            atomicAdd(&h[w][r >> 9], 1);
        } else er[j] = -1;
    }
    __syncthreads();
    // per-bucket: claim a contiguous run in the bucket's fixed region
    for (int b = t; b < NB; b += 512) {
        int cw[8], tot = 0;
        #pragma unroll
        for (int w2 = 0; w2 < 8; ++w2) { cw[w2] = h[w2][b]; tot += cw[w2]; }
        int base = tot ? (b * STRIDE + atomicAdd(&bcursor[b], tot)) : 0;
        #pragma unroll
        for (int w2 = 0; w2 < 8; ++w2) { h[w2][b] = base; base += cw[w2]; }
    }
    __syncthreads();
    #pragma unroll
    for (int j = 0; j < EPT; ++j) {
        if (er[j] >= 0) {
            int r = er[j];
            int dst = atomicAdd(&h[w][r >> 9], 1);
            Pair p;
            p.c = cr[j] | ((r & (RPB - 1)) << 18);
            p.v = vr[j];
            bcv[dst] = p;
        }
    }
}

// ---------------------------------------------------------------------------
// Post-scan: bucket counts (=bcursor) -> dense CSR bucket bases.
// ---------------------------------------------------------------------------
__global__ void post_scan_kernel(const int* __restrict__ counts, int* __restrict__ bbase,
                                 int* __restrict__ rowptr, int nnz) {
    __shared__ int sm[512];
    int t = threadIdx.x;
    int v = (t < NB) ? counts[t] : 0;
    sm[t] = v;
    __syncthreads();
    for (int off = 1; off < 512; off <<= 1) {
        int tmp = (t >= off) ? sm[t - off] : 0;
        __syncthreads();
        sm[t] += tmp;
        __syncthreads();
    }
    if (t < NB) bbase[t] = sm[t] - v;
    if (t == 511) bbase[NB] = sm[511];
    if (t == 0) rowptr[N_NODES] = nnz;
}

// ---------------------------------------------------------------------------
// Per-bucket counting sort in LDS -> final dense CSR perm + rowptr.
// Phase-1 hist uses 8-way wave replication to cut LDS atomic contention.
// ---------------------------------------------------------------------------
__global__ void bucket_sort_kernel(const Pair* __restrict__ bcv,
                                   const int* __restrict__ counts,
                                   const int* __restrict__ bbase,
                                   int* __restrict__ rowptr, Pair* __restrict__ perm) {
    __shared__ int rh8[8][RPB + 8];
    __shared__ int rh[RPB];
    __shared__ int sc[RPB];
    int blk = blockIdx.x;
    int t = threadIdx.x;        // 512 threads
    int w = t >> 6;
    int src  = blk * STRIDE;
    int base = bbase[blk];
    int cnt  = counts[blk];
    for (int i = t; i < 8 * (RPB + 8); i += 512) ((int*)rh8)[i] = 0;
    __syncthreads();
    for (int i = t; i < cnt; i += 512)
        atomicAdd(&rh8[w][(unsigned)bcv[src + i].c >> 18], 1);
    __syncthreads();
    int v = 0;
    #pragma unroll
    for (int w2 = 0; w2 < 8; ++w2) v += rh8[w2][t];
    sc[t] = v;
    __syncthreads();
    for (int off = 1; off < 512; off <<= 1) {
        int tmp = (t >= off) ? sc[t - off] : 0;
        __syncthreads();
        sc[t] += tmp;
        __syncthreads();
    }
    int excl = sc[t] - v;
    int g = blk * RPB + t;
    if (g < N_NODES) rowptr[g] = base + excl;
    rh[t] = excl;               // per-row cursor
    __syncthreads();
    for (int i = t; i < cnt; i += 512) {
        Pair p = bcv[src + i];
        int r = (unsigned)p.c >> 18;
        int rk = atomicAdd(&rh[r], 1);
        p.c &= 0x3FFFF;
        perm[base + rk] = p;
    }
}

// ---------------------------------------------------------------------------
// CSR SpMM, f16 in / f16 out (f32 accumulate via v_fma_mix). One wave per
// row; 8 groups of 8 lanes, each lane covers 8 dims with one 16B load;
// 4-edge unroll -> 32 edges in flight per wave. Cross-group shfl reduce.
// FLAGGED variant computes only rows marked in `flags` (layer 3).
// ---------------------------------------------------------------------------
template<bool FLAGGED>
__global__ void spmm_csr_f16_kernel(const unsigned short* __restrict__ xh,
                                    const Pair* __restrict__ pe,
                                    const int* __restrict__ rowptr,
                                    const int* __restrict__ flags,
                                    unsigned short* __restrict__ out) {
    int row  = blockIdx.x * 4 + (threadIdx.x >> 6);
    if (row >= N_NODES) return;
    if (FLAGGED && !flags[row]) return;
    int lane = threadIdx.x & 63;
    int g = lane >> 3;        // edge slot 0..7
    int q = lane & 7;         // 8-dim chunk
    int start = rowptr[row];
    int end   = rowptr[row + 1];
    float a0=0,a1=0,a2=0,a3=0,a4=0,a5=0,a6=0,a7=0;
    int e = start + g;
    for (; e + 24 < end; e += 32) {
        Pair p0 = pe[e];
        Pair p1 = pe[e + 8];
        Pair p2 = pe[e + 16];
        Pair p3 = pe[e + 24];
        uint4 x0 = *(const uint4*)(xh + (size_t)p0.c * DIM + q * 8);
        uint4 x1 = *(const uint4*)(xh + (size_t)p1.c * DIM + q * 8);
        uint4 x2 = *(const uint4*)(xh + (size_t)p2.c * DIM + q * 8);
        uint4 x3 = *(const uint4*)(xh + (size_t)p3.c * DIM + q * 8);
        EDGE_MIX(p0, x0);
        EDGE_MIX(p1, x1);
        EDGE_MIX(p2, x2);
        EDGE_MIX(p3, x3);
    }
    for (; e + 8 < end; e += 16) {
        Pair p0 = pe[e];
        Pair p1 = pe[e + 8];
        uint4 x0 = *(const uint4*)(xh + (size_t)p0.c * DIM + q * 8);
        uint4 x1 = *(const uint4*)(xh + (size_t)p1.c * DIM + q * 8);
        EDGE_MIX(p0, x0);
        EDGE_MIX(p1, x1);
    }
    for (; e < end; e += 8) {
        Pair p = pe[e];
        uint4 x = *(const uint4*)(xh + (size_t)p.c * DIM + q * 8);
        EDGE_MIX(p, x);
    }
    #pragma unroll
    for (int s = 8; s <= 32; s <<= 1) {
        a0 += __shfl_xor(a0, s, 64); a1 += __shfl_xor(a1, s, 64);
        a2 += __shfl_xor(a2, s, 64); a3 += __shfl_xor(a3, s, 64);
        a4 += __shfl_xor(a4, s, 64); a5 += __shfl_xor(a5, s, 64);
        a6 += __shfl_xor(a6, s, 64); a7 += __shfl_xor(a7, s, 64);
    }
    if (g == 0) {
        uint4 o;
        o.x = pkh(a0, a1);
        o.y = pkh(a2, a3);
        o.z = pkh(a4, a5);
        o.w = pkh(a6, a7);
        *(uint4*)(out + (size_t)row * DIM + q * 8) = o;
    }
}

// ---------------------------------------------------------------------------
// Legacy COO atomic SpMM (fallback when ws is too small for CSR buffers).
// ---------------------------------------------------------------------------
__global__ void spmm_atomic_kernel(const float* __restrict__ xu, const float* __restrict__ xi,
                                   const float* __restrict__ vals, const int* __restrict__ rows,
                                   const int* __restrict__ cols,
                                   float* __restrict__ out, int nnz) {
    long long tid = (long long)blockIdx.x * blockDim.x + threadIdx.x;
    int e = (int)(tid >> 4);
    if (e >= nnz) return;
    int q = (int)(tid & 15);
    int r = rows[e];
    int c = cols[e];
    float v = vals[e];
    const float* src = (c < N_USERS) ? (xu + (size_t)c * DIM)
                                     : (xi + (size_t)(c - N_USERS) * DIM);
    float4 x = *(const float4*)(src + q * 4);
    float* dst = out + (size_t)r * DIM + q * 4;
    unsafeAtomicAdd(dst + 0, v * x.x);
    unsafeAtomicAdd(dst + 1, v * x.y);
    unsafeAtomicAdd(dst + 2, v * x.z);
    unsafeAtomicAdd(dst + 3, v * x.w);
}

// ---------------------------------------------------------------------------
// Gather-accumulate a layer's f16 output at the batch rows only.
// ---------------------------------------------------------------------------
__global__ void gather_add_f16_kernel(const unsigned short* __restrict__ x,
                                      const int* __restrict__ users, const int* __restrict__ pos,
                                      const int* __restrict__ neg,
                                      float* __restrict__ uacc, float* __restrict__ pacc,
                                      float* __restrict__ nacc) {
    int tid = blockIdx.x * blockDim.x + threadIdx.x;
    int i = tid >> 4;
    int q = tid & 15;
    if (i >= BATCH) return;
    size_t o = (size_t)i * DIM + q * 4;
    float4 a;
    uint2 u;

    a = *(float4*)(uacc + o);
    u = *(const uint2*)(x + (size_t)users[i] * DIM + q * 4);
    a.x += h2f(u.x & 0xffff); a.y += h2f(u.x >> 16);
    a.z += h2f(u.y & 0xffff); a.w += h2f(u.y >> 16);
    *(float4*)(uacc + o) = a;

    a = *(float4*)(pacc + o);
    u = *(const uint2*)(x + (size_t)(N_USERS + pos[i]) * DIM + q * 4);
    a.x += h2f(u.x & 0xffff); a.y += h2f(u.x >> 16);
    a.z += h2f(u.y & 0xffff); a.w += h2f(u.y >> 16);
    *(float4*)(pacc + o) = a;

    a = *(float4*)(nacc + o);
    u = *(const uint2*)(x + (size_t)(N_USERS + neg[i]) * DIM + q * 4);
    a.x += h2f(u.x & 0xffff); a.y += h2f(u.x >> 16);
    a.z += h2f(u.y & 0xffff); a.w += h2f(u.y >> 16);
    *(float4*)(nacc + o) = a;
}

// ---------------------------------------------------------------------------
// Fused layer-3 gather + BPR score. final = acc/4, so dot scales by 1/16.
// ---------------------------------------------------------------------------
__global__ void gather_score_kernel(const unsigned short* __restrict__ x,
                                    const int* __restrict__ users, const int* __restrict__ pos,
                                    const int* __restrict__ neg,
                                    const float* __restrict__ uacc, const float* __restrict__ pacc,
                                    const float* __restrict__ nacc, float* __restrict__ loss_sum) {
    int tid = blockIdx.x * blockDim.x + threadIdx.x;
    int i = tid >> 4;
    int q = tid & 15;
    float ps = 0.0f, ns = 0.0f;
    if (i < BATCH) {
        size_t o = (size_t)i * DIM + q * 4;
        float4 u = *(const float4*)(uacc + o);
        float4 p = *(const float4*)(pacc + o);
        float4 n = *(const float4*)(nacc + o);
        uint2 t;
        t = *(const uint2*)(x + (size_t)users[i] * DIM + q * 4);
        u.x += h2f(t.x & 0xffff); u.y += h2f(t.x >> 16);
        u.z += h2f(t.y & 0xffff); u.w += h2f(t.y >> 16);
        t = *(const uint2*)(x + (size_t)(N_USERS + pos[i]) * DIM + q * 4);
        p.x += h2f(t.x & 0xffff); p.y += h2f(t.x >> 16);
        p.z += h2f(t.y & 0xffff); p.w += h2f(t.y >> 16);
        t = *(const uint2*)(x + (size_t)(N_USERS + neg[i]) * DIM + q * 4);
        n.x += h2f(t.x & 0xffff); n.y += h2f(t.x >> 16);
        n.z += h2f(t.y & 0xffff); n.w += h2f(t.y >> 16);
        ps = u.x*p.x + u.y*p.y + u.z*p.z + u.w*p.w;
        ns = u.x*n.x + u.y*n.y + u.z*n.z + u.w*n.w;
    }
    for (int s = 8; s > 0; s >>= 1) {
        ps += __shfl_xor(ps, s, 16);
        ns += __shfl_xor(ns, s, 16);
    }
    float term = 0.0f;
    if (q == 0 && i < BATCH) {
        float d = (ps - ns) * (1.0f / 16.0f);
        float sig = 1.0f / (1.0f + expf(-d));
        term = logf(sig + 1e-8f);
    }
    float bt = block_reduce_sum(term);
    if (threadIdx.x == 0) unsafeAtomicAdd(loss_sum, bt);
}

// f32 gather-add + score (fallback path)
__global__ void gather_add_kernel(const float* __restrict__ x,
                                  const int* __restrict__ users, const int* __restrict__ pos,
                                  const int* __restrict__ neg,
                                  float* __restrict__ uacc, float* __restrict__ pacc,
                                  float* __restrict__ nacc) {
    int tid = blockIdx.x * blockDim.x + threadIdx.x;
    int i = tid >> 4;
    int q = tid & 15;
    if (i >= BATCH) return;
    size_t o = (size_t)i * DIM + q * 4;
    float4 a, b;
    a = *(float4*)(uacc + o);
    b = *(const float4*)(x + (size_t)users[i] * DIM + q * 4);
    a.x += b.x; a.y += b.y; a.z += b.z; a.w += b.w;
    *(float4*)(uacc + o) = a;
    a = *(float4*)(pacc + o);
    b = *(const float4*)(x + (size_t)(N_USERS + pos[i]) * DIM + q * 4);
    a.x += b.x; a.y += b.y; a.z += b.z; a.w += b.w;
    *(float4*)(pacc + o) = a;
    a = *(float4*)(nacc + o);
    b = *(const float4*)(x + (size_t)(N_USERS + neg[i]) * DIM + q * 4);
    a.x += b.x; a.y += b.y; a.z += b.z; a.w += b.w;
    *(float4*)(nacc + o) = a;
}

__global__ void score_kernel(const float* __restrict__ uacc, const float* __restrict__ pacc,
                             const float* __restrict__ nacc, float* __restrict__ loss_sum) {
    int tid = blockIdx.x * blockDim.x + threadIdx.x;
    int i = tid >> 4;
    int q = tid & 15;
    float ps = 0.0f, ns = 0.0f;
    if (i < BATCH) {
        size_t o = (size_t)i * DIM + q * 4;
        float4 u = *(const float4*)(uacc + o);
        float4 p = *(const float4*)(pacc + o);
        float4 n = *(const float4*)(nacc + o);
        ps = u.x*p.x + u.y*p.y + u.z*p.z + u.w*p.w;
        ns = u.x*n.x + u.y*n.y + u.z*n.z + u.w*n.w;
    }
    for (int s = 8; s > 0; s >>= 1) {
        ps += __shfl_xor(ps, s, 16);
        ns += __shfl_xor(ns, s, 16);
    }
    float term = 0.0f;
    if (q == 0 && i < BATCH) {
        float d = (ps - ns) * (1.0f / 16.0f);
        float sig = 1.0f / (1.0f + expf(-d));
        term = logf(sig + 1e-8f);
    }
    float bt = block_reduce_sum(term);
    if (threadIdx.x == 0) unsafeAtomicAdd(loss_sum, bt);
}

__global__ void finalize_kernel(const float* __restrict__ sums, float* __restrict__ out) {
    if (threadIdx.x == 0 && blockIdx.x == 0) {
        out[0] = -sums[0] / (float)BATCH;
        out[1] =  sums[1] / (float)BATCH;
    }
}

static inline size_t align256(size_t x) { return (x + 255) & ~(size_t)255; }

extern "C" void kernel_launch(void* const* d_in, const int* in_sizes, int n_in,
                              void* d_out, int out_size, void* d_ws, size_t ws_size,
                              hipStream_t stream) {
    const float* uw   = (const float*)d_in[0];
    const float* iw   = (const float*)d_in[1];
    const float* vals = (const float*)d_in[2];
    const int*   rows = (const int*)d_in[3];
    const int*   cols = (const int*)d_in[4];
    const int*   users = (const int*)d_in[5];
    const int*   pos   = (const int*)d_in[6];
    const int*   neg   = (const int*)d_in[7];
    const int nnz = in_sizes[2];

    char* ws = (char*)d_ws;
    const size_t nodeBytes = (size_t)N_NODES * DIM * sizeof(float);          // 38.4 MB
    const size_t hBytes    = (size_t)N_NODES * DIM * sizeof(unsigned short); // 19.2 MB
    const size_t accBytes  = (size_t)BATCH * DIM * sizeof(float);

    size_t off = 0;
    char*  nodeReg = ws + off;            off += align256(2 * nodeBytes);    // 76.8 MB region
    float* uacc = (float*)(ws + off);     off += align256(accBytes);
    float* pacc = (float*)(ws + off);     off += align256(accBytes);
    float* nacc = (float*)(ws + off);     off += align256(accBytes);
    float* sums = (float*)(ws + off);     off += 256;   // [0]=loss, [1]=reg
    Pair*  perm = (Pair*)(ws + off);      off += align256((size_t)nnz * sizeof(Pair));
    int*   rowptr = (int*)(ws + off);     off += align256((size_t)(N_NODES + 1) * sizeof(int));
    int*   bbase  = (int*)(ws + off);     off += align256((size_t)(NB + 1) * sizeof(int));
    int*   bcursor= (int*)(ws + off);     off += align256((size_t)NB * sizeof(int));
    int*   flags  = (int*)(ws + off);     off += align256((size_t)N_NODES * sizeof(int));
    // bcv fixed-stride region aliases xb2's slot + spare (consumed before xb2 is written)
    const bool fits_alias = (2 * align256(hBytes) + (size_t)NB * STRIDE * sizeof(Pair)) <= 2 * nodeBytes;
    const bool use_csr = (off <= ws_size) && fits_alias && (N_NODES < (1 << 18));

    unsigned short* xb0 = (unsigned short*)nodeReg;
    unsigned short* xb1 = (unsigned short*)(nodeReg + align256(hBytes));
    unsigned short* xb2 = (unsigned short*)(nodeReg + 2 * align256(hBytes));
    Pair*           bcv = (Pair*)(nodeReg + 2 * align256(hBytes));
    // fallback f32 views of the same region
    float* xA = (float*)nodeReg;
    float* xB = (float*)(nodeReg + nodeBytes);

    float* out = (float*)d_out;

    const int bthreads = BATCH * 16;
    const int bblocks  = bthreads / 256;
    const int tblocks  = (nnz + TILE_E - 1) / TILE_E;
    const int cblocks  = (int)(((size_t)N_NODES * DIM / 8 + 255) / 256);

    (void)hipMemsetAsync(sums, 0, 2 * sizeof(float), stream);
    init_kernel<<<bblocks, 256, 0, stream>>>(uw, iw, users, pos, neg, uacc, pacc, nacc, sums + 1);

    if (use_csr) {
        // ---- CSR build: binned scatter (fixed regions) -> scan -> LDS sort ----
        (void)hipMemsetAsync(bcursor, 0, (size_t)NB * sizeof(int), stream);
        (void)hipMemsetAsync(flags, 0, (size_t)N_NODES * sizeof(int), stream);
        flag_kernel<<<(3 * BATCH + 255) / 256, 256, 0, stream>>>(users, pos, neg, flags);
        convert_kernel<<<cblocks, 256, 0, stream>>>(uw, iw, xb0);
        binned_scatter_kernel<<<tblocks, 512, 0, stream>>>(rows, cols, vals, bcursor, bcv, nnz);
        post_scan_kernel<<<1, 512, 0, stream>>>(bcursor, bbase, rowptr, nnz);
        bucket_sort_kernel<<<NB, 512, 0, stream>>>(bcv, bcursor, bbase, rowptr, perm);

        const int sblocks = (N_NODES + 3) / 4;
        // Layer 1: xb0 -> xb1
        spmm_csr_f16_kernel<false><<<sblocks, 256, 0, stream>>>(xb0, perm, rowptr, flags, xb1);
        gather_add_f16_kernel<<<bblocks, 256, 0, stream>>>(xb1, users, pos, neg, uacc, pacc, nacc);
        // Layer 2: xb1 -> xb2 (bcv dead after sort)
        spmm_csr_f16_kernel<false><<<sblocks, 256, 0, stream>>>(xb1, perm, rowptr, flags, xb2);
        gather_add_f16_kernel<<<bblocks, 256, 0, stream>>>(xb2, users, pos, neg, uacc, pacc, nacc);
        // Layer 3: xb2 -> xb0, only needed rows; fused gather+score epilogue
        spmm_csr_f16_kernel<true><<<sblocks, 256, 0, stream>>>(xb2, perm, rowptr, flags, xb0);
        gather_score_kernel<<<bblocks, 256, 0, stream>>>(xb0, users, pos, neg, uacc, pacc, nacc, sums);
    } else {
        // ---- Fallback: COO atomic path (f32) ----
        const long long sthreads = (long long)nnz * 16;
        const int sblocks = (int)((sthreads + 255) / 256);
        (void)hipMemsetAsync(xA, 0, nodeBytes, stream);
        spmm_atomic_kernel<<<sblocks, 256, 0, stream>>>(uw, iw, vals, rows, cols, xA, nnz);
        gather_add_kernel<<<bblocks, 256, 0, stream>>>(xA, users, pos, neg, uacc, pacc, nacc);
        (void)hipMemsetAsync(xB, 0, nodeBytes, stream);
        spmm_atomic_kernel<<<sblocks, 256, 0, stream>>>(xA, xA + (size_t)N_USERS * DIM, vals, rows, cols, xB, nnz);
        gather_add_kernel<<<bblocks, 256, 0, stream>>>(xB, users, pos, neg, uacc, pacc, nacc);
        (void)hipMemsetAsync(xA, 0, nodeBytes, stream);
        spmm_atomic_kernel<<<sblocks, 256, 0, stream>>>(xB, xB + (size_t)N_USERS * DIM, vals, rows, cols, xA, nnz);
        gather_add_kernel<<<bblocks, 256, 0, stream>>>(xA, users, pos, neg, uacc, pacc, nacc);
        score_kernel<<<bblocks, 256, 0, stream>>>(uacc, pacc, nacc, sums);
    }

    finalize_kernel<<<1, 1, 0, stream>>>(sums, out);
}

// Round 10
// 267.835 us; speedup vs baseline: 22.8934x; 1.0479x over previous
//
#include <hip/hip_runtime.h>

#define N_USERS 100000
#define N_ITEMS 50000
#define N_NODES (N_USERS + N_ITEMS)
#define DIM 64
#define BATCH 16384
#define RPB 512                          // rows per bucket
#define NB ((N_NODES + RPB - 1) / RPB)   // 293 buckets
#define HP 296                           // padded hist stride (bank stagger)
#define EPT 8                            // edges per thread in scatter
#define TILE_E (512 * EPT)               // 4096 edges per scatter block
#define STRIDE 12288                     // bcv region stride per bucket
#define XSCALE 64.0f                     // fp8 storage scale
#define INV_XSCALE 0.015625f             // 1/64

struct __align__(8) Pair { int c; float v; };
typedef float floatx2 __attribute__((ext_vector_type(2)));

// ---- fp8 helpers (e4m3, gfx940+ builtins) ---------------------------------
__device__ __forceinline__ unsigned pk8(float a, float b, float c, float d) {
    int w = __builtin_amdgcn_cvt_pk_fp8_f32(a, b, 0, false);
    w = __builtin_amdgcn_cvt_pk_fp8_f32(c, d, w, true);
    return (unsigned)w;
}

#define EDGE_F8(P, X) { \
    floatx2 d01 = __builtin_amdgcn_cvt_pk_f32_fp8((X).x, false); \
    floatx2 d23 = __builtin_amdgcn_cvt_pk_f32_fp8((X).x, true); \
    floatx2 d45 = __builtin_amdgcn_cvt_pk_f32_fp8((X).y, false); \
    floatx2 d67 = __builtin_amdgcn_cvt_pk_f32_fp8((X).y, true); \
    a0 = fmaf((P).v, d01.x, a0); a1 = fmaf((P).v, d01.y, a1); \
    a2 = fmaf((P).v, d23.x, a2); a3 = fmaf((P).v, d23.y, a3); \
    a4 = fmaf((P).v, d45.x, a4); a5 = fmaf((P).v, d45.y, a5); \
    a6 = fmaf((P).v, d67.x, a6); a7 = fmaf((P).v, d67.y, a7); }

// ---------------------------------------------------------------------------
__device__ __forceinline__ float block_reduce_sum(float v) {
    for (int s = 32; s > 0; s >>= 1) v += __shfl_xor(v, s, 64);
    __shared__ float sm[8];
    int lane = threadIdx.x & 63;
    int wid  = threadIdx.x >> 6;
    if (lane == 0) sm[wid] = v;
    __syncthreads();
    float t = 0.0f;
    if (threadIdx.x == 0) {
        int nw = (blockDim.x + 63) >> 6;
        for (int w = 0; w < nw; ++w) t += sm[w];
    }
    return t;
}

// ---------------------------------------------------------------------------
// Convert concat [uw;iw] f32 -> fp8 (x64 scale). Also clears flags + bcursor
// (folded to save two memset dispatches).
// ---------------------------------------------------------------------------
__global__ void convert_kernel(const float* __restrict__ uw, const float* __restrict__ iw,
                               unsigned char* __restrict__ x8,
                               int* __restrict__ flags, int* __restrict__ bcursor) {
    size_t tid = (size_t)blockIdx.x * 256 + threadIdx.x;
    if (tid < N_NODES) flags[tid] = 0;
    else if (tid < N_NODES + NB) bcursor[tid - N_NODES] = 0;
    size_t base = tid * 8;
    if (base >= (size_t)N_NODES * DIM) return;
    const float* src = (base < (size_t)N_USERS * DIM) ? uw + base
                                                      : iw + (base - (size_t)N_USERS * DIM);
    float4 a = ((const float4*)src)[0];
    float4 b = ((const float4*)src)[1];
    uint2 o;
    o.x = pk8(XSCALE * a.x, XSCALE * a.y, XSCALE * a.z, XSCALE * a.w);
    o.y = pk8(XSCALE * b.x, XSCALE * b.y, XSCALE * b.z, XSCALE * b.w);
    *(uint2*)(x8 + base) = o;
}

// ---------------------------------------------------------------------------
// Init: acc_0 = gathered layer-0 embeddings + reg_sum from ORIGINAL weights.
// ---------------------------------------------------------------------------
__global__ void init_kernel(const float* __restrict__ uw, const float* __restrict__ iw,
                            const int* __restrict__ users, const int* __restrict__ pos,
                            const int* __restrict__ neg,
                            float* __restrict__ uacc, float* __restrict__ pacc,
                            float* __restrict__ nacc, float* __restrict__ reg_sum) {
    int tid = blockIdx.x * blockDim.x + threadIdx.x;
    int i = tid >> 4;
    int q = tid & 15;
    if (i >= BATCH) return;
    size_t o = (size_t)i * DIM + q * 4;
    float4 u = *(const float4*)(uw + (size_t)users[i] * DIM + q * 4);
    float4 p = *(const float4*)(iw + (size_t)pos[i]   * DIM + q * 4);
    float4 n = *(const float4*)(iw + (size_t)neg[i]   * DIM + q * 4);
    *(float4*)(uacc + o) = u;
    *(float4*)(pacc + o) = p;
    *(float4*)(nacc + o) = n;
    float ss = u.x*u.x + u.y*u.y + u.z*u.z + u.w*u.w
             + p.x*p.x + p.y*p.y + p.z*p.z + p.w*p.w
             + n.x*n.x + n.y*n.y + n.z*n.z + n.w*n.w;
    float bt = block_reduce_sum(ss);
    if (threadIdx.x == 0) unsafeAtomicAdd(reg_sum, bt);
}

// ---------------------------------------------------------------------------
// Mark rows needed by the final gather; also zero the loss/reg sums.
// ---------------------------------------------------------------------------
__global__ void flag_kernel(const int* __restrict__ users, const int* __restrict__ pos,
                            const int* __restrict__ neg, int* __restrict__ flags,
                            float* __restrict__ sums) {
    int tid = blockIdx.x * blockDim.x + threadIdx.x;
    if (blockIdx.x == 0 && threadIdx.x < 2) sums[threadIdx.x] = 0.0f;
    if (tid < BATCH)               flags[users[tid]] = 1;
    else if (tid < 2 * BATCH)      flags[N_USERS + pos[tid - BATCH]] = 1;
    else if (tid < 3 * BATCH)      flags[N_USERS + neg[tid - 2 * BATCH]] = 1;
}

// ---------------------------------------------------------------------------
// Binned scatter into fixed-stride per-bucket regions. All global loads in
// phase 1; per-wave LDS hist; one packed 8B store per edge.
// packed c-field = col | (row_local << 18)
// ---------------------------------------------------------------------------
__global__ void binned_scatter_kernel(const int* __restrict__ rows, const int* __restrict__ cols,
                                      const float* __restrict__ vals, int* __restrict__ bcursor,
                                      Pair* __restrict__ bcv, int nnz) {
    __shared__ int h[8][HP];
    int t = threadIdx.x, w = t >> 6;
    for (int i = t; i < 8 * HP; i += 512) ((int*)h)[i] = 0;
    __syncthreads();
    long long tile = (long long)blockIdx.x * TILE_E;
    int er[EPT], cr[EPT];
    float vr[EPT];
    #pragma unroll
    for (int j = 0; j < EPT; ++j) {
        long long e = tile + t + j * 512;
        if (e < nnz) {
            int r = rows[e];
            er[j] = r;
            cr[j] = cols[e];
            vr[j] = vals[e];
            atomicAdd(&h[w][r >> 9], 1);
        } else er[j] = -1;
    }
    __syncthreads();
    for (int b = t; b < NB; b += 512) {
        int cw[8], tot = 0;
        #pragma unroll
        for (int w2 = 0; w2 < 8; ++w2) { cw[w2] = h[w2][b]; tot += cw[w2]; }
        int base = tot ? (b * STRIDE + atomicAdd(&bcursor[b], tot)) : 0;
        #pragma unroll
        for (int w2 = 0; w2 < 8; ++w2) { h[w2][b] = base; base += cw[w2]; }
    }
    __syncthreads();
    #pragma unroll
    for (int j = 0; j < EPT; ++j) {
        if (er[j] >= 0) {
            int r = er[j];
            int dst = atomicAdd(&h[w][r >> 9], 1);
            Pair p;
            p.c = cr[j] | ((r & (RPB - 1)) << 18);
            p.v = vr[j];
            bcv[dst] = p;
        }
    }
}

// ---------------------------------------------------------------------------
// Post-scan: bucket counts -> dense CSR bucket bases.
// ---------------------------------------------------------------------------
__global__ void post_scan_kernel(const int* __restrict__ counts, int* __restrict__ bbase,
                                 int* __restrict__ rowptr, int nnz) {
    __shared__ int sm[512];
    int t = threadIdx.x;
    int v = (t < NB) ? counts[t] : 0;
    sm[t] = v;
    __syncthreads();
    for (int off = 1; off < 512; off <<= 1) {
        int tmp = (t >= off) ? sm[t - off] : 0;
        __syncthreads();
        sm[t] += tmp;
        __syncthreads();
    }
    if (t < NB) bbase[t] = sm[t] - v;
    if (t == 511) bbase[NB] = sm[511];
    if (t == 0) rowptr[N_NODES] = nnz;
}

// ---------------------------------------------------------------------------
// Per-bucket counting sort in LDS -> final dense CSR perm + rowptr.
// ---------------------------------------------------------------------------
__global__ void bucket_sort_kernel(const Pair* __restrict__ bcv,
                                   const int* __restrict__ counts,
                                   const int* __restrict__ bbase,
                                   int* __restrict__ rowptr, Pair* __restrict__ perm) {
    __shared__ int rh8[8][RPB + 8];
    __shared__ int rh[RPB];
    __shared__ int sc[RPB];
    int blk = blockIdx.x;
    int t = threadIdx.x;        // 512 threads
    int w = t >> 6;
    int src  = blk * STRIDE;
    int base = bbase[blk];
    int cnt  = counts[blk];
    for (int i = t; i < 8 * (RPB + 8); i += 512) ((int*)rh8)[i] = 0;
    __syncthreads();
    for (int i = t; i < cnt; i += 512)
        atomicAdd(&rh8[w][(unsigned)bcv[src + i].c >> 18], 1);
    __syncthreads();
    int v = 0;
    #pragma unroll
    for (int w2 = 0; w2 < 8; ++w2) v += rh8[w2][t];
    sc[t] = v;
    __syncthreads();
    for (int off = 1; off < 512; off <<= 1) {
        int tmp = (t >= off) ? sc[t - off] : 0;
        __syncthreads();
        sc[t] += tmp;
        __syncthreads();
    }
    int excl = sc[t] - v;
    int g = blk * RPB + t;
    if (g < N_NODES) rowptr[g] = base + excl;
    rh[t] = excl;
    __syncthreads();
    for (int i = t; i < cnt; i += 512) {
        Pair p = bcv[src + i];
        int r = (unsigned)p.c >> 18;
        int rk = atomicAdd(&rh[r], 1);
        p.c &= 0x3FFFF;
        perm[base + rk] = p;
    }
}

// ---------------------------------------------------------------------------
// CSR SpMM, fp8 in / fp8 out (f32 accumulate, x64 scale passthrough).
// One wave per row; 8 groups of 8 lanes; each lane covers 8 dims via one
// 8B load (row = 64B = one cache line). 2-edge unroll.
// ---------------------------------------------------------------------------
template<bool FLAGGED>
__global__ void spmm_csr_f8_kernel(const unsigned char* __restrict__ x8,
                                   const Pair* __restrict__ pe,
                                   const int* __restrict__ rowptr,
                                   const int* __restrict__ flags,
                                   unsigned char* __restrict__ out8) {
    int row  = blockIdx.x * 4 + (threadIdx.x >> 6);
    if (row >= N_NODES) return;
    if (FLAGGED && !flags[row]) return;
    int lane = threadIdx.x & 63;
    int g = lane >> 3;        // edge slot 0..7
    int q = lane & 7;         // 8-dim chunk (8 bytes)
    int start = rowptr[row];
    int end   = rowptr[row + 1];
    float a0=0,a1=0,a2=0,a3=0,a4=0,a5=0,a6=0,a7=0;
    int e = start + g;
    for (; e + 8 < end; e += 16) {
        Pair p0 = pe[e];
        Pair p1 = pe[e + 8];
        uint2 x0 = *(const uint2*)(x8 + ((size_t)p0.c << 6) + q * 8);
        uint2 x1 = *(const uint2*)(x8 + ((size_t)p1.c << 6) + q * 8);
        EDGE_F8(p0, x0);
        EDGE_F8(p1, x1);
    }
    for (; e < end; e += 8) {
        Pair p = pe[e];
        uint2 x = *(const uint2*)(x8 + ((size_t)p.c << 6) + q * 8);
        EDGE_F8(p, x);
    }
    #pragma unroll
    for (int s = 8; s <= 32; s <<= 1) {
        a0 += __shfl_xor(a0, s, 64); a1 += __shfl_xor(a1, s, 64);
        a2 += __shfl_xor(a2, s, 64); a3 += __shfl_xor(a3, s, 64);
        a4 += __shfl_xor(a4, s, 64); a5 += __shfl_xor(a5, s, 64);
        a6 += __shfl_xor(a6, s, 64); a7 += __shfl_xor(a7, s, 64);
    }
    if (g == 0) {
        uint2 o;
        o.x = pk8(a0, a1, a2, a3);
        o.y = pk8(a4, a5, a6, a7);
        *(uint2*)(out8 + ((size_t)row << 6) + q * 8) = o;
    }
}

// ---------------------------------------------------------------------------
// Legacy COO atomic SpMM (fallback).
// ---------------------------------------------------------------------------
__global__ void spmm_atomic_kernel(const float* __restrict__ xu, const float* __restrict__ xi,
                                   const float* __restrict__ vals, const int* __restrict__ rows,
                                   const int* __restrict__ cols,
                                   float* __restrict__ out, int nnz) {
    long long tid = (long long)blockIdx.x * blockDim.x + threadIdx.x;
    int e = (int)(tid >> 4);
    if (e >= nnz) return;
    int q = (int)(tid & 15);
    int r = rows[e];
    int c = cols[e];
    float v = vals[e];
    const float* src = (c < N_USERS) ? (xu + (size_t)c * DIM)
                                     : (xi + (size_t)(c - N_USERS) * DIM);
    float4 x = *(const float4*)(src + q * 4);
    float* dst = out + (size_t)r * DIM + q * 4;
    unsafeAtomicAdd(dst + 0, v * x.x);
    unsafeAtomicAdd(dst + 1, v * x.y);
    unsafeAtomicAdd(dst + 2, v * x.z);
    unsafeAtomicAdd(dst + 3, v * x.w);
}

// ---------------------------------------------------------------------------
// Gather-accumulate a layer's fp8 output at the batch rows only (unscale).
// ---------------------------------------------------------------------------
__global__ void gather_add_f8_kernel(const unsigned char* __restrict__ x8,
                                     const int* __restrict__ users, const int* __restrict__ pos,
                                     const int* __restrict__ neg,
                                     float* __restrict__ uacc, float* __restrict__ pacc,
                                     float* __restrict__ nacc) {
    int tid = blockIdx.x * blockDim.x + threadIdx.x;
    int i = tid >> 4;
    int q = tid & 15;
    if (i >= BATCH) return;
    size_t o = (size_t)i * DIM + q * 4;
    float4 a;
    unsigned u;
    floatx2 lo, hi;

    a = *(float4*)(uacc + o);
    u = *(const unsigned*)(x8 + ((size_t)users[i] << 6) + q * 4);
    lo = __builtin_amdgcn_cvt_pk_f32_fp8(u, false);
    hi = __builtin_amdgcn_cvt_pk_f32_fp8(u, true);
    a.x = fmaf(lo.x, INV_XSCALE, a.x); a.y = fmaf(lo.y, INV_XSCALE, a.y);
    a.z = fmaf(hi.x, INV_XSCALE, a.z); a.w = fmaf(hi.y, INV_XSCALE, a.w);
    *(float4*)(uacc + o) = a;

    a = *(float4*)(pacc + o);
    u = *(const unsigned*)(x8 + ((size_t)(N_USERS + pos[i]) << 6) + q * 4);
    lo = __builtin_amdgcn_cvt_pk_f32_fp8(u, false);
    hi = __builtin_amdgcn_cvt_pk_f32_fp8(u, true);
    a.x = fmaf(lo.x, INV_XSCALE, a.x); a.y = fmaf(lo.y, INV_XSCALE, a.y);
    a.z = fmaf(hi.x, INV_XSCALE, a.z); a.w = fmaf(hi.y, INV_XSCALE, a.w);
    *(float4*)(pacc + o) = a;

    a = *(float4*)(nacc + o);
    u = *(const unsigned*)(x8 + ((size_t)(N_USERS + neg[i]) << 6) + q * 4);
    lo = __builtin_amdgcn_cvt_pk_f32_fp8(u, false);
    hi = __builtin_amdgcn_cvt_pk_f32_fp8(u, true);
    a.x = fmaf(lo.x, INV_XSCALE, a.x); a.y = fmaf(lo.y, INV_XSCALE, a.y);
    a.z = fmaf(hi.x, INV_XSCALE, a.z); a.w = fmaf(hi.y, INV_XSCALE, a.w);
    *(float4*)(nacc + o) = a;
}

// ---------------------------------------------------------------------------
// Fused layer-3 gather + BPR score. final = acc/4, so dot scales by 1/16.
// ---------------------------------------------------------------------------
__global__ void gather_score_kernel(const unsigned char* __restrict__ x8,
                                    const int* __restrict__ users, const int* __restrict__ pos,
                                    const int* __restrict__ neg,
                                    const float* __restrict__ uacc, const float* __restrict__ pacc,
                                    const float* __restrict__ nacc, float* __restrict__ loss_sum) {
    int tid = blockIdx.x * blockDim.x + threadIdx.x;
    int i = tid >> 4;
    int q = tid & 15;
    float ps = 0.0f, ns = 0.0f;
    if (i < BATCH) {
        size_t o = (size_t)i * DIM + q * 4;
        float4 u = *(const float4*)(uacc + o);
        float4 p = *(const float4*)(pacc + o);
        float4 n = *(const float4*)(nacc + o);
        unsigned t;
        floatx2 lo, hi;
        t = *(const unsigned*)(x8 + ((size_t)users[i] << 6) + q * 4);
        lo = __builtin_amdgcn_cvt_pk_f32_fp8(t, false);
        hi = __builtin_amdgcn_cvt_pk_f32_fp8(t, true);
        u.x = fmaf(lo.x, INV_XSCALE, u.x); u.y = fmaf(lo.y, INV_XSCALE, u.y);
        u.z = fmaf(hi.x, INV_XSCALE, u.z); u.w = fmaf(hi.y, INV_XSCALE, u.w);
        t = *(const unsigned*)(x8 + ((size_t)(N_USERS + pos[i]) << 6) + q * 4);
        lo = __builtin_amdgcn_cvt_pk_f32_fp8(t, false);
        hi = __builtin_amdgcn_cvt_pk_f32_fp8(t, true);
        p.x = fmaf(lo.x, INV_XSCALE, p.x); p.y = fmaf(lo.y, INV_XSCALE, p.y);
        p.z = fmaf(hi.x, INV_XSCALE, p.z); p.w = fmaf(hi.y, INV_XSCALE, p.w);
        t = *(const unsigned*)(x8 + ((size_t)(N_USERS + neg[i]) << 6) + q * 4);
        lo = __builtin_amdgcn_cvt_pk_f32_fp8(t, false);
        hi = __builtin_amdgcn_cvt_pk_f32_fp8(t, true);
        n.x = fmaf(lo.x, INV_XSCALE, n.x); n.y = fmaf(lo.y, INV_XSCALE, n.y);
        n.z = fmaf(hi.x, INV_XSCALE, n.z); n.w = fmaf(hi.y, INV_XSCALE, n.w);
        ps = u.x*p.x + u.y*p.y + u.z*p.z + u.w*p.w;
        ns = u.x*n.x + u.y*n.y + u.z*n.z + u.w*n.w;
    }
    for (int s = 8; s > 0; s >>= 1) {
        ps += __shfl_xor(ps, s, 16);
        ns += __shfl_xor(ns, s, 16);
    }
    float term = 0.0f;
    if (q == 0 && i < BATCH) {
        float d = (ps - ns) * (1.0f / 16.0f);
        float sig = 1.0f / (1.0f + expf(-d));
        term = logf(sig + 1e-8f);
    }
    float bt = block_reduce_sum(term);
    if (threadIdx.x == 0) unsafeAtomicAdd(loss_sum, bt);
}

// f32 gather-add + score (fallback path)
__global__ void gather_add_kernel(const float* __restrict__ x,
                                  const int* __restrict__ users, const int* __restrict__ pos,
                                  const int* __restrict__ neg,
                                  float* __restrict__ uacc, float* __restrict__ pacc,
                                  float* __restrict__ nacc) {
    int tid = blockIdx.x * blockDim.x + threadIdx.x;
    int i = tid >> 4;
    int q = tid & 15;
    if (i >= BATCH) return;
    size_t o = (size_t)i * DIM + q * 4;
    float4 a, b;
    a = *(float4*)(uacc + o);
    b = *(const float4*)(x + (size_t)users[i] * DIM + q * 4);
    a.x += b.x; a.y += b.y; a.z += b.z; a.w += b.w;
    *(float4*)(uacc + o) = a;
    a = *(float4*)(pacc + o);
    b = *(const float4*)(x + (size_t)(N_USERS + pos[i]) * DIM + q * 4);
    a.x += b.x; a.y += b.y; a.z += b.z; a.w += b.w;
    *(float4*)(pacc + o) = a;
    a = *(float4*)(nacc + o);
    b = *(const float4*)(x + (size_t)(N_USERS + neg[i]) * DIM + q * 4);
    a.x += b.x; a.y += b.y; a.z += b.z; a.w += b.w;
    *(float4*)(nacc + o) = a;
}

__global__ void score_kernel(const float* __restrict__ uacc, const float* __restrict__ pacc,
                             const float* __restrict__ nacc, float* __restrict__ loss_sum) {
    int tid = blockIdx.x * blockDim.x + threadIdx.x;
    int i = tid >> 4;
    int q = tid & 15;
    float ps = 0.0f, ns = 0.0f;
    if (i < BATCH) {
        size_t o = (size_t)i * DIM + q * 4;
        float4 u = *(const float4*)(uacc + o);
        float4 p = *(const float4*)(pacc + o);
        float4 n = *(const float4*)(nacc + o);
        ps = u.x*p.x + u.y*p.y + u.z*p.z + u.w*p.w;
        ns = u.x*n.x + u.y*n.y + u.z*n.z + u.w*n.w;
    }
    for (int s = 8; s > 0; s >>= 1) {
        ps += __shfl_xor(ps, s, 16);
        ns += __shfl_xor(ns, s, 16);
    }
    float term = 0.0f;
    if (q == 0 && i < BATCH) {
        float d = (ps - ns) * (1.0f / 16.0f);
        float sig = 1.0f / (1.0f + expf(-d));
        term = logf(sig + 1e-8f);
    }
    float bt = block_reduce_sum(term);
    if (threadIdx.x == 0) unsafeAtomicAdd(loss_sum, bt);
}

__global__ void finalize_kernel(const float* __restrict__ sums, float* __restrict__ out) {
    if (threadIdx.x == 0 && blockIdx.x == 0) {
        out[0] = -sums[0] / (float)BATCH;
        out[1] =  sums[1] / (float)BATCH;
    }
}

static inline size_t align256(size_t x) { return (x + 255) & ~(size_t)255; }

extern "C" void kernel_launch(void* const* d_in, const int* in_sizes, int n_in,
                              void* d_out, int out_size, void* d_ws, size_t ws_size,
                              hipStream_t stream) {
    const float* uw   = (const float*)d_in[0];
    const float* iw   = (const float*)d_in[1];
    const float* vals = (const float*)d_in[2];
    const int*   rows = (const int*)d_in[3];
    const int*   cols = (const int*)d_in[4];
    const int*   users = (const int*)d_in[5];
    const int*   pos   = (const int*)d_in[6];
    const int*   neg   = (const int*)d_in[7];
    const int nnz = in_sizes[2];

    char* ws = (char*)d_ws;
    const size_t nodeBytes = (size_t)N_NODES * DIM * sizeof(float);   // 38.4 MB
    const size_t qBytes    = (size_t)N_NODES * DIM;                   // 9.6 MB (fp8)
    const size_t accBytes  = (size_t)BATCH * DIM * sizeof(float);

    size_t off = 0;
    char*  nodeReg = ws + off;            off += align256(2 * nodeBytes);   // 76.8 MB region
    float* uacc = (float*)(ws + off);     off += align256(accBytes);
    float* pacc = (float*)(ws + off);     off += align256(accBytes);
    float* nacc = (float*)(ws + off);     off += align256(accBytes);
    float* sums = (float*)(ws + off);     off += 256;   // [0]=loss, [1]=reg
    Pair*  perm = (Pair*)(ws + off);      off += align256((size_t)nnz * sizeof(Pair));
    int*   rowptr = (int*)(ws + off);     off += align256((size_t)(N_NODES + 1) * sizeof(int));
    int*   bbase  = (int*)(ws + off);     off += align256((size_t)(NB + 1) * sizeof(int));
    int*   bcursor= (int*)(ws + off);     off += align256((size_t)NB * sizeof(int));
    int*   flags  = (int*)(ws + off);     off += align256((size_t)N_NODES * sizeof(int));
    // bcv fixed-stride region aliases xb2's slot + spare (consumed before xb2 written)
    const bool fits_alias = (2 * align256(qBytes) + (size_t)NB * STRIDE * sizeof(Pair)) <= 2 * nodeBytes;
    const bool use_csr = (off <= ws_size) && fits_alias && (N_NODES < (1 << 18));

    unsigned char* xb0 = (unsigned char*)nodeReg;
    unsigned char* xb1 = (unsigned char*)(nodeReg + align256(qBytes));
    unsigned char* xb2 = (unsigned char*)(nodeReg + 2 * align256(qBytes));
    Pair*          bcv = (Pair*)(nodeReg + 2 * align256(qBytes));
    // fallback f32 views of the same region
    float* xA = (float*)nodeReg;
    float* xB = (float*)(nodeReg + nodeBytes);

    float* out = (float*)d_out;

    const int bthreads = BATCH * 16;
    const int bblocks  = bthreads / 256;
    const int tblocks  = (nnz + TILE_E - 1) / TILE_E;
    const int cblocks  = (int)(((size_t)N_NODES * DIM / 8 + 255) / 256);

    if (use_csr) {
        // convert also clears flags + bcursor; flag also clears sums
        convert_kernel<<<cblocks, 256, 0, stream>>>(uw, iw, xb0, flags, bcursor);
        flag_kernel<<<(3 * BATCH + 255) / 256, 256, 0, stream>>>(users, pos, neg, flags, sums);
        init_kernel<<<bblocks, 256, 0, stream>>>(uw, iw, users, pos, neg, uacc, pacc, nacc, sums + 1);
        binned_scatter_kernel<<<tblocks, 512, 0, stream>>>(rows, cols, vals, bcursor, bcv, nnz);
        post_scan_kernel<<<1, 512, 0, stream>>>(bcursor, bbase, rowptr, nnz);
        bucket_sort_kernel<<<NB, 512, 0, stream>>>(bcv, bcursor, bbase, rowptr, perm);

        const int sblocks = (N_NODES + 3) / 4;
        // Layer 1: xb0 -> xb1
        spmm_csr_f8_kernel<false><<<sblocks, 256, 0, stream>>>(xb0, perm, rowptr, flags, xb1);
        gather_add_f8_kernel<<<bblocks, 256, 0, stream>>>(xb1, users, pos, neg, uacc, pacc, nacc);
        // Layer 2: xb1 -> xb2 (bcv dead after sort)
        spmm_csr_f8_kernel<false><<<sblocks, 256, 0, stream>>>(xb1, perm, rowptr, flags, xb2);
        gather_add_f8_kernel<<<bblocks, 256, 0, stream>>>(xb2, users, pos, neg, uacc, pacc, nacc);
        // Layer 3: xb2 -> xb0, only flagged rows; fused gather+score epilogue
        spmm_csr_f8_kernel<true><<<sblocks, 256, 0, stream>>>(xb2, perm, rowptr, flags, xb0);
        gather_score_kernel<<<bblocks, 256, 0, stream>>>(xb0, users, pos, neg, uacc, pacc, nacc, sums);
    } else {
        // ---- Fallback: COO atomic path (f32) ----
        const long long sthreads = (long long)nnz * 16;
        const int sblocks = (int)((sthreads + 255) / 256);
        (void)hipMemsetAsync(sums, 0, 2 * sizeof(float), stream);
        init_kernel<<<bblocks, 256, 0, stream>>>(uw, iw, users, pos, neg, uacc, pacc, nacc, sums + 1);
        (void)hipMemsetAsync(xA, 0, nodeBytes, stream);
        spmm_atomic_kernel<<<sblocks, 256, 0, stream>>>(uw, iw, vals, rows, cols, xA, nnz);
        gather_add_kernel<<<bblocks, 256, 0, stream>>>(xA, users, pos, neg, uacc, pacc, nacc);
        (void)hipMemsetAsync(xB, 0, nodeBytes, stream);
        spmm_atomic_kernel<<<sblocks, 256, 0, stream>>>(xA, xA + (size_t)N_USERS * DIM, vals, rows, cols, xB, nnz);
        gather_add_kernel<<<bblocks, 256, 0, stream>>>(xB, users, pos, neg, uacc, pacc, nacc);
        (void)hipMemsetAsync(xA, 0, nodeBytes, stream);
        spmm_atomic_kernel<<<sblocks, 256, 0, stream>>>(xB, xB + (size_t)N_USERS * DIM, vals, rows, cols, xA, nnz);
        gather_add_kernel<<<bblocks, 256, 0, stream>>>(xA, users, pos, neg, uacc, pacc, nacc);
        score_kernel<<<bblocks, 256, 0, stream>>>(uacc, pacc, nacc, sums);
    }

    finalize_kernel<<<1, 1, 0, stream>>>(sums, out);
}

// Round 11
// 235.853 us; speedup vs baseline: 25.9978x; 1.1356x over previous
//
#include <hip/hip_runtime.h>

#define N_USERS 100000
#define N_ITEMS 50000
#define N_NODES (N_USERS + N_ITEMS)
#define DIM 64
#define BATCH 16384
#define RPB 512                          // rows per bucket
#define NB ((N_NODES + RPB - 1) / RPB)   // 293 buckets
#define HP 296                           // padded hist stride (bank stagger)
#define EPT 8                            // edges per thread in scatter
#define TILE_E (512 * EPT)               // 4096 edges per scatter block
#define STRIDE 12288                     // bcv region stride per bucket
#define XSCALE 64.0f                     // fp8 storage scale
#define INV_XSCALE 0.015625f             // 1/64

struct __align__(8) Pair { int c; float v; };
typedef float floatx2 __attribute__((ext_vector_type(2)));

// ---- fp8 helpers (e4m3, gfx940+ builtins) ---------------------------------
__device__ __forceinline__ unsigned pk8(float a, float b, float c, float d) {
    int w = __builtin_amdgcn_cvt_pk_fp8_f32(a, b, 0, false);
    w = __builtin_amdgcn_cvt_pk_fp8_f32(c, d, w, true);
    return (unsigned)w;
}

// acc(a0..a3) += v * fp8x4(x)   — 2 cvt + 4 fma
#define EDGE_F8D(V, X) { \
    floatx2 lo_ = __builtin_amdgcn_cvt_pk_f32_fp8((X), false); \
    floatx2 hi_ = __builtin_amdgcn_cvt_pk_f32_fp8((X), true); \
    a0 = fmaf((V), lo_.x, a0); a1 = fmaf((V), lo_.y, a1); \
    a2 = fmaf((V), hi_.x, a2); a3 = fmaf((V), hi_.y, a3); }

// ---------------------------------------------------------------------------
__device__ __forceinline__ float block_reduce_sum(float v) {
    for (int s = 32; s > 0; s >>= 1) v += __shfl_xor(v, s, 64);
    __shared__ float sm[8];
    int lane = threadIdx.x & 63;
    int wid  = threadIdx.x >> 6;
    if (lane == 0) sm[wid] = v;
    __syncthreads();
    float t = 0.0f;
    if (threadIdx.x == 0) {
        int nw = (blockDim.x + 63) >> 6;
        for (int w = 0; w < nw; ++w) t += sm[w];
    }
    return t;
}

// ---------------------------------------------------------------------------
// Convert concat [uw;iw] f32 -> fp8 (x64 scale). Also clears flags + bcursor.
// ---------------------------------------------------------------------------
__global__ void convert_kernel(const float* __restrict__ uw, const float* __restrict__ iw,
                               unsigned char* __restrict__ x8,
                               int* __restrict__ flags, int* __restrict__ bcursor) {
    size_t tid = (size_t)blockIdx.x * 256 + threadIdx.x;
    if (tid < N_NODES) flags[tid] = 0;
    else if (tid < N_NODES + NB) bcursor[tid - N_NODES] = 0;
    size_t base = tid * 8;
    if (base >= (size_t)N_NODES * DIM) return;
    const float* src = (base < (size_t)N_USERS * DIM) ? uw + base
                                                      : iw + (base - (size_t)N_USERS * DIM);
    float4 a = ((const float4*)src)[0];
    float4 b = ((const float4*)src)[1];
    uint2 o;
    o.x = pk8(XSCALE * a.x, XSCALE * a.y, XSCALE * a.z, XSCALE * a.w);
    o.y = pk8(XSCALE * b.x, XSCALE * b.y, XSCALE * b.z, XSCALE * b.w);
    *(uint2*)(x8 + base) = o;
}

// ---------------------------------------------------------------------------
// Init: acc_0 = gathered layer-0 embeddings + reg_sum from ORIGINAL weights.
// ---------------------------------------------------------------------------
__global__ void init_kernel(const float* __restrict__ uw, const float* __restrict__ iw,
                            const int* __restrict__ users, const int* __restrict__ pos,
                            const int* __restrict__ neg,
                            float* __restrict__ uacc, float* __restrict__ pacc,
                            float* __restrict__ nacc, float* __restrict__ reg_sum) {
    int tid = blockIdx.x * blockDim.x + threadIdx.x;
    int i = tid >> 4;
    int q = tid & 15;
    if (i >= BATCH) return;
    size_t o = (size_t)i * DIM + q * 4;
    float4 u = *(const float4*)(uw + (size_t)users[i] * DIM + q * 4);
    float4 p = *(const float4*)(iw + (size_t)pos[i]   * DIM + q * 4);
    float4 n = *(const float4*)(iw + (size_t)neg[i]   * DIM + q * 4);
    *(float4*)(uacc + o) = u;
    *(float4*)(pacc + o) = p;
    *(float4*)(nacc + o) = n;
    float ss = u.x*u.x + u.y*u.y + u.z*u.z + u.w*u.w
             + p.x*p.x + p.y*p.y + p.z*p.z + p.w*p.w
             + n.x*n.x + n.y*n.y + n.z*n.z + n.w*n.w;
    float bt = block_reduce_sum(ss);
    if (threadIdx.x == 0) unsafeAtomicAdd(reg_sum, bt);
}

// ---------------------------------------------------------------------------
// Mark rows needed by the final gather; also zero the loss/reg sums.
// ---------------------------------------------------------------------------
__global__ void flag_kernel(const int* __restrict__ users, const int* __restrict__ pos,
                            const int* __restrict__ neg, int* __restrict__ flags,
                            float* __restrict__ sums) {
    int tid = blockIdx.x * blockDim.x + threadIdx.x;
    if (blockIdx.x == 0 && threadIdx.x < 2) sums[threadIdx.x] = 0.0f;
    if (tid < BATCH)               flags[users[tid]] = 1;
    else if (tid < 2 * BATCH)      flags[N_USERS + pos[tid - BATCH]] = 1;
    else if (tid < 3 * BATCH)      flags[N_USERS + neg[tid - 2 * BATCH]] = 1;
}

// ---------------------------------------------------------------------------
// Binned scatter into fixed-stride per-bucket regions.
// ---------------------------------------------------------------------------
__global__ void binned_scatter_kernel(const int* __restrict__ rows, const int* __restrict__ cols,
                                      const float* __restrict__ vals, int* __restrict__ bcursor,
                                      Pair* __restrict__ bcv, int nnz) {
    __shared__ int h[8][HP];
    int t = threadIdx.x, w = t >> 6;
    for (int i = t; i < 8 * HP; i += 512) ((int*)h)[i] = 0;
    __syncthreads();
    long long tile = (long long)blockIdx.x * TILE_E;
    int er[EPT], cr[EPT];
    float vr[EPT];
    #pragma unroll
    for (int j = 0; j < EPT; ++j) {
        long long e = tile + t + j * 512;
        if (e < nnz) {
            int r = rows[e];
            er[j] = r;
            cr[j] = cols[e];
            vr[j] = vals[e];
            atomicAdd(&h[w][r >> 9], 1);
        } else er[j] = -1;
    }
    __syncthreads();
    for (int b = t; b < NB; b += 512) {
        int cw[8], tot = 0;
        #pragma unroll
        for (int w2 = 0; w2 < 8; ++w2) { cw[w2] = h[w2][b]; tot += cw[w2]; }
        int base = tot ? (b * STRIDE + atomicAdd(&bcursor[b], tot)) : 0;
        #pragma unroll
        for (int w2 = 0; w2 < 8; ++w2) { h[w2][b] = base; base += cw[w2]; }
    }
    __syncthreads();
    #pragma unroll
    for (int j = 0; j < EPT; ++j) {
        if (er[j] >= 0) {
            int r = er[j];
            int dst = atomicAdd(&h[w][r >> 9], 1);
            Pair p;
            p.c = cr[j] | ((r & (RPB - 1)) << 18);
            p.v = vr[j];
            bcv[dst] = p;
        }
    }
}

// ---------------------------------------------------------------------------
// Post-scan: bucket counts -> dense CSR bucket bases.
// ---------------------------------------------------------------------------
__global__ void post_scan_kernel(const int* __restrict__ counts, int* __restrict__ bbase,
                                 int* __restrict__ rowptr, int nnz) {
    __shared__ int sm[512];
    int t = threadIdx.x;
    int v = (t < NB) ? counts[t] : 0;
    sm[t] = v;
    __syncthreads();
    for (int off = 1; off < 512; off <<= 1) {
        int tmp = (t >= off) ? sm[t - off] : 0;
        __syncthreads();
        sm[t] += tmp;
        __syncthreads();
    }
    if (t < NB) bbase[t] = sm[t] - v;
    if (t == 511) bbase[NB] = sm[511];
    if (t == 0) rowptr[N_NODES] = nnz;
}

// ---------------------------------------------------------------------------
// Per-bucket counting sort in LDS -> final dense CSR perm + rowptr.
// ---------------------------------------------------------------------------
__global__ void bucket_sort_kernel(const Pair* __restrict__ bcv,
                                   const int* __restrict__ counts,
                                   const int* __restrict__ bbase,
                                   int* __restrict__ rowptr, Pair* __restrict__ perm) {
    __shared__ int rh8[8][RPB + 8];
    __shared__ int rh[RPB];
    __shared__ int sc[RPB];
    int blk = blockIdx.x;
    int t = threadIdx.x;        // 512 threads
    int w = t >> 6;
    int src  = blk * STRIDE;
    int base = bbase[blk];
    int cnt  = counts[blk];
    for (int i = t; i < 8 * (RPB + 8); i += 512) ((int*)rh8)[i] = 0;
    __syncthreads();
    for (int i = t; i < cnt; i += 512)
        atomicAdd(&rh8[w][(unsigned)bcv[src + i].c >> 18], 1);
    __syncthreads();
    int v = 0;
    #pragma unroll
    for (int w2 = 0; w2 < 8; ++w2) v += rh8[w2][t];
    sc[t] = v;
    __syncthreads();
    for (int off = 1; off < 512; off <<= 1) {
        int tmp = (t >= off) ? sc[t - off] : 0;
        __syncthreads();
        sc[t] += tmp;
        __syncthreads();
    }
    int excl = sc[t] - v;
    int g = blk * RPB + t;
    if (g < N_NODES) rowptr[g] = base + excl;
    rh[t] = excl;
    __syncthreads();
    for (int i = t; i < cnt; i += 512) {
        Pair p = bcv[src + i];
        int r = (unsigned)p.c >> 18;
        int rk = atomicAdd(&rh[r], 1);
        p.c &= 0x3FFFF;
        perm[base + rk] = p;
    }
}

// ---------------------------------------------------------------------------
// CSR SpMM, fp8 in / fp8 out (f32 accumulate). 16 lanes per ROW (one dword
// = 4 dims per lane); each 16-lane group walks its row's edges sequentially
// with 8-deep unroll (8 gathers + 8 perm loads in flight per lane; 32 edge
// gathers in flight per wave). Zero shuffles; trivial epilogue.
// ---------------------------------------------------------------------------
template<bool FLAGGED>
__global__ void spmm_csr_f8_kernel(const unsigned char* __restrict__ x8,
                                   const Pair* __restrict__ pe,
                                   const int* __restrict__ rowptr,
                                   const int* __restrict__ flags,
                                   unsigned char* __restrict__ out8) {
    int row = blockIdx.x * 16 + (threadIdx.x >> 4);
    if (row >= N_NODES) return;
    if (FLAGGED && !flags[row]) return;
    int q = threadIdx.x & 15;        // dword slot (4 dims)
    int start = rowptr[row];
    int end   = rowptr[row + 1];
    float a0 = 0.f, a1 = 0.f, a2 = 0.f, a3 = 0.f;
    int e = start;
    for (; e + 7 < end; e += 8) {
        Pair p0 = pe[e],     p1 = pe[e + 1], p2 = pe[e + 2], p3 = pe[e + 3];
        Pair p4 = pe[e + 4], p5 = pe[e + 5], p6 = pe[e + 6], p7 = pe[e + 7];
        unsigned x0 = *(const unsigned*)(x8 + ((size_t)p0.c << 6) + q * 4);
        unsigned x1 = *(const unsigned*)(x8 + ((size_t)p1.c << 6) + q * 4);
        unsigned x2 = *(const unsigned*)(x8 + ((size_t)p2.c << 6) + q * 4);
        unsigned x3 = *(const unsigned*)(x8 + ((size_t)p3.c << 6) + q * 4);
        unsigned x4 = *(const unsigned*)(x8 + ((size_t)p4.c << 6) + q * 4);
        unsigned x5 = *(const unsigned*)(x8 + ((size_t)p5.c << 6) + q * 4);
        unsigned x6 = *(const unsigned*)(x8 + ((size_t)p6.c << 6) + q * 4);
        unsigned x7 = *(const unsigned*)(x8 + ((size_t)p7.c << 6) + q * 4);
        EDGE_F8D(p0.v, x0); EDGE_F8D(p1.v, x1);
        EDGE_F8D(p2.v, x2); EDGE_F8D(p3.v, x3);
        EDGE_F8D(p4.v, x4); EDGE_F8D(p5.v, x5);
        EDGE_F8D(p6.v, x6); EDGE_F8D(p7.v, x7);
    }
    for (; e + 1 < end; e += 2) {
        Pair p0 = pe[e], p1 = pe[e + 1];
        unsigned x0 = *(const unsigned*)(x8 + ((size_t)p0.c << 6) + q * 4);
        unsigned x1 = *(const unsigned*)(x8 + ((size_t)p1.c << 6) + q * 4);
        EDGE_F8D(p0.v, x0); EDGE_F8D(p1.v, x1);
    }
    if (e < end) {
        Pair p = pe[e];
        unsigned x = *(const unsigned*)(x8 + ((size_t)p.c << 6) + q * 4);
        EDGE_F8D(p.v, x);
    }
    *(unsigned*)(out8 + ((size_t)row << 6) + q * 4) = pk8(a0, a1, a2, a3);
}

// ---------------------------------------------------------------------------
// Legacy COO atomic SpMM (fallback).
// ---------------------------------------------------------------------------
__global__ void spmm_atomic_kernel(const float* __restrict__ xu, const float* __restrict__ xi,
                                   const float* __restrict__ vals, const int* __restrict__ rows,
                                   const int* __restrict__ cols,
                                   float* __restrict__ out, int nnz) {
    long long tid = (long long)blockIdx.x * blockDim.x + threadIdx.x;
    int e = (int)(tid >> 4);
    if (e >= nnz) return;
    int q = (int)(tid & 15);
    int r = rows[e];
    int c = cols[e];
    float v = vals[e];
    const float* src = (c < N_USERS) ? (xu + (size_t)c * DIM)
                                     : (xi + (size_t)(c - N_USERS) * DIM);
    float4 x = *(const float4*)(src + q * 4);
    float* dst = out + (size_t)r * DIM + q * 4;
    unsafeAtomicAdd(dst + 0, v * x.x);
    unsafeAtomicAdd(dst + 1, v * x.y);
    unsafeAtomicAdd(dst + 2, v * x.z);
    unsafeAtomicAdd(dst + 3, v * x.w);
}

// ---------------------------------------------------------------------------
// Gather-accumulate a layer's fp8 output at the batch rows only (unscale).
// ---------------------------------------------------------------------------
__global__ void gather_add_f8_kernel(const unsigned char* __restrict__ x8,
                                     const int* __restrict__ users, const int* __restrict__ pos,
                                     const int* __restrict__ neg,
                                     float* __restrict__ uacc, float* __restrict__ pacc,
                                     float* __restrict__ nacc) {
    int tid = blockIdx.x * blockDim.x + threadIdx.x;
    int i = tid >> 4;
    int q = tid & 15;
    if (i >= BATCH) return;
    size_t o = (size_t)i * DIM + q * 4;
    float4 a;
    unsigned u;
    floatx2 lo, hi;

    a = *(float4*)(uacc + o);
    u = *(const unsigned*)(x8 + ((size_t)users[i] << 6) + q * 4);
    lo = __builtin_amdgcn_cvt_pk_f32_fp8(u, false);
    hi = __builtin_amdgcn_cvt_pk_f32_fp8(u, true);
    a.x = fmaf(lo.x, INV_XSCALE, a.x); a.y = fmaf(lo.y, INV_XSCALE, a.y);
    a.z = fmaf(hi.x, INV_XSCALE, a.z); a.w = fmaf(hi.y, INV_XSCALE, a.w);
    *(float4*)(uacc + o) = a;

    a = *(float4*)(pacc + o);
    u = *(const unsigned*)(x8 + ((size_t)(N_USERS + pos[i]) << 6) + q * 4);
    lo = __builtin_amdgcn_cvt_pk_f32_fp8(u, false);
    hi = __builtin_amdgcn_cvt_pk_f32_fp8(u, true);
    a.x = fmaf(lo.x, INV_XSCALE, a.x); a.y = fmaf(lo.y, INV_XSCALE, a.y);
    a.z = fmaf(hi.x, INV_XSCALE, a.z); a.w = fmaf(hi.y, INV_XSCALE, a.w);
    *(float4*)(pacc + o) = a;

    a = *(float4*)(nacc + o);
    u = *(const unsigned*)(x8 + ((size_t)(N_USERS + neg[i]) << 6) + q * 4);
    lo = __builtin_amdgcn_cvt_pk_f32_fp8(u, false);
    hi = __builtin_amdgcn_cvt_pk_f32_fp8(u, true);
    a.x = fmaf(lo.x, INV_XSCALE, a.x); a.y = fmaf(lo.y, INV_XSCALE, a.y);
    a.z = fmaf(hi.x, INV_XSCALE, a.z); a.w = fmaf(hi.y, INV_XSCALE, a.w);
    *(float4*)(nacc + o) = a;
}

// ---------------------------------------------------------------------------
// Fused layer-3 gather + BPR score. final = acc/4, so dot scales by 1/16.
// ---------------------------------------------------------------------------
__global__ void gather_score_kernel(const unsigned char* __restrict__ x8,
                                    const int* __restrict__ users, const int* __restrict__ pos,
                                    const int* __restrict__ neg,
                                    const float* __restrict__ uacc, const float* __restrict__ pacc,
                                    const float* __restrict__ nacc, float* __restrict__ loss_sum) {
    int tid = blockIdx.x * blockDim.x + threadIdx.x;
    int i = tid >> 4;
    int q = tid & 15;
    float ps = 0.0f, ns = 0.0f;
    if (i < BATCH) {
        size_t o = (size_t)i * DIM + q * 4;
        float4 u = *(const float4*)(uacc + o);
        float4 p = *(const float4*)(pacc + o);
        float4 n = *(const float4*)(nacc + o);
        unsigned t;
        floatx2 lo, hi;
        t = *(const unsigned*)(x8 + ((size_t)users[i] << 6) + q * 4);
        lo = __builtin_amdgcn_cvt_pk_f32_fp8(t, false);
        hi = __builtin_amdgcn_cvt_pk_f32_fp8(t, true);
        u.x = fmaf(lo.x, INV_XSCALE, u.x); u.y = fmaf(lo.y, INV_XSCALE, u.y);
        u.z = fmaf(hi.x, INV_XSCALE, u.z); u.w = fmaf(hi.y, INV_XSCALE, u.w);
        t = *(const unsigned*)(x8 + ((size_t)(N_USERS + pos[i]) << 6) + q * 4);
        lo = __builtin_amdgcn_cvt_pk_f32_fp8(t, false);
        hi = __builtin_amdgcn_cvt_pk_f32_fp8(t, true);
        p.x = fmaf(lo.x, INV_XSCALE, p.x); p.y = fmaf(lo.y, INV_XSCALE, p.y);
        p.z = fmaf(hi.x, INV_XSCALE, p.z); p.w = fmaf(hi.y, INV_XSCALE, p.w);
        t = *(const unsigned*)(x8 + ((size_t)(N_USERS + neg[i]) << 6) + q * 4);
        lo = __builtin_amdgcn_cvt_pk_f32_fp8(t, false);
        hi = __builtin_amdgcn_cvt_pk_f32_fp8(t, true);
        n.x = fmaf(lo.x, INV_XSCALE, n.x); n.y = fmaf(lo.y, INV_XSCALE, n.y);
        n.z = fmaf(hi.x, INV_XSCALE, n.z); n.w = fmaf(hi.y, INV_XSCALE, n.w);
        ps = u.x*p.x + u.y*p.y + u.z*p.z + u.w*p.w;
        ns = u.x*n.x + u.y*n.y + u.z*n.z + u.w*n.w;
    }
    for (int s = 8; s > 0; s >>= 1) {
        ps += __shfl_xor(ps, s, 16);
        ns += __shfl_xor(ns, s, 16);
    }
    float term = 0.0f;
    if (q == 0 && i < BATCH) {
        float d = (ps - ns) * (1.0f / 16.0f);
        float sig = 1.0f / (1.0f + expf(-d));
        term = logf(sig + 1e-8f);
    }
    float bt = block_reduce_sum(term);
    if (threadIdx.x == 0) unsafeAtomicAdd(loss_sum, bt);
}

// f32 gather-add + score (fallback path)
__global__ void gather_add_kernel(const float* __restrict__ x,
                                  const int* __restrict__ users, const int* __restrict__ pos,
                                  const int* __restrict__ neg,
                                  float* __restrict__ uacc, float* __restrict__ pacc,
                                  float* __restrict__ nacc) {
    int tid = blockIdx.x * blockDim.x + threadIdx.x;
    int i = tid >> 4;
    int q = tid & 15;
    if (i >= BATCH) return;
    size_t o = (size_t)i * DIM + q * 4;
    float4 a, b;
    a = *(float4*)(uacc + o);
    b = *(const float4*)(x + (size_t)users[i] * DIM + q * 4);
    a.x += b.x; a.y += b.y; a.z += b.z; a.w += b.w;
    *(float4*)(uacc + o) = a;
    a = *(float4*)(pacc + o);
    b = *(const float4*)(x + (size_t)(N_USERS + pos[i]) * DIM + q * 4);
    a.x += b.x; a.y += b.y; a.z += b.z; a.w += b.w;
    *(float4*)(pacc + o) = a;
    a = *(float4*)(nacc + o);
    b = *(const float4*)(x + (size_t)(N_USERS + neg[i]) * DIM + q * 4);
    a.x += b.x; a.y += b.y; a.z += b.z; a.w += b.w;
    *(float4*)(nacc + o) = a;
}

__global__ void score_kernel(const float* __restrict__ uacc, const float* __restrict__ pacc,
                             const float* __restrict__ nacc, float* __restrict__ loss_sum) {
    int tid = blockIdx.x * blockDim.x + threadIdx.x;
    int i = tid >> 4;
    int q = tid & 15;
    float ps = 0.0f, ns = 0.0f;
    if (i < BATCH) {
        size_t o = (size_t)i * DIM + q * 4;
        float4 u = *(const float4*)(uacc + o);
        float4 p = *(const float4*)(pacc + o);
        float4 n = *(const float4*)(nacc + o);
        ps = u.x*p.x + u.y*p.y + u.z*p.z + u.w*p.w;
        ns = u.x*n.x + u.y*n.y + u.z*n.z + u.w*n.w;
    }
    for (int s = 8; s > 0; s >>= 1) {
        ps += __shfl_xor(ps, s, 16);
        ns += __shfl_xor(ns, s, 16);
    }
    float term = 0.0f;
    if (q == 0 && i < BATCH) {
        float d = (ps - ns) * (1.0f / 16.0f);
        float sig = 1.0f / (1.0f + expf(-d));
        term = logf(sig + 1e-8f);
    }
    float bt = block_reduce_sum(term);
    if (threadIdx.x == 0) unsafeAtomicAdd(loss_sum, bt);
}

__global__ void finalize_kernel(const float* __restrict__ sums, float* __restrict__ out) {
    if (threadIdx.x == 0 && blockIdx.x == 0) {
        out[0] = -sums[0] / (float)BATCH;
        out[1] =  sums[1] / (float)BATCH;
    }
}

static inline size_t align256(size_t x) { return (x + 255) & ~(size_t)255; }

extern "C" void kernel_launch(void* const* d_in, const int* in_sizes, int n_in,
                              void* d_out, int out_size, void* d_ws, size_t ws_size,
                              hipStream_t stream) {
    const float* uw   = (const float*)d_in[0];
    const float* iw   = (const float*)d_in[1];
    const float* vals = (const float*)d_in[2];
    const int*   rows = (const int*)d_in[3];
    const int*   cols = (const int*)d_in[4];
    const int*   users = (const int*)d_in[5];
    const int*   pos   = (const int*)d_in[6];
    const int*   neg   = (const int*)d_in[7];
    const int nnz = in_sizes[2];

    char* ws = (char*)d_ws;
    const size_t nodeBytes = (size_t)N_NODES * DIM * sizeof(float);   // 38.4 MB
    const size_t qBytes    = (size_t)N_NODES * DIM;                   // 9.6 MB (fp8)
    const size_t accBytes  = (size_t)BATCH * DIM * sizeof(float);

    size_t off = 0;
    char*  nodeReg = ws + off;            off += align256(2 * nodeBytes);   // 76.8 MB region
    float* uacc = (float*)(ws + off);     off += align256(accBytes);
    float* pacc = (float*)(ws + off);     off += align256(accBytes);
    float* nacc = (float*)(ws + off);     off += align256(accBytes);
    float* sums = (float*)(ws + off);     off += 256;   // [0]=loss, [1]=reg
    Pair*  perm = (Pair*)(ws + off);      off += align256((size_t)nnz * sizeof(Pair));
    int*   rowptr = (int*)(ws + off);     off += align256((size_t)(N_NODES + 1) * sizeof(int));
    int*   bbase  = (int*)(ws + off);     off += align256((size_t)(NB + 1) * sizeof(int));
    int*   bcursor= (int*)(ws + off);     off += align256((size_t)NB * sizeof(int));
    int*   flags  = (int*)(ws + off);     off += align256((size_t)N_NODES * sizeof(int));
    const bool fits_alias = (2 * align256(qBytes) + (size_t)NB * STRIDE * sizeof(Pair)) <= 2 * nodeBytes;
    const bool use_csr = (off <= ws_size) && fits_alias && (N_NODES < (1 << 18));

    unsigned char* xb0 = (unsigned char*)nodeReg;
    unsigned char* xb1 = (unsigned char*)(nodeReg + align256(qBytes));
    unsigned char* xb2 = (unsigned char*)(nodeReg + 2 * align256(qBytes));
    Pair*          bcv = (Pair*)(nodeReg + 2 * align256(qBytes));
    float* xA = (float*)nodeReg;
    float* xB = (float*)(nodeReg + nodeBytes);

    float* out = (float*)d_out;

    const int bthreads = BATCH * 16;
    const int bblocks  = bthreads / 256;
    const int tblocks  = (nnz + TILE_E - 1) / TILE_E;
    const int cblocks  = (int)(((size_t)N_NODES * DIM / 8 + 255) / 256);

    if (use_csr) {
        convert_kernel<<<cblocks, 256, 0, stream>>>(uw, iw, xb0, flags, bcursor);
        flag_kernel<<<(3 * BATCH + 255) / 256, 256, 0, stream>>>(users, pos, neg, flags, sums);
        init_kernel<<<bblocks, 256, 0, stream>>>(uw, iw, users, pos, neg, uacc, pacc, nacc, sums + 1);
        binned_scatter_kernel<<<tblocks, 512, 0, stream>>>(rows, cols, vals, bcursor, bcv, nnz);
        post_scan_kernel<<<1, 512, 0, stream>>>(bcursor, bbase, rowptr, nnz);
        bucket_sort_kernel<<<NB, 512, 0, stream>>>(bcv, bcursor, bbase, rowptr, perm);

        const int sblocks = (N_NODES + 15) / 16;   // 16 rows per 256-thread block
        // Layer 1: xb0 -> xb1
        spmm_csr_f8_kernel<false><<<sblocks, 256, 0, stream>>>(xb0, perm, rowptr, flags, xb1);
        gather_add_f8_kernel<<<bblocks, 256, 0, stream>>>(xb1, users, pos, neg, uacc, pacc, nacc);
        // Layer 2: xb1 -> xb2 (bcv dead after sort)
        spmm_csr_f8_kernel<false><<<sblocks, 256, 0, stream>>>(xb1, perm, rowptr, flags, xb2);
        gather_add_f8_kernel<<<bblocks, 256, 0, stream>>>(xb2, users, pos, neg, uacc, pacc, nacc);
        // Layer 3: xb2 -> xb0, only flagged rows; fused gather+score epilogue
        spmm_csr_f8_kernel<true><<<sblocks, 256, 0, stream>>>(xb2, perm, rowptr, flags, xb0);
        gather_score_kernel<<<bblocks, 256, 0, stream>>>(xb0, users, pos, neg, uacc, pacc, nacc, sums);
    } else {
        const long long sthreads = (long long)nnz * 16;
        const int sblocks = (int)((sthreads + 255) / 256);
        (void)hipMemsetAsync(sums, 0, 2 * sizeof(float), stream);
        init_kernel<<<bblocks, 256, 0, stream>>>(uw, iw, users, pos, neg, uacc, pacc, nacc, sums + 1);
        (void)hipMemsetAsync(xA, 0, nodeBytes, stream);
        spmm_atomic_kernel<<<sblocks, 256, 0, stream>>>(uw, iw, vals, rows, cols, xA, nnz);
        gather_add_kernel<<<bblocks, 256, 0, stream>>>(xA, users, pos, neg, uacc, pacc, nacc);
        (void)hipMemsetAsync(xB, 0, nodeBytes, stream);
        spmm_atomic_kernel<<<sblocks, 256, 0, stream>>>(xA, xA + (size_t)N_USERS * DIM, vals, rows, cols, xB, nnz);
        gather_add_kernel<<<bblocks, 256, 0, stream>>>(xB, users, pos, neg, uacc, pacc, nacc);
        (void)hipMemsetAsync(xA, 0, nodeBytes, stream);
        spmm_atomic_kernel<<<sblocks, 256, 0, stream>>>(xB, xB + (size_t)N_USERS * DIM, vals, rows, cols, xA, nnz);
        gather_add_kernel<<<bblocks, 256, 0, stream>>>(xA, users, pos, neg, uacc, pacc, nacc);
        score_kernel<<<bblocks, 256, 0, stream>>>(uacc, pacc, nacc, sums);
    }

    finalize_kernel<<<1, 1, 0, stream>>>(sums, out);
}